// Round 1
// baseline (1427.885 us; speedup 1.0000x reference)
//
#include <hip/hip_runtime.h>
#include <hip/hip_bf16.h>
#include <math.h>

// Model dims
#define BB 8
#define TT 1024
#define DD 256
#define HH 512
#define NN 16
#define RR 8
#define OUT_LEN 96
#define IN_DIM 32
#define MM (BB*TT)   // 8192 rows

// ---------------------------------------------------------------------------
// Embedding + positional encoding: h[bt,d] = x[bt,:] . emb_w[d,:] + emb_b[d] + pe[t,d]
// ---------------------------------------------------------------------------
__global__ __launch_bounds__(256) void embed_kernel(
    const float* __restrict__ x, const float* __restrict__ emb_w,
    const float* __restrict__ emb_b, float* __restrict__ h)
{
    int bt = blockIdx.x;           // 0..8191
    int d  = threadIdx.x;          // 0..255
    int t  = bt & (TT - 1);

    __shared__ float xs[IN_DIM];
    if (threadIdx.x < IN_DIM) xs[threadIdx.x] = x[bt * IN_DIM + threadIdx.x];
    __syncthreads();

    const float* w = emb_w + d * IN_DIM;
    float acc = emb_b[d];
#pragma unroll
    for (int i = 0; i < IN_DIM; i++) acc = fmaf(xs[i], w[i], acc);

    // positional encoding
    int i2 = d & ~1;  // 2*i
    float div = expf(-(float)i2 * (logf(10000.0f) / (float)DD));
    float arg = (float)t * div;
    float pe = (d & 1) ? cosf(arg) : sinf(arg);
    h[bt * DD + d] = acc + pe;
}

// ---------------------------------------------------------------------------
// LayerNorm over D=256, one block per (b,t) row
// ---------------------------------------------------------------------------
__global__ __launch_bounds__(256) void ln_kernel(
    const float* __restrict__ h, const float* __restrict__ g,
    const float* __restrict__ b, float* __restrict__ out)
{
    int bt = blockIdx.x;
    int d  = threadIdx.x;
    float v = h[bt * DD + d];

    __shared__ float red[4], red2[4];
    float s = v;
#pragma unroll
    for (int o = 32; o > 0; o >>= 1) s += __shfl_down(s, o);
    int lane = d & 63, wave = d >> 6;
    if (lane == 0) red[wave] = s;
    __syncthreads();
    float mean = (red[0] + red[1] + red[2] + red[3]) * (1.0f / DD);

    float c = v - mean;
    float s2 = c * c;
#pragma unroll
    for (int o = 32; o > 0; o >>= 1) s2 += __shfl_down(s2, o);
    if (lane == 0) red2[wave] = s2;
    __syncthreads();
    float var = (red2[0] + red2[1] + red2[2] + red2[3]) * (1.0f / DD);

    out[bt * DD + d] = c * rsqrtf(var + 1e-5f) * g[d] + b[d];
}

// ---------------------------------------------------------------------------
// fp32 NT GEMM: C[m,n] = sum_k A[m,k] * B[n,k]  (A row-major MxK, B row-major NxK)
// optional in-place accumulate (addC=1): C += A*B^T
// BM x BN block tile, TM x TN per-thread micro-tile, BK=16, 256 threads.
// ---------------------------------------------------------------------------
template<int BM, int BN, int TM, int TN>
__global__ __launch_bounds__(256) void gemm_nt(
    const float* __restrict__ A, const float* __restrict__ B,
    float* __restrict__ C, int M, int N, int K, int addC)
{
    constexpr int BK = 16;
    __shared__ __align__(16) float As[BK][BM + 4];
    __shared__ __align__(16) float Bs[BK][BN + 4];

    const int tid = threadIdx.x;
    const int bm = blockIdx.y * BM;
    const int bn = blockIdx.x * BN;
    constexpr int TX = BN / TN;        // 16
    const int tx = tid % TX;
    const int ty = tid / TX;

    float acc[TM][TN];
#pragma unroll
    for (int i = 0; i < TM; i++)
#pragma unroll
        for (int j = 0; j < TN; j++) acc[i][j] = 0.0f;

    const int arow = tid >> 2;          // 0..63
    const int acol = (tid & 3) << 2;    // 0,4,8,12
    const float* Ag = A + (size_t)(bm + arow) * K + acol;
    const float* Bg = B + (size_t)(bn + arow) * K + acol;   // BN==64 assumed

    for (int k0 = 0; k0 < K; k0 += BK) {
#pragma unroll
        for (int j = 0; j < BM / 64; j++) {
            float4 av = *(const float4*)(Ag + (size_t)j * 64 * K + k0);
            As[acol + 0][arow + j * 64] = av.x;
            As[acol + 1][arow + j * 64] = av.y;
            As[acol + 2][arow + j * 64] = av.z;
            As[acol + 3][arow + j * 64] = av.w;
        }
        {
            float4 bv = *(const float4*)(Bg + k0);
            Bs[acol + 0][arow] = bv.x;
            Bs[acol + 1][arow] = bv.y;
            Bs[acol + 2][arow] = bv.z;
            Bs[acol + 3][arow] = bv.w;
        }
        __syncthreads();
#pragma unroll
        for (int kk = 0; kk < BK; kk++) {
            float a[TM], bb[TN];
#pragma unroll
            for (int i = 0; i < TM; i += 4) {
                float4 t4 = *(const float4*)&As[kk][ty * TM + i];
                a[i] = t4.x; a[i + 1] = t4.y; a[i + 2] = t4.z; a[i + 3] = t4.w;
            }
#pragma unroll
            for (int j = 0; j < TN; j += 4) {
                float4 t4 = *(const float4*)&Bs[kk][tx * TN + j];
                bb[j] = t4.x; bb[j + 1] = t4.y; bb[j + 2] = t4.z; bb[j + 3] = t4.w;
            }
#pragma unroll
            for (int i = 0; i < TM; i++)
#pragma unroll
                for (int j = 0; j < TN; j++)
                    acc[i][j] = fmaf(a[i], bb[j], acc[i][j]);
        }
        __syncthreads();
    }

#pragma unroll
    for (int i = 0; i < TM; i++) {
        float* Cp = C + (size_t)(bm + ty * TM + i) * N + bn + tx * TN;
#pragma unroll
        for (int j = 0; j < TN; j += 4) {
            float4 cv;
            cv.x = acc[i][j]; cv.y = acc[i][j + 1];
            cv.z = acc[i][j + 2]; cv.w = acc[i][j + 3];
            if (addC) {
                float4 old = *(const float4*)(Cp + j);
                cv.x += old.x; cv.y += old.y; cv.z += old.z; cv.w += old.w;
            }
            *(float4*)(Cp + j) = cv;
        }
    }
}

// ---------------------------------------------------------------------------
// Depthwise conv (k=3, pad 1, cross-correlation) over time + SiLU
// v layout (B,T,H); out same layout
// ---------------------------------------------------------------------------
__global__ __launch_bounds__(256) void conv_silu_kernel(
    const float* __restrict__ v, const float* __restrict__ w,
    float* __restrict__ out)
{
    int idx = blockIdx.x * 256 + threadIdx.x;   // B*T*H
    int h = idx & (HH - 1);
    int t = (idx >> 9) & (TT - 1);
    const float* wp = w + h * 3;
    float acc = wp[1] * v[idx];
    if (t > 0)      acc = fmaf(wp[0], v[idx - HH], acc);
    if (t < TT - 1) acc = fmaf(wp[2], v[idx + HH], acc);
    out[idx] = acc / (1.0f + __expf(-acc));   // silu
}

// ---------------------------------------------------------------------------
// dt1: dtr[m,r] = relu(sum_h vs[m,h]*dt1_w[r,h] + dt1_b[r]); one wave per m
// ---------------------------------------------------------------------------
__global__ __launch_bounds__(256) void dt1_kernel(
    const float* __restrict__ vs, const float* __restrict__ w,
    const float* __restrict__ bias, float* __restrict__ dtr)
{
    int wave = threadIdx.x >> 6;
    int lane = threadIdx.x & 63;
    int m = blockIdx.x * 4 + wave;
    const float* vrow = vs + (size_t)m * HH;

    float acc[RR];
#pragma unroll
    for (int r = 0; r < RR; r++) acc[r] = 0.0f;

#pragma unroll
    for (int j = 0; j < HH / 64; j++) {
        int hh = lane + j * 64;
        float vv = vrow[hh];
#pragma unroll
        for (int r = 0; r < RR; r++) acc[r] = fmaf(vv, w[r * HH + hh], acc[r]);
    }
#pragma unroll
    for (int r = 0; r < RR; r++) {
#pragma unroll
        for (int o = 32; o > 0; o >>= 1) acc[r] += __shfl_down(acc[r], o);
    }
    if (lane == 0) {
#pragma unroll
        for (int r = 0; r < RR; r++)
            dtr[m * RR + r] = fmaxf(acc[r] + bias[r], 0.0f);
    }
}

// ---------------------------------------------------------------------------
// dt2 + softplus: dtf[m,h] = softplus(sum_r dtr[m,r]*dt2_w[h,r] + dt2_b[h])
// ---------------------------------------------------------------------------
__global__ __launch_bounds__(256) void dt2_kernel(
    const float* __restrict__ dtr, const float* __restrict__ w,
    const float* __restrict__ bias, float* __restrict__ out)
{
    int idx = blockIdx.x * 256 + threadIdx.x;  // M*H
    int h = idx & (HH - 1);
    int m = idx >> 9;
    const float* dr = dtr + m * RR;
    const float* wr = w + h * RR;
    float acc = bias[h];
#pragma unroll
    for (int r = 0; r < RR; r++) acc = fmaf(dr[r], wr[r], acc);
    out[idx] = (acc > 20.0f) ? acc : log1pf(__expf(acc));
}

// ---------------------------------------------------------------------------
// Selective scan. Lane = (h_sub, n); block handles (b, 16 h-channels).
// state_t = exp(A*dt)*state + ((exp(A*dt)-1)/A*dt)*x ; y = sum_n state*A_p + D_p*x
// ---------------------------------------------------------------------------
#define TC 64
__global__ __launch_bounds__(256) void scan_kernel(
    const float* __restrict__ vs,    // (B,T,H) post conv+silu
    const float* __restrict__ dtf,   // (B,T,H) softplus(dt)
    const float* __restrict__ A_p,   // (H,N) layer slice
    const float* __restrict__ D_p,   // (H,)
    float* __restrict__ y)           // (B,T,H)
{
    int b  = blockIdx.y;
    int h0 = blockIdx.x * 16;
    int tid = threadIdx.x;
    int hs = tid >> 4;     // 0..15
    int n  = tid & 15;
    int h  = h0 + hs;

    float Ap   = A_p[h * NN + n];
    float A    = -__expf(Ap);
    float invA = 1.0f / A;
    float Dp   = D_p[h];

    __shared__ float xs[16][TC + 1];
    __shared__ float ds[16][TC + 1];
    __shared__ float ys[16][TC + 1];

    const float* vbase = vs  + (size_t)b * TT * HH + h0;
    const float* dbase = dtf + (size_t)b * TT * HH + h0;
    float*       ybase = y   + (size_t)b * TT * HH + h0;

    int lt = tid >> 4;   // t-sub for load phases
    int lh = tid & 15;   // h-sub for load phases

    float state = 0.0f;
    for (int t0 = 0; t0 < TT; t0 += TC) {
#pragma unroll
        for (int j = 0; j < TC / 16; j++) {
            int t = lt + j * 16;
            xs[lh][t] = vbase[(size_t)(t0 + t) * HH + lh];
            ds[lh][t] = dbase[(size_t)(t0 + t) * HH + lh];
        }
        __syncthreads();
#pragma unroll 4
        for (int t = 0; t < TC; t++) {
            float dt = ds[hs][t];
            float xv = xs[hs][t];
            float e  = __expf(A * dt);
            float dB = (e - 1.0f) * invA * dt;
            state = fmaf(e, state, dB * xv);
            float contrib = state * Ap;
            contrib += __shfl_xor(contrib, 1);
            contrib += __shfl_xor(contrib, 2);
            contrib += __shfl_xor(contrib, 4);
            contrib += __shfl_xor(contrib, 8);
            if (n == 0) ys[hs][t] = fmaf(Dp, xv, contrib);
        }
        __syncthreads();
#pragma unroll
        for (int j = 0; j < TC / 16; j++) {
            int t = lt + j * 16;
            ybase[(size_t)(t0 + t) * HH + lh] = ys[lh][t];
        }
        // next-iteration's post-load __syncthreads() orders store(c) vs compute(c+1)
    }
}

// ---------------------------------------------------------------------------
// Head: final LN on last token, head1+silu, head2. One block per batch.
// ---------------------------------------------------------------------------
__global__ __launch_bounds__(256) void head_kernel(
    const float* __restrict__ h,
    const float* __restrict__ fg, const float* __restrict__ fb,
    const float* __restrict__ w1, const float* __restrict__ b1,
    const float* __restrict__ w2, const float* __restrict__ b2,
    float* __restrict__ out)
{
    int b = blockIdx.x;
    int d = threadIdx.x;
    __shared__ float hn[DD], s1[DD];
    __shared__ float red[4];

    float v = h[((size_t)b * TT + (TT - 1)) * DD + d];

    float s = v;
#pragma unroll
    for (int o = 32; o > 0; o >>= 1) s += __shfl_down(s, o);
    int lane = d & 63, wave = d >> 6;
    if (lane == 0) red[wave] = s;
    __syncthreads();
    float mean = (red[0] + red[1] + red[2] + red[3]) * (1.0f / DD);
    __syncthreads();

    float c = v - mean;
    float s2 = c * c;
#pragma unroll
    for (int o = 32; o > 0; o >>= 1) s2 += __shfl_down(s2, o);
    if (lane == 0) red[wave] = s2;
    __syncthreads();
    float var = (red[0] + red[1] + red[2] + red[3]) * (1.0f / DD);

    hn[d] = c * rsqrtf(var + 1e-5f) * fg[d] + fb[d];
    __syncthreads();

    // head1 + silu
    float a1 = b1[d];
    const float* w1r = w1 + d * DD;
#pragma unroll 8
    for (int k = 0; k < DD; k++) a1 = fmaf(hn[k], w1r[k], a1);
    s1[d] = a1 / (1.0f + __expf(-a1));
    __syncthreads();

    if (d < OUT_LEN) {
        float a2 = b2[d];
        const float* w2r = w2 + d * DD;
#pragma unroll 8
        for (int k = 0; k < DD; k++) a2 = fmaf(s1[k], w2r[k], a2);
        out[b * OUT_LEN + d] = a2;
    }
}

// ---------------------------------------------------------------------------
extern "C" void kernel_launch(void* const* d_in, const int* in_sizes, int n_in,
                              void* d_out, int out_size, void* d_ws, size_t ws_size,
                              hipStream_t stream)
{
    (void)in_sizes; (void)n_in; (void)out_size; (void)ws_size;

    const float* x       = (const float*)d_in[0];
    const float* emb_w   = (const float*)d_in[1];
    const float* emb_b   = (const float*)d_in[2];
    const float* norm_g  = (const float*)d_in[3];
    const float* norm_b  = (const float*)d_in[4];
    const float* in_w    = (const float*)d_in[5];
    const float* conv_w  = (const float*)d_in[6];
    const float* A_p     = (const float*)d_in[7];
    const float* D_p     = (const float*)d_in[8];
    const float* dt1_w   = (const float*)d_in[9];
    const float* dt1_b   = (const float*)d_in[10];
    const float* dt2_w   = (const float*)d_in[11];
    const float* dt2_b   = (const float*)d_in[12];
    const float* out_w   = (const float*)d_in[13];
    const float* final_g = (const float*)d_in[14];
    const float* final_b = (const float*)d_in[15];
    const float* head1_w = (const float*)d_in[16];
    const float* head1_b = (const float*)d_in[17];
    const float* head2_w = (const float*)d_in[18];
    const float* head2_b = (const float*)d_in[19];
    float* outp = (float*)d_out;

    float* ws  = (float*)d_ws;
    float* h   = ws;                         // 8192*256   = 2,097,152
    float* v   = h  + (size_t)MM * DD;       // 8192*512   = 4,194,304  (reused as dtf)
    float* vsb = v  + (size_t)MM * HH;       // 8192*512
    float* yb  = vsb + (size_t)MM * HH;      // 8192*512   (LN buffer, then y)
    float* dtr = yb + (size_t)MM * HH;       // 8192*8

    embed_kernel<<<MM, 256, 0, stream>>>(x, emb_w, emb_b, h);

    for (int l = 0; l < 4; l++) {
        ln_kernel<<<MM, 256, 0, stream>>>(h, norm_g + l * DD, norm_b + l * DD, yb);
        gemm_nt<128, 64, 8, 4><<<dim3(HH / 64, MM / 128), 256, 0, stream>>>(
            yb, in_w + (size_t)l * HH * DD, v, MM, HH, DD, 0);
        conv_silu_kernel<<<(MM * HH) / 256, 256, 0, stream>>>(
            v, conv_w + (size_t)l * HH * 3, vsb);
        dt1_kernel<<<MM / 4, 256, 0, stream>>>(
            vsb, dt1_w + (size_t)l * RR * HH, dt1_b + l * RR, dtr);
        dt2_kernel<<<(MM * HH) / 256, 256, 0, stream>>>(
            dtr, dt2_w + (size_t)l * HH * RR, dt2_b + l * HH, v /*dtf*/);
        scan_kernel<<<dim3(HH / 16, BB), 256, 0, stream>>>(
            vsb, v, A_p + (size_t)l * HH * NN, D_p + l * HH, yb);
        gemm_nt<64, 64, 4, 4><<<dim3(DD / 64, MM / 64), 256, 0, stream>>>(
            yb, out_w + (size_t)l * DD * HH, h, MM, DD, HH, 1);
    }

    head_kernel<<<BB, 256, 0, stream>>>(h, final_g, final_b,
                                        head1_w, head1_b, head2_w, head2_b, outp);
}

// Round 2
// 999.622 us; speedup vs baseline: 1.4284x; 1.4284x over previous
//
#include <hip/hip_runtime.h>
#include <hip/hip_bf16.h>
#include <math.h>

// Model dims
#define BB 8
#define TT 1024
#define DD 256
#define HH 512
#define NN 16
#define RR 8
#define OUT_LEN 96
#define IN_DIM 32
#define MM (BB*TT)   // 8192 rows

// scan chunking
#define SC 128
#define CC (TT/SC)   // 8
static_assert(CC == 8, "carry kernel assumes 8 chunks");

// ---------------------------------------------------------------------------
// Embedding + positional encoding
// ---------------------------------------------------------------------------
__global__ __launch_bounds__(256) void embed_kernel(
    const float* __restrict__ x, const float* __restrict__ emb_w,
    const float* __restrict__ emb_b, float* __restrict__ h)
{
    int bt = blockIdx.x;           // 0..8191
    int d  = threadIdx.x;          // 0..255
    int t  = bt & (TT - 1);

    __shared__ float xs[IN_DIM];
    if (threadIdx.x < IN_DIM) xs[threadIdx.x] = x[bt * IN_DIM + threadIdx.x];
    __syncthreads();

    const float* w = emb_w + d * IN_DIM;
    float acc = emb_b[d];
#pragma unroll
    for (int i = 0; i < IN_DIM; i++) acc = fmaf(xs[i], w[i], acc);

    int i2 = d & ~1;  // 2*i
    float div = expf(-(float)i2 * (logf(10000.0f) / (float)DD));
    float arg = (float)t * div;
    float pe = (d & 1) ? cosf(arg) : sinf(arg);
    h[bt * DD + d] = acc + pe;
}

// ---------------------------------------------------------------------------
// LayerNorm over D=256, one block per (b,t) row
// ---------------------------------------------------------------------------
__global__ __launch_bounds__(256) void ln_kernel(
    const float* __restrict__ h, const float* __restrict__ g,
    const float* __restrict__ b, float* __restrict__ out)
{
    int bt = blockIdx.x;
    int d  = threadIdx.x;
    float v = h[bt * DD + d];

    __shared__ float red[4], red2[4];
    float s = v;
#pragma unroll
    for (int o = 32; o > 0; o >>= 1) s += __shfl_down(s, o);
    int lane = d & 63, wave = d >> 6;
    if (lane == 0) red[wave] = s;
    __syncthreads();
    float mean = (red[0] + red[1] + red[2] + red[3]) * (1.0f / DD);

    float c = v - mean;
    float s2 = c * c;
#pragma unroll
    for (int o = 32; o > 0; o >>= 1) s2 += __shfl_down(s2, o);
    if (lane == 0) red2[wave] = s2;
    __syncthreads();
    float var = (red2[0] + red2[1] + red2[2] + red2[3]) * (1.0f / DD);

    out[bt * DD + d] = c * rsqrtf(var + 1e-5f) * g[d] + b[d];
}

// ---------------------------------------------------------------------------
// fp32 NT GEMM: C[m,n] = sum_k A[m,k] * B[n,k]; optional C += (addC)
// ---------------------------------------------------------------------------
template<int BM, int BN, int TM, int TN>
__global__ __launch_bounds__(256) void gemm_nt(
    const float* __restrict__ A, const float* __restrict__ B,
    float* __restrict__ C, int M, int N, int K, int addC)
{
    constexpr int BK = 16;
    __shared__ __align__(16) float As[BK][BM + 4];
    __shared__ __align__(16) float Bs[BK][BN + 4];

    const int tid = threadIdx.x;
    const int bm = blockIdx.y * BM;
    const int bn = blockIdx.x * BN;
    constexpr int TX = BN / TN;
    const int tx = tid % TX;
    const int ty = tid / TX;

    float acc[TM][TN];
#pragma unroll
    for (int i = 0; i < TM; i++)
#pragma unroll
        for (int j = 0; j < TN; j++) acc[i][j] = 0.0f;

    const int arow = tid >> 2;
    const int acol = (tid & 3) << 2;
    const float* Ag = A + (size_t)(bm + arow) * K + acol;
    const float* Bg = B + (size_t)(bn + arow) * K + acol;   // BN==64 assumed

    for (int k0 = 0; k0 < K; k0 += BK) {
#pragma unroll
        for (int j = 0; j < BM / 64; j++) {
            float4 av = *(const float4*)(Ag + (size_t)j * 64 * K + k0);
            As[acol + 0][arow + j * 64] = av.x;
            As[acol + 1][arow + j * 64] = av.y;
            As[acol + 2][arow + j * 64] = av.z;
            As[acol + 3][arow + j * 64] = av.w;
        }
        {
            float4 bv = *(const float4*)(Bg + k0);
            Bs[acol + 0][arow] = bv.x;
            Bs[acol + 1][arow] = bv.y;
            Bs[acol + 2][arow] = bv.z;
            Bs[acol + 3][arow] = bv.w;
        }
        __syncthreads();
#pragma unroll
        for (int kk = 0; kk < BK; kk++) {
            float a[TM], bb[TN];
#pragma unroll
            for (int i = 0; i < TM; i += 4) {
                float4 t4 = *(const float4*)&As[kk][ty * TM + i];
                a[i] = t4.x; a[i + 1] = t4.y; a[i + 2] = t4.z; a[i + 3] = t4.w;
            }
#pragma unroll
            for (int j = 0; j < TN; j += 4) {
                float4 t4 = *(const float4*)&Bs[kk][tx * TN + j];
                bb[j] = t4.x; bb[j + 1] = t4.y; bb[j + 2] = t4.z; bb[j + 3] = t4.w;
            }
#pragma unroll
            for (int i = 0; i < TM; i++)
#pragma unroll
                for (int j = 0; j < TN; j++)
                    acc[i][j] = fmaf(a[i], bb[j], acc[i][j]);
        }
        __syncthreads();
    }

#pragma unroll
    for (int i = 0; i < TM; i++) {
        float* Cp = C + (size_t)(bm + ty * TM + i) * N + bn + tx * TN;
#pragma unroll
        for (int j = 0; j < TN; j += 4) {
            float4 cv;
            cv.x = acc[i][j]; cv.y = acc[i][j + 1];
            cv.z = acc[i][j + 2]; cv.w = acc[i][j + 3];
            if (addC) {
                float4 old = *(const float4*)(Cp + j);
                cv.x += old.x; cv.y += old.y; cv.z += old.z; cv.w += old.w;
            }
            *(float4*)(Cp + j) = cv;
        }
    }
}

// ---------------------------------------------------------------------------
// Depthwise conv (k=3, pad 1) over time + SiLU; (B,T,H) layout
// ---------------------------------------------------------------------------
__global__ __launch_bounds__(256) void conv_silu_kernel(
    const float* __restrict__ v, const float* __restrict__ w,
    float* __restrict__ out)
{
    int idx = blockIdx.x * 256 + threadIdx.x;   // B*T*H
    int h = idx & (HH - 1);
    int t = (idx >> 9) & (TT - 1);
    const float* wp = w + h * 3;
    float acc = wp[1] * v[idx];
    if (t > 0)      acc = fmaf(wp[0], v[idx - HH], acc);
    if (t < TT - 1) acc = fmaf(wp[2], v[idx + HH], acc);
    out[idx] = acc / (1.0f + __expf(-acc));   // silu
}

// ---------------------------------------------------------------------------
// dt1: dtr[m,r] = relu(vs[m,:] . dt1_w[r,:] + dt1_b[r]); one wave per m
// ---------------------------------------------------------------------------
__global__ __launch_bounds__(256) void dt1_kernel(
    const float* __restrict__ vs, const float* __restrict__ w,
    const float* __restrict__ bias, float* __restrict__ dtr)
{
    int wave = threadIdx.x >> 6;
    int lane = threadIdx.x & 63;
    int m = blockIdx.x * 4 + wave;
    const float* vrow = vs + (size_t)m * HH;

    float acc[RR];
#pragma unroll
    for (int r = 0; r < RR; r++) acc[r] = 0.0f;

#pragma unroll
    for (int j = 0; j < HH / 64; j++) {
        int hh = lane + j * 64;
        float vv = vrow[hh];
#pragma unroll
        for (int r = 0; r < RR; r++) acc[r] = fmaf(vv, w[r * HH + hh], acc[r]);
    }
#pragma unroll
    for (int r = 0; r < RR; r++) {
#pragma unroll
        for (int o = 32; o > 0; o >>= 1) acc[r] += __shfl_down(acc[r], o);
    }
    if (lane == 0) {
#pragma unroll
        for (int r = 0; r < RR; r++)
            dtr[m * RR + r] = fmaxf(acc[r] + bias[r], 0.0f);
    }
}

// ---------------------------------------------------------------------------
// dt2 + softplus
// ---------------------------------------------------------------------------
__global__ __launch_bounds__(256) void dt2_kernel(
    const float* __restrict__ dtr, const float* __restrict__ w,
    const float* __restrict__ bias, float* __restrict__ out)
{
    int idx = blockIdx.x * 256 + threadIdx.x;  // M*H
    int h = idx & (HH - 1);
    int m = idx >> 9;
    const float* dr = dtr + m * RR;
    const float* wr = w + h * RR;
    float acc = bias[h];
#pragma unroll
    for (int r = 0; r < RR; r++) acc = fmaf(dr[r], wr[r], acc);
    out[idx] = (acc > 20.0f) ? acc : log1pf(__expf(acc));
}

// ---------------------------------------------------------------------------
// Chunk-parallel selective scan.
// Recurrence state_t = a_t*state + b_t is associative; split T into CC chunks
// of SC steps. pass1: local scan from 0 → (prod a, end state) per chunk.
// carry: serial combine over CC chunks per (b,h,n), write carry-in in place.
// pass2: re-run local scan seeded with carry; n-reduce; coalesced y store.
// ---------------------------------------------------------------------------
__global__ __launch_bounds__(256) void scan_pass1(
    const float* __restrict__ vs,    // (B,T,H)
    const float* __restrict__ dtf,   // (B,T,H)
    const float* __restrict__ A_p,   // (H,N)
    float* __restrict__ aA,          // (B,H,N,CC)
    float* __restrict__ bB)          // (B,H,N,CC)
{
    int hg = blockIdx.x;             // 0..HH/16-1
    int c  = blockIdx.y;             // 0..CC-1
    int b  = blockIdx.z;
    int tid = threadIdx.x;
    int hs = tid >> 4, n = tid & 15;
    int h = hg * 16 + hs;

    __shared__ float xs[16][SC + 1];
    __shared__ float ds[16][SC + 1];

    const float* vbase = vs  + ((size_t)b * TT + (size_t)c * SC) * HH + hg * 16;
    const float* dbase = dtf + ((size_t)b * TT + (size_t)c * SC) * HH + hg * 16;

    int lh = tid & 15, lt = tid >> 4;
#pragma unroll
    for (int j = 0; j < SC / 16; j++) {
        int t = lt + j * 16;
        xs[lh][t] = vbase[(size_t)t * HH + lh];
        ds[lh][t] = dbase[(size_t)t * HH + lh];
    }
    __syncthreads();

    float Ap = A_p[h * NN + n];
    float A  = -__expf(Ap);
    float invA = 1.0f / A;

    float state = 0.0f, aprod = 1.0f;
#pragma unroll 8
    for (int t = 0; t < SC; t++) {
        float dt = ds[hs][t], xv = xs[hs][t];
        float e = __expf(A * dt);
        float dB = (e - 1.0f) * invA * dt;
        state = fmaf(e, state, dB * xv);
        aprod *= e;
    }
    size_t idx = (((size_t)b * HH + h) * NN + n) * CC + c;
    aA[idx] = aprod;
    bB[idx] = state;
}

__global__ __launch_bounds__(256) void scan_carry(
    const float* __restrict__ aA, float* __restrict__ bB)
{
    size_t i = (size_t)blockIdx.x * 256 + threadIdx.x;   // (b*HH+h)*NN+n
    const float4 a0 = *(const float4*)(aA + i * CC);
    const float4 a1 = *(const float4*)(aA + i * CC + 4);
    const float4 b0 = *(const float4*)(bB + i * CC);
    const float4 b1 = *(const float4*)(bB + i * CC + 4);
    float a[8]  = {a0.x, a0.y, a0.z, a0.w, a1.x, a1.y, a1.z, a1.w};
    float bb[8] = {b0.x, b0.y, b0.z, b0.w, b1.x, b1.y, b1.z, b1.w};
    float s = 0.0f, cr[8];
#pragma unroll
    for (int c = 0; c < 8; c++) { cr[c] = s; s = fmaf(a[c], s, bb[c]); }
    *(float4*)(bB + i * CC)     = make_float4(cr[0], cr[1], cr[2], cr[3]);
    *(float4*)(bB + i * CC + 4) = make_float4(cr[4], cr[5], cr[6], cr[7]);
}

__global__ __launch_bounds__(256) void scan_pass2(
    const float* __restrict__ vs, const float* __restrict__ dtf,
    const float* __restrict__ A_p, const float* __restrict__ D_p,
    const float* __restrict__ carry,   // (B,H,N,CC) carry-in states
    float* __restrict__ y)             // (B,T,H)
{
    int hg = blockIdx.x;
    int c  = blockIdx.y;
    int b  = blockIdx.z;
    int tid = threadIdx.x;
    int hs = tid >> 4, n = tid & 15;
    int h = hg * 16 + hs;

    __shared__ float xs[16][SC + 1];
    __shared__ float ds[16][SC + 1];
    __shared__ float ys[16][SC + 1];

    const float* vbase = vs  + ((size_t)b * TT + (size_t)c * SC) * HH + hg * 16;
    const float* dbase = dtf + ((size_t)b * TT + (size_t)c * SC) * HH + hg * 16;
    float*       ybase = y   + ((size_t)b * TT + (size_t)c * SC) * HH + hg * 16;

    int lh = tid & 15, lt = tid >> 4;
#pragma unroll
    for (int j = 0; j < SC / 16; j++) {
        int t = lt + j * 16;
        xs[lh][t] = vbase[(size_t)t * HH + lh];
        ds[lh][t] = dbase[(size_t)t * HH + lh];
    }
    __syncthreads();

    float Ap = A_p[h * NN + n];
    float A  = -__expf(Ap);
    float invA = 1.0f / A;
    float Dp = D_p[h];

    size_t idx = (((size_t)b * HH + h) * NN + n) * CC + c;
    float state = carry[idx];

#pragma unroll 4
    for (int t = 0; t < SC; t++) {
        float dt = ds[hs][t], xv = xs[hs][t];
        float e = __expf(A * dt);
        float dB = (e - 1.0f) * invA * dt;
        state = fmaf(e, state, dB * xv);
        float contrib = state * Ap;
        contrib += __shfl_xor(contrib, 1);
        contrib += __shfl_xor(contrib, 2);
        contrib += __shfl_xor(contrib, 4);
        contrib += __shfl_xor(contrib, 8);
        if (n == 0) ys[hs][t] = fmaf(Dp, xv, contrib);
    }
    __syncthreads();

#pragma unroll
    for (int j = 0; j < SC / 16; j++) {
        int t = lt + j * 16;
        ybase[(size_t)t * HH + lh] = ys[lh][t];
    }
}

// ---------------------------------------------------------------------------
// Head: final LN on last token, head1+silu, head2. One block per batch.
// ---------------------------------------------------------------------------
__global__ __launch_bounds__(256) void head_kernel(
    const float* __restrict__ h,
    const float* __restrict__ fg, const float* __restrict__ fb,
    const float* __restrict__ w1, const float* __restrict__ b1,
    const float* __restrict__ w2, const float* __restrict__ b2,
    float* __restrict__ out)
{
    int b = blockIdx.x;
    int d = threadIdx.x;
    __shared__ float hn[DD], s1[DD];
    __shared__ float red[4];

    float v = h[((size_t)b * TT + (TT - 1)) * DD + d];

    float s = v;
#pragma unroll
    for (int o = 32; o > 0; o >>= 1) s += __shfl_down(s, o);
    int lane = d & 63, wave = d >> 6;
    if (lane == 0) red[wave] = s;
    __syncthreads();
    float mean = (red[0] + red[1] + red[2] + red[3]) * (1.0f / DD);
    __syncthreads();

    float c = v - mean;
    float s2 = c * c;
#pragma unroll
    for (int o = 32; o > 0; o >>= 1) s2 += __shfl_down(s2, o);
    if (lane == 0) red[wave] = s2;
    __syncthreads();
    float var = (red[0] + red[1] + red[2] + red[3]) * (1.0f / DD);

    hn[d] = c * rsqrtf(var + 1e-5f) * fg[d] + fb[d];
    __syncthreads();

    float a1 = b1[d];
    const float* w1r = w1 + d * DD;
#pragma unroll 8
    for (int k = 0; k < DD; k++) a1 = fmaf(hn[k], w1r[k], a1);
    s1[d] = a1 / (1.0f + __expf(-a1));
    __syncthreads();

    if (d < OUT_LEN) {
        float a2 = b2[d];
        const float* w2r = w2 + d * DD;
#pragma unroll 8
        for (int k = 0; k < DD; k++) a2 = fmaf(s1[k], w2r[k], a2);
        out[b * OUT_LEN + d] = a2;
    }
}

// ---------------------------------------------------------------------------
extern "C" void kernel_launch(void* const* d_in, const int* in_sizes, int n_in,
                              void* d_out, int out_size, void* d_ws, size_t ws_size,
                              hipStream_t stream)
{
    (void)in_sizes; (void)n_in; (void)out_size; (void)ws_size;

    const float* x       = (const float*)d_in[0];
    const float* emb_w   = (const float*)d_in[1];
    const float* emb_b   = (const float*)d_in[2];
    const float* norm_g  = (const float*)d_in[3];
    const float* norm_b  = (const float*)d_in[4];
    const float* in_w    = (const float*)d_in[5];
    const float* conv_w  = (const float*)d_in[6];
    const float* A_p     = (const float*)d_in[7];
    const float* D_p     = (const float*)d_in[8];
    const float* dt1_w   = (const float*)d_in[9];
    const float* dt1_b   = (const float*)d_in[10];
    const float* dt2_w   = (const float*)d_in[11];
    const float* dt2_b   = (const float*)d_in[12];
    const float* out_w   = (const float*)d_in[13];
    const float* final_g = (const float*)d_in[14];
    const float* final_b = (const float*)d_in[15];
    const float* head1_w = (const float*)d_in[16];
    const float* head1_b = (const float*)d_in[17];
    const float* head2_w = (const float*)d_in[18];
    const float* head2_b = (const float*)d_in[19];
    float* outp = (float*)d_out;

    float* ws  = (float*)d_ws;
    float* h   = ws;                         // MM*DD
    float* v   = h   + (size_t)MM * DD;      // MM*HH (v, then dtf)
    float* vsb = v   + (size_t)MM * HH;      // MM*HH (conv+silu out)
    float* yb  = vsb + (size_t)MM * HH;      // MM*HH (LN buffer, then y)
    float* dtr = yb  + (size_t)MM * HH;      // MM*RR
    float* aA  = dtr + (size_t)MM * RR;      // B*H*N*CC = 524288
    float* bB  = aA  + (size_t)BB * HH * NN * CC;

    embed_kernel<<<MM, 256, 0, stream>>>(x, emb_w, emb_b, h);

    for (int l = 0; l < 4; l++) {
        ln_kernel<<<MM, 256, 0, stream>>>(h, norm_g + l * DD, norm_b + l * DD, yb);
        gemm_nt<128, 64, 8, 4><<<dim3(HH / 64, MM / 128), 256, 0, stream>>>(
            yb, in_w + (size_t)l * HH * DD, v, MM, HH, DD, 0);
        conv_silu_kernel<<<(MM * HH) / 256, 256, 0, stream>>>(
            v, conv_w + (size_t)l * HH * 3, vsb);
        dt1_kernel<<<MM / 4, 256, 0, stream>>>(
            vsb, dt1_w + (size_t)l * RR * HH, dt1_b + l * RR, dtr);
        dt2_kernel<<<(MM * HH) / 256, 256, 0, stream>>>(
            dtr, dt2_w + (size_t)l * HH * RR, dt2_b + l * HH, v /*dtf*/);

        scan_pass1<<<dim3(HH / 16, CC, BB), 256, 0, stream>>>(
            vsb, v, A_p + (size_t)l * HH * NN, aA, bB);
        scan_carry<<<(BB * HH * NN) / 256, 256, 0, stream>>>(aA, bB);
        scan_pass2<<<dim3(HH / 16, CC, BB), 256, 0, stream>>>(
            vsb, v, A_p + (size_t)l * HH * NN, D_p + l * HH, bB, yb);

        gemm_nt<64, 64, 4, 4><<<dim3(DD / 64, MM / 64), 256, 0, stream>>>(
            yb, out_w + (size_t)l * DD * HH, h, MM, DD, HH, 1);
    }

    head_kernel<<<BB, 256, 0, stream>>>(h, final_g, final_b,
                                        head1_w, head1_b, head2_w, head2_b, outp);
}

// Round 3
// 887.251 us; speedup vs baseline: 1.6093x; 1.1267x over previous
//
#include <hip/hip_runtime.h>
#include <hip/hip_bf16.h>
#include <math.h>

// Model dims
#define BB 8
#define TT 1024
#define DD 256
#define HH 512
#define NN 16
#define RR 8
#define OUT_LEN 96
#define IN_DIM 32
#define MM (BB*TT)   // 8192 rows

// scan chunking: CC chunks of SC steps; one thread per (b,h,chunk), all N
// states in registers (no shuffles, no LDS).
#define SC 64
#define CC (TT/SC)   // 16

// ---------------------------------------------------------------------------
// Embedding + positional encoding
// ---------------------------------------------------------------------------
__global__ __launch_bounds__(256) void embed_kernel(
    const float* __restrict__ x, const float* __restrict__ emb_w,
    const float* __restrict__ emb_b, float* __restrict__ h)
{
    int bt = blockIdx.x;           // 0..8191
    int d  = threadIdx.x;          // 0..255
    int t  = bt & (TT - 1);

    __shared__ float xs[IN_DIM];
    if (threadIdx.x < IN_DIM) xs[threadIdx.x] = x[bt * IN_DIM + threadIdx.x];
    __syncthreads();

    const float* w = emb_w + d * IN_DIM;
    float acc = emb_b[d];
#pragma unroll
    for (int i = 0; i < IN_DIM; i++) acc = fmaf(xs[i], w[i], acc);

    int i2 = d & ~1;  // 2*i
    float div = expf(-(float)i2 * (logf(10000.0f) / (float)DD));
    float arg = (float)t * div;
    float pe = (d & 1) ? cosf(arg) : sinf(arg);
    h[bt * DD + d] = acc + pe;
}

// ---------------------------------------------------------------------------
// LayerNorm over D=256, one block per (b,t) row
// ---------------------------------------------------------------------------
__global__ __launch_bounds__(256) void ln_kernel(
    const float* __restrict__ h, const float* __restrict__ g,
    const float* __restrict__ b, float* __restrict__ out)
{
    int bt = blockIdx.x;
    int d  = threadIdx.x;
    float v = h[bt * DD + d];

    __shared__ float red[4], red2[4];
    float s = v;
#pragma unroll
    for (int o = 32; o > 0; o >>= 1) s += __shfl_down(s, o);
    int lane = d & 63, wave = d >> 6;
    if (lane == 0) red[wave] = s;
    __syncthreads();
    float mean = (red[0] + red[1] + red[2] + red[3]) * (1.0f / DD);

    float c = v - mean;
    float s2 = c * c;
#pragma unroll
    for (int o = 32; o > 0; o >>= 1) s2 += __shfl_down(s2, o);
    if (lane == 0) red2[wave] = s2;
    __syncthreads();
    float var = (red2[0] + red2[1] + red2[2] + red2[3]) * (1.0f / DD);

    out[bt * DD + d] = c * rsqrtf(var + 1e-5f) * g[d] + b[d];
}

// ---------------------------------------------------------------------------
// fp32 NT GEMM: C[m,n] = sum_k A[m,k] * B[n,k]; optional C += (addC)
// ---------------------------------------------------------------------------
template<int BM, int BN, int TM, int TN>
__global__ __launch_bounds__(256) void gemm_nt(
    const float* __restrict__ A, const float* __restrict__ B,
    float* __restrict__ C, int M, int N, int K, int addC)
{
    constexpr int BK = 16;
    __shared__ __align__(16) float As[BK][BM + 4];
    __shared__ __align__(16) float Bs[BK][BN + 4];

    const int tid = threadIdx.x;
    const int bm = blockIdx.y * BM;
    const int bn = blockIdx.x * BN;
    constexpr int TX = BN / TN;
    const int tx = tid % TX;
    const int ty = tid / TX;

    float acc[TM][TN];
#pragma unroll
    for (int i = 0; i < TM; i++)
#pragma unroll
        for (int j = 0; j < TN; j++) acc[i][j] = 0.0f;

    const int arow = tid >> 2;
    const int acol = (tid & 3) << 2;
    const float* Ag = A + (size_t)(bm + arow) * K + acol;
    const float* Bg = B + (size_t)(bn + arow) * K + acol;   // BN==64 assumed

    for (int k0 = 0; k0 < K; k0 += BK) {
#pragma unroll
        for (int j = 0; j < BM / 64; j++) {
            float4 av = *(const float4*)(Ag + (size_t)j * 64 * K + k0);
            As[acol + 0][arow + j * 64] = av.x;
            As[acol + 1][arow + j * 64] = av.y;
            As[acol + 2][arow + j * 64] = av.z;
            As[acol + 3][arow + j * 64] = av.w;
        }
        {
            float4 bv = *(const float4*)(Bg + k0);
            Bs[acol + 0][arow] = bv.x;
            Bs[acol + 1][arow] = bv.y;
            Bs[acol + 2][arow] = bv.z;
            Bs[acol + 3][arow] = bv.w;
        }
        __syncthreads();
#pragma unroll
        for (int kk = 0; kk < BK; kk++) {
            float a[TM], bb[TN];
#pragma unroll
            for (int i = 0; i < TM; i += 4) {
                float4 t4 = *(const float4*)&As[kk][ty * TM + i];
                a[i] = t4.x; a[i + 1] = t4.y; a[i + 2] = t4.z; a[i + 3] = t4.w;
            }
#pragma unroll
            for (int j = 0; j < TN; j += 4) {
                float4 t4 = *(const float4*)&Bs[kk][tx * TN + j];
                bb[j] = t4.x; bb[j + 1] = t4.y; bb[j + 2] = t4.z; bb[j + 3] = t4.w;
            }
#pragma unroll
            for (int i = 0; i < TM; i++)
#pragma unroll
                for (int j = 0; j < TN; j++)
                    acc[i][j] = fmaf(a[i], bb[j], acc[i][j]);
        }
        __syncthreads();
    }

#pragma unroll
    for (int i = 0; i < TM; i++) {
        float* Cp = C + (size_t)(bm + ty * TM + i) * N + bn + tx * TN;
#pragma unroll
        for (int j = 0; j < TN; j += 4) {
            float4 cv;
            cv.x = acc[i][j]; cv.y = acc[i][j + 1];
            cv.z = acc[i][j + 2]; cv.w = acc[i][j + 3];
            if (addC) {
                float4 old = *(const float4*)(Cp + j);
                cv.x += old.x; cv.y += old.y; cv.z += old.z; cv.w += old.w;
            }
            *(float4*)(Cp + j) = cv;
        }
    }
}

// ---------------------------------------------------------------------------
// Depthwise conv (k=3, pad 1) over time + SiLU; (B,T,H) layout
// ---------------------------------------------------------------------------
__global__ __launch_bounds__(256) void conv_silu_kernel(
    const float* __restrict__ v, const float* __restrict__ w,
    float* __restrict__ out)
{
    int idx = blockIdx.x * 256 + threadIdx.x;   // B*T*H
    int h = idx & (HH - 1);
    int t = (idx >> 9) & (TT - 1);
    const float* wp = w + h * 3;
    float acc = wp[1] * v[idx];
    if (t > 0)      acc = fmaf(wp[0], v[idx - HH], acc);
    if (t < TT - 1) acc = fmaf(wp[2], v[idx + HH], acc);
    out[idx] = acc / (1.0f + __expf(-acc));   // silu
}

// ---------------------------------------------------------------------------
// dt1: dtr[m,r] = relu(vs[m,:] . dt1_w[r,:] + dt1_b[r]); one wave per m
// ---------------------------------------------------------------------------
__global__ __launch_bounds__(256) void dt1_kernel(
    const float* __restrict__ vs, const float* __restrict__ w,
    const float* __restrict__ bias, float* __restrict__ dtr)
{
    int wave = threadIdx.x >> 6;
    int lane = threadIdx.x & 63;
    int m = blockIdx.x * 4 + wave;
    const float* vrow = vs + (size_t)m * HH;

    float acc[RR];
#pragma unroll
    for (int r = 0; r < RR; r++) acc[r] = 0.0f;

#pragma unroll
    for (int j = 0; j < HH / 64; j++) {
        int hh = lane + j * 64;
        float vv = vrow[hh];
#pragma unroll
        for (int r = 0; r < RR; r++) acc[r] = fmaf(vv, w[r * HH + hh], acc[r]);
    }
#pragma unroll
    for (int r = 0; r < RR; r++) {
#pragma unroll
        for (int o = 32; o > 0; o >>= 1) acc[r] += __shfl_down(acc[r], o);
    }
    if (lane == 0) {
#pragma unroll
        for (int r = 0; r < RR; r++)
            dtr[m * RR + r] = fmaxf(acc[r] + bias[r], 0.0f);
    }
}

// ---------------------------------------------------------------------------
// dt2 + softplus
// ---------------------------------------------------------------------------
__global__ __launch_bounds__(256) void dt2_kernel(
    const float* __restrict__ dtr, const float* __restrict__ w,
    const float* __restrict__ bias, float* __restrict__ out)
{
    int idx = blockIdx.x * 256 + threadIdx.x;  // M*H
    int h = idx & (HH - 1);
    int m = idx >> 9;
    const float* dr = dtr + m * RR;
    const float* wr = w + h * RR;
    float acc = bias[h];
#pragma unroll
    for (int r = 0; r < RR; r++) acc = fmaf(dr[r], wr[r], acc);
    out[idx] = (acc > 20.0f) ? acc : log1pf(__expf(acc));
}

// ---------------------------------------------------------------------------
// Chunk-parallel selective scan, register-state version.
// Thread = (b, h, chunk); all N=16 states live in registers.
//   pass1: local scan from 0 → end-states L (CC,B,H,N) and sum_dt (CC,B,H).
//          (prod_t exp(A dt_t) == exp(A * sum_dt) — recomputed in carry.)
//   carry: per (b,h,n): E=0; for c: carry[c]=E; E = L_c + exp(A*sdt_c)*E.
//   pass2: re-run local scan seeded with carry; y = Dp*x + sum_n st_n*Ap_n
//          entirely in registers; coalesced y store.
// ---------------------------------------------------------------------------
__global__ __launch_bounds__(256) void scan_pass1(
    const float* __restrict__ vs,    // (B,T,H)
    const float* __restrict__ dtf,   // (B,T,H)
    const float* __restrict__ A_p,   // (H,N)
    float* __restrict__ Lst,         // (CC,B,H,N) local end states
    float* __restrict__ sdt)         // (CC,B,H)   per-chunk sum of dt
{
    int h = blockIdx.x * 256 + threadIdx.x;   // grid.x = HH/256
    int c = blockIdx.y;
    int b = blockIdx.z;

    float A[NN], invA[NN], st[NN];
    const float* ap = A_p + h * NN;
#pragma unroll
    for (int n = 0; n < NN; n++) {
        float a = -__expf(ap[n]);
        A[n] = a; invA[n] = 1.0f / a; st[n] = 0.0f;
    }

    const float* vbase = vs  + ((size_t)b * TT + (size_t)c * SC) * HH + h;
    const float* dbase = dtf + ((size_t)b * TT + (size_t)c * SC) * HH + h;

    float s_dt = 0.0f;
#pragma unroll 4
    for (int t = 0; t < SC; t++) {
        float dt = dbase[(size_t)t * HH];
        float xv = vbase[(size_t)t * HH];
        s_dt += dt;
#pragma unroll
        for (int n = 0; n < NN; n++) {
            float e  = __expf(A[n] * dt);
            float dB = (e - 1.0f) * invA[n] * dt;
            st[n] = fmaf(e, st[n], dB * xv);
        }
    }

    size_t base = (((size_t)c * BB + b) * HH + h) * NN;
#pragma unroll
    for (int n = 0; n < NN; n += 4)
        *(float4*)(Lst + base + n) = make_float4(st[n], st[n+1], st[n+2], st[n+3]);
    sdt[((size_t)c * BB + b) * HH + h] = s_dt;
}

__global__ __launch_bounds__(256) void scan_carry(
    const float* __restrict__ A_p, const float* __restrict__ sdt,
    float* __restrict__ Lst)   // in: local ends; out: carry-in states
{
    int i = blockIdx.x * 256 + threadIdx.x;   // (b*HH+h)*NN+n, B*H*N total
    int n  = i & (NN - 1);
    int bh = i >> 4;
    int h  = bh & (HH - 1);
    int b  = bh >> 9;

    float A = -__expf(A_p[h * NN + n]);
    float E = 0.0f;
#pragma unroll
    for (int c = 0; c < CC; c++) {
        size_t sidx = ((size_t)c * BB + b) * HH + h;
        float P = __expf(A * sdt[sidx]);
        size_t lidx = sidx * NN + n;
        float Lc = Lst[lidx];
        Lst[lidx] = E;            // carry-in for chunk c
        E = fmaf(P, E, Lc);
    }
}

__global__ __launch_bounds__(256) void scan_pass2(
    const float* __restrict__ vs, const float* __restrict__ dtf,
    const float* __restrict__ A_p, const float* __restrict__ D_p,
    const float* __restrict__ carry,   // (CC,B,H,N) carry-in states
    float* __restrict__ y)             // (B,T,H)
{
    int h = blockIdx.x * 256 + threadIdx.x;
    int c = blockIdx.y;
    int b = blockIdx.z;

    float A[NN], invA[NN], Ap[NN], st[NN];
    const float* app = A_p + h * NN;
    size_t cbase = (((size_t)c * BB + b) * HH + h) * NN;
#pragma unroll
    for (int n = 0; n < NN; n += 4) {
        float4 c4 = *(const float4*)(carry + cbase + n);
        st[n] = c4.x; st[n+1] = c4.y; st[n+2] = c4.z; st[n+3] = c4.w;
    }
#pragma unroll
    for (int n = 0; n < NN; n++) {
        float apv = app[n];
        Ap[n] = apv;
        float a = -__expf(apv);
        A[n] = a; invA[n] = 1.0f / a;
    }
    float Dp = D_p[h];

    const float* vbase = vs  + ((size_t)b * TT + (size_t)c * SC) * HH + h;
    const float* dbase = dtf + ((size_t)b * TT + (size_t)c * SC) * HH + h;
    float*       ybase = y   + ((size_t)b * TT + (size_t)c * SC) * HH + h;

#pragma unroll 2
    for (int t = 0; t < SC; t++) {
        float dt = dbase[(size_t)t * HH];
        float xv = vbase[(size_t)t * HH];
        float acc = Dp * xv;
#pragma unroll
        for (int n = 0; n < NN; n++) {
            float e  = __expf(A[n] * dt);
            float dB = (e - 1.0f) * invA[n] * dt;
            st[n] = fmaf(e, st[n], dB * xv);
            acc = fmaf(st[n], Ap[n], acc);
        }
        ybase[(size_t)t * HH] = acc;
    }
}

// ---------------------------------------------------------------------------
// Head: final LN on last token, head1+silu, head2. One block per batch.
// ---------------------------------------------------------------------------
__global__ __launch_bounds__(256) void head_kernel(
    const float* __restrict__ h,
    const float* __restrict__ fg, const float* __restrict__ fb,
    const float* __restrict__ w1, const float* __restrict__ b1,
    const float* __restrict__ w2, const float* __restrict__ b2,
    float* __restrict__ out)
{
    int b = blockIdx.x;
    int d = threadIdx.x;
    __shared__ float hn[DD], s1[DD];
    __shared__ float red[4];

    float v = h[((size_t)b * TT + (TT - 1)) * DD + d];

    float s = v;
#pragma unroll
    for (int o = 32; o > 0; o >>= 1) s += __shfl_down(s, o);
    int lane = d & 63, wave = d >> 6;
    if (lane == 0) red[wave] = s;
    __syncthreads();
    float mean = (red[0] + red[1] + red[2] + red[3]) * (1.0f / DD);
    __syncthreads();

    float c = v - mean;
    float s2 = c * c;
#pragma unroll
    for (int o = 32; o > 0; o >>= 1) s2 += __shfl_down(s2, o);
    if (lane == 0) red[wave] = s2;
    __syncthreads();
    float var = (red[0] + red[1] + red[2] + red[3]) * (1.0f / DD);

    hn[d] = c * rsqrtf(var + 1e-5f) * fg[d] + fb[d];
    __syncthreads();

    float a1 = b1[d];
    const float* w1r = w1 + d * DD;
#pragma unroll 8
    for (int k = 0; k < DD; k++) a1 = fmaf(hn[k], w1r[k], a1);
    s1[d] = a1 / (1.0f + __expf(-a1));
    __syncthreads();

    if (d < OUT_LEN) {
        float a2 = b2[d];
        const float* w2r = w2 + d * DD;
#pragma unroll 8
        for (int k = 0; k < DD; k++) a2 = fmaf(s1[k], w2r[k], a2);
        out[b * OUT_LEN + d] = a2;
    }
}

// ---------------------------------------------------------------------------
extern "C" void kernel_launch(void* const* d_in, const int* in_sizes, int n_in,
                              void* d_out, int out_size, void* d_ws, size_t ws_size,
                              hipStream_t stream)
{
    (void)in_sizes; (void)n_in; (void)out_size; (void)ws_size;

    const float* x       = (const float*)d_in[0];
    const float* emb_w   = (const float*)d_in[1];
    const float* emb_b   = (const float*)d_in[2];
    const float* norm_g  = (const float*)d_in[3];
    const float* norm_b  = (const float*)d_in[4];
    const float* in_w    = (const float*)d_in[5];
    const float* conv_w  = (const float*)d_in[6];
    const float* A_p     = (const float*)d_in[7];
    const float* D_p     = (const float*)d_in[8];
    const float* dt1_w   = (const float*)d_in[9];
    const float* dt1_b   = (const float*)d_in[10];
    const float* dt2_w   = (const float*)d_in[11];
    const float* dt2_b   = (const float*)d_in[12];
    const float* out_w   = (const float*)d_in[13];
    const float* final_g = (const float*)d_in[14];
    const float* final_b = (const float*)d_in[15];
    const float* head1_w = (const float*)d_in[16];
    const float* head1_b = (const float*)d_in[17];
    const float* head2_w = (const float*)d_in[18];
    const float* head2_b = (const float*)d_in[19];
    float* outp = (float*)d_out;

    float* ws  = (float*)d_ws;
    float* h   = ws;                         // MM*DD
    float* v   = h   + (size_t)MM * DD;      // MM*HH (v, then dtf)
    float* vsb = v   + (size_t)MM * HH;      // MM*HH (conv+silu out)
    float* yb  = vsb + (size_t)MM * HH;      // MM*HH (LN buffer, then y)
    float* dtr = yb  + (size_t)MM * HH;      // MM*RR
    float* Lst = dtr + (size_t)MM * RR;      // CC*B*H*N = 1,048,576
    float* sdt = Lst + (size_t)CC * BB * HH * NN;  // CC*B*H = 65,536

    embed_kernel<<<MM, 256, 0, stream>>>(x, emb_w, emb_b, h);

    for (int l = 0; l < 4; l++) {
        ln_kernel<<<MM, 256, 0, stream>>>(h, norm_g + l * DD, norm_b + l * DD, yb);
        gemm_nt<128, 64, 8, 4><<<dim3(HH / 64, MM / 128), 256, 0, stream>>>(
            yb, in_w + (size_t)l * HH * DD, v, MM, HH, DD, 0);
        conv_silu_kernel<<<(MM * HH) / 256, 256, 0, stream>>>(
            v, conv_w + (size_t)l * HH * 3, vsb);
        dt1_kernel<<<MM / 4, 256, 0, stream>>>(
            vsb, dt1_w + (size_t)l * RR * HH, dt1_b + l * RR, dtr);
        dt2_kernel<<<(MM * HH) / 256, 256, 0, stream>>>(
            dtr, dt2_w + (size_t)l * HH * RR, dt2_b + l * HH, v /*dtf*/);

        scan_pass1<<<dim3(HH / 256, CC, BB), 256, 0, stream>>>(
            vsb, v, A_p + (size_t)l * HH * NN, Lst, sdt);
        scan_carry<<<(BB * HH * NN) / 256, 256, 0, stream>>>(
            A_p + (size_t)l * HH * NN, sdt, Lst);
        scan_pass2<<<dim3(HH / 256, CC, BB), 256, 0, stream>>>(
            vsb, v, A_p + (size_t)l * HH * NN, D_p + l * HH, Lst, yb);

        gemm_nt<64, 64, 4, 4><<<dim3(DD / 64, MM / 64), 256, 0, stream>>>(
            yb, out_w + (size_t)l * DD * HH, h, MM, DD, HH, 1);
    }

    head_kernel<<<BB, 256, 0, stream>>>(h, final_g, final_b,
                                        head1_w, head1_b, head2_w, head2_b, outp);
}

// Round 4
// 709.175 us; speedup vs baseline: 2.0134x; 1.2511x over previous
//
#include <hip/hip_runtime.h>
#include <hip/hip_bf16.h>
#include <math.h>

// Model dims
#define BB 8
#define TT 1024
#define DD 256
#define HH 512
#define NN 16
#define RR 8
#define OUT_LEN 96
#define IN_DIM 32
#define MM (BB*TT)   // 8192 rows

// scan chunking
#define SC 64
#define CC (TT/SC)   // 16

typedef unsigned short u16;
typedef __attribute__((ext_vector_type(8))) short short8;
typedef __attribute__((ext_vector_type(4))) float float4v;

__device__ __forceinline__ u16 f2bf(float f) {
    __hip_bfloat16 h = __float2bfloat16(f);
    return *(u16*)&h;
}

#define GLD_LDS16(src, dst) __builtin_amdgcn_global_load_lds( \
    (const __attribute__((address_space(1))) void*)(src),     \
    (__attribute__((address_space(3))) void*)(dst), 16, 0, 0)

// ---------------------------------------------------------------------------
// Embedding + positional encoding
// ---------------------------------------------------------------------------
__global__ __launch_bounds__(256) void embed_kernel(
    const float* __restrict__ x, const float* __restrict__ emb_w,
    const float* __restrict__ emb_b, float* __restrict__ h)
{
    int bt = blockIdx.x;           // 0..8191
    int d  = threadIdx.x;          // 0..255
    int t  = bt & (TT - 1);

    __shared__ float xs[IN_DIM];
    if (threadIdx.x < IN_DIM) xs[threadIdx.x] = x[bt * IN_DIM + threadIdx.x];
    __syncthreads();

    const float* w = emb_w + d * IN_DIM;
    float acc = emb_b[d];
#pragma unroll
    for (int i = 0; i < IN_DIM; i++) acc = fmaf(xs[i], w[i], acc);

    int i2 = d & ~1;  // 2*i
    float div = expf(-(float)i2 * (logf(10000.0f) / (float)DD));
    float arg = (float)t * div;
    float pe = (d & 1) ? cosf(arg) : sinf(arg);
    h[bt * DD + d] = acc + pe;
}

// ---------------------------------------------------------------------------
// fp32 -> bf16 weight conversion
// ---------------------------------------------------------------------------
__global__ __launch_bounds__(256) void cvt_bf16_kernel(
    const float* __restrict__ in, u16* __restrict__ out, int n)
{
    int i = blockIdx.x * 256 + threadIdx.x;
    if (i < n) out[i] = f2bf(in[i]);
}

// ---------------------------------------------------------------------------
// LayerNorm over D=256, one block per (b,t) row -> bf16 output
// ---------------------------------------------------------------------------
__global__ __launch_bounds__(256) void ln_kernel(
    const float* __restrict__ h, const float* __restrict__ g,
    const float* __restrict__ b, u16* __restrict__ out)
{
    int bt = blockIdx.x;
    int d  = threadIdx.x;
    float v = h[bt * DD + d];

    __shared__ float red[4], red2[4];
    float s = v;
#pragma unroll
    for (int o = 32; o > 0; o >>= 1) s += __shfl_down(s, o);
    int lane = d & 63, wave = d >> 6;
    if (lane == 0) red[wave] = s;
    __syncthreads();
    float mean = (red[0] + red[1] + red[2] + red[3]) * (1.0f / DD);

    float c = v - mean;
    float s2 = c * c;
#pragma unroll
    for (int o = 32; o > 0; o >>= 1) s2 += __shfl_down(s2, o);
    if (lane == 0) red2[wave] = s2;
    __syncthreads();
    float var = (red2[0] + red2[1] + red2[2] + red2[3]) * (1.0f / DD);

    out[bt * DD + d] = f2bf(c * rsqrtf(var + 1e-5f) * g[d] + b[d]);
}

// ---------------------------------------------------------------------------
// bf16 MFMA NT GEMM: C[m,n] = sum_k A[m,k]*B[n,k], fp32 accum, optional C +=
// A: M x K bf16 row-major.  B: N x K bf16 row-major.  C: M x N fp32.
// 256 threads = 4 waves in 2x2; BK=32 (one 16x16x32 MFMA K-step).
// LDS layout [q][row][8] (k-quad-major): lane-contiguous for global_load_lds
// AND conflict-free for ds_read_b128 fragment loads.
// ---------------------------------------------------------------------------
template<int BM, int BN>
__global__ __launch_bounds__(256) void gemm_bf16(
    const u16* __restrict__ A, const u16* __restrict__ B,
    float* __restrict__ C, int M, int N, int K, int addC)
{
    constexpr int BK = 32;
    constexpr int MT = BM / 32;   // m-subtiles per wave (wave covers BM/2 rows)
    constexpr int NT = BN / 32;   // n-subtiles per wave
    static_assert(4 * BN == 256, "B staging assumes BN==64");

    __shared__ u16 Al[4][BM][8];  // [k-quad][row][8 bf16] : 16B chunks
    __shared__ u16 Bl[4][BN][8];

    const int tid = threadIdx.x;
    const int bm = blockIdx.y * BM;
    const int bn = blockIdx.x * BN;
    const int wid = tid >> 6, lane = tid & 63;
    const int wm = wid >> 1, wn = wid & 1;
    const int lq = lane >> 4, lm = lane & 15;

    float4v acc[MT][NT];
#pragma unroll
    for (int i = 0; i < MT; i++)
#pragma unroll
        for (int j = 0; j < NT; j++) acc[i][j] = (float4v){0.f, 0.f, 0.f, 0.f};

    for (int k0 = 0; k0 < K; k0 += BK) {
        // stage A: 4*BM chunks of 16B, chunk c -> Al[c/BM][c%BM]
#pragma unroll
        for (int it = 0; it < (4 * BM) / 256; it++) {
            int c = it * 256 + tid;
            int q = c / BM, row = c % BM;
            GLD_LDS16(A + (size_t)(bm + row) * K + k0 + q * 8, &Al[q][row][0]);
        }
        // stage B: 4*BN == 256 chunks
        {
            int q = tid >> 6, row = tid & 63;
            GLD_LDS16(B + (size_t)(bn + row) * K + k0 + q * 8, &Bl[q][row][0]);
        }
        __syncthreads();   // barrier drains vmcnt -> LDS valid

        short8 af[MT], bf[NT];
#pragma unroll
        for (int mt = 0; mt < MT; mt++)
            af[mt] = *(const short8*)&Al[lq][wm * (BM / 2) + mt * 16 + lm][0];
#pragma unroll
        for (int nt = 0; nt < NT; nt++)
            bf[nt] = *(const short8*)&Bl[lq][wn * (BN / 2) + nt * 16 + lm][0];

#pragma unroll
        for (int mt = 0; mt < MT; mt++)
#pragma unroll
            for (int nt = 0; nt < NT; nt++)
                acc[mt][nt] = __builtin_amdgcn_mfma_f32_16x16x32_bf16(
                    af[mt], bf[nt], acc[mt][nt], 0, 0, 0);
        __syncthreads();
    }

    // epilogue: C/D layout row = lq*4 + reg, col = lm
#pragma unroll
    for (int mt = 0; mt < MT; mt++)
#pragma unroll
        for (int nt = 0; nt < NT; nt++) {
            int row0 = bm + wm * (BM / 2) + mt * 16 + lq * 4;
            int col  = bn + wn * (BN / 2) + nt * 16 + lm;
#pragma unroll
            for (int r = 0; r < 4; r++) {
                float* cp = C + (size_t)(row0 + r) * N + col;
                float vv = acc[mt][nt][r];
                if (addC) vv += *cp;
                *cp = vv;
            }
        }
}

// ---------------------------------------------------------------------------
// Depthwise conv (k=3, pad 1) over time + SiLU; (B,T,H) layout, fp32
// ---------------------------------------------------------------------------
__global__ __launch_bounds__(256) void conv_silu_kernel(
    const float* __restrict__ v, const float* __restrict__ w,
    float* __restrict__ out)
{
    int idx = blockIdx.x * 256 + threadIdx.x;   // B*T*H
    int h = idx & (HH - 1);
    int t = (idx >> 9) & (TT - 1);
    const float* wp = w + h * 3;
    float acc = wp[1] * v[idx];
    if (t > 0)      acc = fmaf(wp[0], v[idx - HH], acc);
    if (t < TT - 1) acc = fmaf(wp[2], v[idx + HH], acc);
    out[idx] = acc / (1.0f + __expf(-acc));   // silu
}

// ---------------------------------------------------------------------------
// dt1: dtr[m,r] = relu(vs[m,:] . dt1_w[r,:] + dt1_b[r]); one wave per m
// ---------------------------------------------------------------------------
__global__ __launch_bounds__(256) void dt1_kernel(
    const float* __restrict__ vs, const float* __restrict__ w,
    const float* __restrict__ bias, float* __restrict__ dtr)
{
    int wave = threadIdx.x >> 6;
    int lane = threadIdx.x & 63;
    int m = blockIdx.x * 4 + wave;
    const float* vrow = vs + (size_t)m * HH;

    float acc[RR];
#pragma unroll
    for (int r = 0; r < RR; r++) acc[r] = 0.0f;

#pragma unroll
    for (int j = 0; j < HH / 64; j++) {
        int hh = lane + j * 64;
        float vv = vrow[hh];
#pragma unroll
        for (int r = 0; r < RR; r++) acc[r] = fmaf(vv, w[r * HH + hh], acc[r]);
    }
#pragma unroll
    for (int r = 0; r < RR; r++) {
#pragma unroll
        for (int o = 32; o > 0; o >>= 1) acc[r] += __shfl_down(acc[r], o);
    }
    if (lane == 0) {
#pragma unroll
        for (int r = 0; r < RR; r++)
            dtr[m * RR + r] = fmaxf(acc[r] + bias[r], 0.0f);
    }
}

// ---------------------------------------------------------------------------
// dt2 + softplus
// ---------------------------------------------------------------------------
__global__ __launch_bounds__(256) void dt2_kernel(
    const float* __restrict__ dtr, const float* __restrict__ w,
    const float* __restrict__ bias, float* __restrict__ out)
{
    int idx = blockIdx.x * 256 + threadIdx.x;  // M*H
    int h = idx & (HH - 1);
    int m = idx >> 9;
    const float* dr = dtr + m * RR;
    const float* wr = w + h * RR;
    float acc = bias[h];
#pragma unroll
    for (int r = 0; r < RR; r++) acc = fmaf(dr[r], wr[r], acc);
    out[idx] = (acc > 20.0f) ? acc : log1pf(__expf(acc));
}

// ---------------------------------------------------------------------------
// Chunk-parallel selective scan, register-state version (see R3).
// pass2 now emits bf16 y (feeds the bf16 out-projection GEMM).
// ---------------------------------------------------------------------------
__global__ __launch_bounds__(256) void scan_pass1(
    const float* __restrict__ vs, const float* __restrict__ dtf,
    const float* __restrict__ A_p,
    float* __restrict__ Lst,         // (CC,B,H,N)
    float* __restrict__ sdt)         // (CC,B,H)
{
    int h = blockIdx.x * 256 + threadIdx.x;
    int c = blockIdx.y;
    int b = blockIdx.z;

    float A[NN], invA[NN], st[NN];
    const float* ap = A_p + h * NN;
#pragma unroll
    for (int n = 0; n < NN; n++) {
        float a = -__expf(ap[n]);
        A[n] = a; invA[n] = 1.0f / a; st[n] = 0.0f;
    }

    const float* vbase = vs  + ((size_t)b * TT + (size_t)c * SC) * HH + h;
    const float* dbase = dtf + ((size_t)b * TT + (size_t)c * SC) * HH + h;

    float s_dt = 0.0f;
#pragma unroll 4
    for (int t = 0; t < SC; t++) {
        float dt = dbase[(size_t)t * HH];
        float xv = vbase[(size_t)t * HH];
        s_dt += dt;
#pragma unroll
        for (int n = 0; n < NN; n++) {
            float e  = __expf(A[n] * dt);
            float dB = (e - 1.0f) * invA[n] * dt;
            st[n] = fmaf(e, st[n], dB * xv);
        }
    }

    size_t base = (((size_t)c * BB + b) * HH + h) * NN;
#pragma unroll
    for (int n = 0; n < NN; n += 4)
        *(float4*)(Lst + base + n) = make_float4(st[n], st[n+1], st[n+2], st[n+3]);
    sdt[((size_t)c * BB + b) * HH + h] = s_dt;
}

__global__ __launch_bounds__(256) void scan_carry(
    const float* __restrict__ A_p, const float* __restrict__ sdt,
    float* __restrict__ Lst)
{
    int i = blockIdx.x * 256 + threadIdx.x;   // (b*HH+h)*NN+n
    int n  = i & (NN - 1);
    int bh = i >> 4;
    int h  = bh & (HH - 1);
    int b  = bh >> 9;

    float A = -__expf(A_p[h * NN + n]);
    float E = 0.0f;
#pragma unroll
    for (int c = 0; c < CC; c++) {
        size_t sidx = ((size_t)c * BB + b) * HH + h;
        float P = __expf(A * sdt[sidx]);
        size_t lidx = sidx * NN + n;
        float Lc = Lst[lidx];
        Lst[lidx] = E;
        E = fmaf(P, E, Lc);
    }
}

__global__ __launch_bounds__(256) void scan_pass2(
    const float* __restrict__ vs, const float* __restrict__ dtf,
    const float* __restrict__ A_p, const float* __restrict__ D_p,
    const float* __restrict__ carry,
    u16* __restrict__ y)               // (B,T,H) bf16
{
    int h = blockIdx.x * 256 + threadIdx.x;
    int c = blockIdx.y;
    int b = blockIdx.z;

    float A[NN], invA[NN], Ap[NN], st[NN];
    const float* app = A_p + h * NN;
    size_t cbase = (((size_t)c * BB + b) * HH + h) * NN;
#pragma unroll
    for (int n = 0; n < NN; n += 4) {
        float4 c4 = *(const float4*)(carry + cbase + n);
        st[n] = c4.x; st[n+1] = c4.y; st[n+2] = c4.z; st[n+3] = c4.w;
    }
#pragma unroll
    for (int n = 0; n < NN; n++) {
        float apv = app[n];
        Ap[n] = apv;
        float a = -__expf(apv);
        A[n] = a; invA[n] = 1.0f / a;
    }
    float Dp = D_p[h];

    const float* vbase = vs  + ((size_t)b * TT + (size_t)c * SC) * HH + h;
    const float* dbase = dtf + ((size_t)b * TT + (size_t)c * SC) * HH + h;
    u16*         ybase = y   + ((size_t)b * TT + (size_t)c * SC) * HH + h;

#pragma unroll 2
    for (int t = 0; t < SC; t++) {
        float dt = dbase[(size_t)t * HH];
        float xv = vbase[(size_t)t * HH];
        float acc = Dp * xv;
#pragma unroll
        for (int n = 0; n < NN; n++) {
            float e  = __expf(A[n] * dt);
            float dB = (e - 1.0f) * invA[n] * dt;
            st[n] = fmaf(e, st[n], dB * xv);
            acc = fmaf(st[n], Ap[n], acc);
        }
        ybase[(size_t)t * HH] = f2bf(acc);
    }
}

// ---------------------------------------------------------------------------
// Head: final LN on last token, head1+silu, head2. One block per batch.
// ---------------------------------------------------------------------------
__global__ __launch_bounds__(256) void head_kernel(
    const float* __restrict__ h,
    const float* __restrict__ fg, const float* __restrict__ fb,
    const float* __restrict__ w1, const float* __restrict__ b1,
    const float* __restrict__ w2, const float* __restrict__ b2,
    float* __restrict__ out)
{
    int b = blockIdx.x;
    int d = threadIdx.x;
    __shared__ float hn[DD], s1[DD];
    __shared__ float red[4];

    float v = h[((size_t)b * TT + (TT - 1)) * DD + d];

    float s = v;
#pragma unroll
    for (int o = 32; o > 0; o >>= 1) s += __shfl_down(s, o);
    int lane = d & 63, wave = d >> 6;
    if (lane == 0) red[wave] = s;
    __syncthreads();
    float mean = (red[0] + red[1] + red[2] + red[3]) * (1.0f / DD);
    __syncthreads();

    float c = v - mean;
    float s2 = c * c;
#pragma unroll
    for (int o = 32; o > 0; o >>= 1) s2 += __shfl_down(s2, o);
    if (lane == 0) red[wave] = s2;
    __syncthreads();
    float var = (red[0] + red[1] + red[2] + red[3]) * (1.0f / DD);

    hn[d] = c * rsqrtf(var + 1e-5f) * fg[d] + fb[d];
    __syncthreads();

    float a1 = b1[d];
    const float* w1r = w1 + d * DD;
#pragma unroll 8
    for (int k = 0; k < DD; k++) a1 = fmaf(hn[k], w1r[k], a1);
    s1[d] = a1 / (1.0f + __expf(-a1));
    __syncthreads();

    if (d < OUT_LEN) {
        float a2 = b2[d];
        const float* w2r = w2 + d * DD;
#pragma unroll 8
        for (int k = 0; k < DD; k++) a2 = fmaf(s1[k], w2r[k], a2);
        out[b * OUT_LEN + d] = a2;
    }
}

// ---------------------------------------------------------------------------
extern "C" void kernel_launch(void* const* d_in, const int* in_sizes, int n_in,
                              void* d_out, int out_size, void* d_ws, size_t ws_size,
                              hipStream_t stream)
{
    (void)in_sizes; (void)n_in; (void)out_size; (void)ws_size;

    const float* x       = (const float*)d_in[0];
    const float* emb_w   = (const float*)d_in[1];
    const float* emb_b   = (const float*)d_in[2];
    const float* norm_g  = (const float*)d_in[3];
    const float* norm_b  = (const float*)d_in[4];
    const float* in_w    = (const float*)d_in[5];
    const float* conv_w  = (const float*)d_in[6];
    const float* A_p     = (const float*)d_in[7];
    const float* D_p     = (const float*)d_in[8];
    const float* dt1_w   = (const float*)d_in[9];
    const float* dt1_b   = (const float*)d_in[10];
    const float* dt2_w   = (const float*)d_in[11];
    const float* dt2_b   = (const float*)d_in[12];
    const float* out_w   = (const float*)d_in[13];
    const float* final_g = (const float*)d_in[14];
    const float* final_b = (const float*)d_in[15];
    const float* head1_w = (const float*)d_in[16];
    const float* head1_b = (const float*)d_in[17];
    const float* head2_w = (const float*)d_in[18];
    const float* head2_b = (const float*)d_in[19];
    float* outp = (float*)d_out;

    float* ws  = (float*)d_ws;
    float* h   = ws;                               // MM*DD fp32
    float* v   = h   + (size_t)MM * DD;            // MM*HH fp32 (v, then dtf)
    float* vsb = v   + (size_t)MM * HH;            // MM*HH fp32 (conv+silu out)
    float* yb  = vsb + (size_t)MM * HH;            // MM*HH (bf16 ln-out / bf16 y)
    float* dtr = yb  + (size_t)MM * HH;            // MM*RR
    float* Lst = dtr + (size_t)MM * RR;            // CC*B*H*N
    float* sdt = Lst + (size_t)CC * BB * HH * NN;  // CC*B*H
    u16*   wbf_in  = (u16*)(sdt + (size_t)CC * BB * HH);       // L*H*D bf16
    u16*   wbf_out = wbf_in + (size_t)4 * HH * DD;             // L*D*H bf16
    u16*   yb_u    = (u16*)yb;

    // one-time (per launch) weight conversion to bf16
    cvt_bf16_kernel<<<(4 * HH * DD) / 256, 256, 0, stream>>>(in_w,  wbf_in,  4 * HH * DD);
    cvt_bf16_kernel<<<(4 * DD * HH) / 256, 256, 0, stream>>>(out_w, wbf_out, 4 * DD * HH);

    embed_kernel<<<MM, 256, 0, stream>>>(x, emb_w, emb_b, h);

    for (int l = 0; l < 4; l++) {
        ln_kernel<<<MM, 256, 0, stream>>>(h, norm_g + l * DD, norm_b + l * DD, yb_u);
        gemm_bf16<128, 64><<<dim3(HH / 64, MM / 128), 256, 0, stream>>>(
            yb_u, wbf_in + (size_t)l * HH * DD, v, MM, HH, DD, 0);
        conv_silu_kernel<<<(MM * HH) / 256, 256, 0, stream>>>(
            v, conv_w + (size_t)l * HH * 3, vsb);
        dt1_kernel<<<MM / 4, 256, 0, stream>>>(
            vsb, dt1_w + (size_t)l * RR * HH, dt1_b + l * RR, dtr);
        dt2_kernel<<<(MM * HH) / 256, 256, 0, stream>>>(
            dtr, dt2_w + (size_t)l * HH * RR, dt2_b + l * HH, v /*dtf*/);

        scan_pass1<<<dim3(HH / 256, CC, BB), 256, 0, stream>>>(
            vsb, v, A_p + (size_t)l * HH * NN, Lst, sdt);
        scan_carry<<<(BB * HH * NN) / 256, 256, 0, stream>>>(
            A_p + (size_t)l * HH * NN, sdt, Lst);
        scan_pass2<<<dim3(HH / 256, CC, BB), 256, 0, stream>>>(
            vsb, v, A_p + (size_t)l * HH * NN, D_p + l * HH, Lst, yb_u);

        gemm_bf16<64, 64><<<dim3(DD / 64, MM / 64), 256, 0, stream>>>(
            yb_u, wbf_out + (size_t)l * DD * HH, h, MM, DD, HH, 1);
    }

    head_kernel<<<BB, 256, 0, stream>>>(h, final_g, final_b,
                                        head1_w, head1_b, head2_w, head2_b, outp);
}

// Round 5
// 642.316 us; speedup vs baseline: 2.2230x; 1.1041x over previous
//
#include <hip/hip_runtime.h>
#include <hip/hip_bf16.h>
#include <math.h>

// Model dims
#define BB 8
#define TT 1024
#define DD 256
#define HH 512
#define NN 16
#define RR 8
#define OUT_LEN 96
#define IN_DIM 32
#define MM (BB*TT)   // 8192 rows

// scan chunking: 512 blocks/pass = 2 waves/SIMD
#define SC 32
#define CC (TT/SC)   // 32

typedef unsigned short u16;
typedef unsigned int u32;
typedef __attribute__((ext_vector_type(8))) short short8;
typedef __attribute__((ext_vector_type(4))) float float4v;

__device__ __forceinline__ u16 f2bf(float f) {
    __hip_bfloat16 h = __float2bfloat16(f);
    return *(u16*)&h;
}
__device__ __forceinline__ float bf2f(u16 u) {
    u32 v = ((u32)u) << 16;
    return *(float*)&v;
}

#define GLD_LDS16(src, dst) __builtin_amdgcn_global_load_lds( \
    (const __attribute__((address_space(1))) void*)(src),     \
    (__attribute__((address_space(3))) void*)(dst), 16, 0, 0)

// ---------------------------------------------------------------------------
// Embedding + positional encoding
// ---------------------------------------------------------------------------
__global__ __launch_bounds__(256) void embed_kernel(
    const float* __restrict__ x, const float* __restrict__ emb_w,
    const float* __restrict__ emb_b, float* __restrict__ h)
{
    int bt = blockIdx.x;
    int d  = threadIdx.x;
    int t  = bt & (TT - 1);

    __shared__ float xs[IN_DIM];
    if (threadIdx.x < IN_DIM) xs[threadIdx.x] = x[bt * IN_DIM + threadIdx.x];
    __syncthreads();

    const float* w = emb_w + d * IN_DIM;
    float acc = emb_b[d];
#pragma unroll
    for (int i = 0; i < IN_DIM; i++) acc = fmaf(xs[i], w[i], acc);

    int i2 = d & ~1;
    float div = expf(-(float)i2 * (logf(10000.0f) / (float)DD));
    float arg = (float)t * div;
    float pe = (d & 1) ? cosf(arg) : sinf(arg);
    h[bt * DD + d] = acc + pe;
}

// ---------------------------------------------------------------------------
// fp32 -> bf16 weight conversion
// ---------------------------------------------------------------------------
__global__ __launch_bounds__(256) void cvt_bf16_kernel(
    const float* __restrict__ in, u16* __restrict__ out, int n)
{
    int i = blockIdx.x * 256 + threadIdx.x;
    if (i < n) out[i] = f2bf(in[i]);
}

// ---------------------------------------------------------------------------
// LayerNorm over D=256 -> bf16 output
// ---------------------------------------------------------------------------
__global__ __launch_bounds__(256) void ln_kernel(
    const float* __restrict__ h, const float* __restrict__ g,
    const float* __restrict__ b, u16* __restrict__ out)
{
    int bt = blockIdx.x;
    int d  = threadIdx.x;
    float v = h[bt * DD + d];

    __shared__ float red[4], red2[4];
    float s = v;
#pragma unroll
    for (int o = 32; o > 0; o >>= 1) s += __shfl_down(s, o);
    int lane = d & 63, wave = d >> 6;
    if (lane == 0) red[wave] = s;
    __syncthreads();
    float mean = (red[0] + red[1] + red[2] + red[3]) * (1.0f / DD);

    float c = v - mean;
    float s2 = c * c;
#pragma unroll
    for (int o = 32; o > 0; o >>= 1) s2 += __shfl_down(s2, o);
    if (lane == 0) red2[wave] = s2;
    __syncthreads();
    float var = (red2[0] + red2[1] + red2[2] + red2[3]) * (1.0f / DD);

    out[bt * DD + d] = f2bf(c * rsqrtf(var + 1e-5f) * g[d] + b[d]);
}

// ---------------------------------------------------------------------------
// bf16 MFMA NT GEMM, BK=64 (16 MFMA per barrier pair).
// A: MxK bf16 row-major. B: NxK bf16 row-major. Out fp32 (+addC) or bf16.
// LDS layout [k-octet][row][8 bf16]: lane-contiguous for global_load_lds,
// conflict-free for ds_read_b128.
// ---------------------------------------------------------------------------
template<int BM, int BN, int OUT_BF16>
__global__ __launch_bounds__(256) void gemm_bf16(
    const u16* __restrict__ A, const u16* __restrict__ B,
    void* __restrict__ Cv, int M, int N, int K, int addC)
{
    constexpr int BK = 64;
    constexpr int MT = BM / 32;
    constexpr int NT = BN / 32;
    static_assert(BN == 64, "B staging assumes BN==64");

    __shared__ __align__(16) u16 Al[8][BM][8];
    __shared__ __align__(16) u16 Bl[8][BN][8];

    const int tid = threadIdx.x;
    const int bm = blockIdx.y * BM;
    const int bn = blockIdx.x * BN;
    const int wid = tid >> 6, lane = tid & 63;
    const int wm = wid >> 1, wn = wid & 1;
    const int lq = lane >> 4, lm = lane & 15;

    float4v acc[MT][NT];
#pragma unroll
    for (int i = 0; i < MT; i++)
#pragma unroll
        for (int j = 0; j < NT; j++) acc[i][j] = (float4v){0.f, 0.f, 0.f, 0.f};

    for (int k0 = 0; k0 < K; k0 += BK) {
        // stage A: 8*BM 16B chunks
#pragma unroll
        for (int it = 0; it < (8 * BM) / 256; it++) {
            int c = it * 256 + tid;
            int q = c / BM, row = c % BM;
            GLD_LDS16(A + (size_t)(bm + row) * K + k0 + q * 8, &Al[q][row][0]);
        }
        // stage B: 8*BN = 512 chunks
#pragma unroll
        for (int it = 0; it < (8 * BN) / 256; it++) {
            int c = it * 256 + tid;
            int q = c / BN, row = c % BN;
            GLD_LDS16(B + (size_t)(bn + row) * K + k0 + q * 8, &Bl[q][row][0]);
        }
        __syncthreads();

        short8 af[2][MT], bf[2][NT];
#pragma unroll
        for (int kk = 0; kk < 2; kk++) {
#pragma unroll
            for (int mt = 0; mt < MT; mt++)
                af[kk][mt] = *(const short8*)&Al[kk * 4 + lq][wm * (BM / 2) + mt * 16 + lm][0];
#pragma unroll
            for (int nt = 0; nt < NT; nt++)
                bf[kk][nt] = *(const short8*)&Bl[kk * 4 + lq][wn * (BN / 2) + nt * 16 + lm][0];
        }

#pragma unroll
        for (int kk = 0; kk < 2; kk++)
#pragma unroll
            for (int mt = 0; mt < MT; mt++)
#pragma unroll
                for (int nt = 0; nt < NT; nt++)
                    acc[mt][nt] = __builtin_amdgcn_mfma_f32_16x16x32_bf16(
                        af[kk][mt], bf[kk][nt], acc[mt][nt], 0, 0, 0);
        __syncthreads();
    }

    // epilogue: C/D layout row = lq*4 + r, col = lm
#pragma unroll
    for (int mt = 0; mt < MT; mt++)
#pragma unroll
        for (int nt = 0; nt < NT; nt++) {
            int row0 = bm + wm * (BM / 2) + mt * 16 + lq * 4;
            int col  = bn + wn * (BN / 2) + nt * 16 + lm;
#pragma unroll
            for (int r = 0; r < 4; r++) {
                float vv = acc[mt][nt][r];
                if (OUT_BF16) {
                    ((u16*)Cv)[(size_t)(row0 + r) * N + col] = f2bf(vv);
                } else {
                    float* cp = (float*)Cv + (size_t)(row0 + r) * N + col;
                    if (addC) vv += *cp;
                    *cp = vv;
                }
            }
        }
}

// ---------------------------------------------------------------------------
// Fused depthwise conv(k=3,pad1)+SiLU -> dt1(relu) -> dt2(softplus).
// One wave per timestep t; weights staged in LDS (dt2_w padded to 9/row).
// v (bf16, B,T,H) -> vsb (bf16), dtf (fp32).
// ---------------------------------------------------------------------------
#define TPB_T 16
__global__ __launch_bounds__(256) void conv_dt_kernel(
    const u16* __restrict__ v,
    const float* __restrict__ conv_w,   // (H,3)
    const float* __restrict__ dt1_w,    // (R,H)
    const float* __restrict__ dt1_b,    // (R)
    const float* __restrict__ dt2_w,    // (H,R)
    const float* __restrict__ dt2_b,    // (H)
    u16* __restrict__ vsb,
    float* __restrict__ dtf)
{
    __shared__ float cw[HH * 3];        // 6 KB
    __shared__ float w1s[RR * HH];      // 16 KB
    __shared__ float w2s[HH * 9];       // 18 KB (padded: stride 9 kills 8-way conflicts)
    __shared__ float b1s[RR];
    __shared__ float b2s[HH];

    int tid = threadIdx.x;
    for (int i = tid; i < HH * 3; i += 256) cw[i] = conv_w[i];
    for (int i = tid; i < RR * HH; i += 256) w1s[i] = dt1_w[i];
    for (int i = tid; i < HH; i += 256) {
        b2s[i] = dt2_b[i];
#pragma unroll
        for (int r = 0; r < RR; r++) w2s[i * 9 + r] = dt2_w[i * RR + r];
    }
    if (tid < RR) b1s[tid] = dt1_b[tid];
    __syncthreads();

    int b  = blockIdx.y;
    int t0 = blockIdx.x * TPB_T;
    int wv = tid >> 6, lane = tid & 63;

    for (int tt = 0; tt < TPB_T / 4; tt++) {
        int t = t0 + tt * 4 + wv;
        const u16* vrow = v + ((size_t)b * TT + t) * HH;

        float cv[HH / 64];
        float acc[RR];
#pragma unroll
        for (int r = 0; r < RR; r++) acc[r] = 0.0f;

#pragma unroll
        for (int j = 0; j < HH / 64; j++) {
            int h = j * 64 + lane;
            float xm = (t > 0)      ? bf2f(vrow[h - HH]) : 0.0f;
            float x0 = bf2f(vrow[h]);
            float xp = (t < TT - 1) ? bf2f(vrow[h + HH]) : 0.0f;
            float a = cw[h * 3] * xm;
            a = fmaf(cw[h * 3 + 1], x0, a);
            a = fmaf(cw[h * 3 + 2], xp, a);
            a = a / (1.0f + __expf(-a));   // silu
            cv[j] = a;
#pragma unroll
            for (int r = 0; r < RR; r++) acc[r] = fmaf(a, w1s[r * HH + h], acc[r]);
        }

        u16* vo = vsb + ((size_t)b * TT + t) * HH;
#pragma unroll
        for (int j = 0; j < HH / 64; j++) vo[j * 64 + lane] = f2bf(cv[j]);

        // butterfly so every lane holds all dtr
#pragma unroll
        for (int r = 0; r < RR; r++) {
#pragma unroll
            for (int o = 1; o < 64; o <<= 1) acc[r] += __shfl_xor(acc[r], o);
            acc[r] = fmaxf(acc[r] + b1s[r], 0.0f);
        }

        float* dout = dtf + ((size_t)b * TT + t) * HH;
#pragma unroll
        for (int j = 0; j < HH / 64; j++) {
            int h = j * 64 + lane;
            float s = b2s[h];
#pragma unroll
            for (int r = 0; r < RR; r++) s = fmaf(acc[r], w2s[h * 9 + r], s);
            dout[h] = (s > 20.0f) ? s : log1pf(__expf(s));
        }
    }
}

// ---------------------------------------------------------------------------
// Chunk-parallel selective scan (register-state). vs is bf16, dtf fp32.
// ---------------------------------------------------------------------------
__global__ __launch_bounds__(256) void scan_pass1(
    const u16* __restrict__ vs, const float* __restrict__ dtf,
    const float* __restrict__ A_p,
    float* __restrict__ Lst,         // (CC,B,H,N)
    float* __restrict__ sdt)         // (CC,B,H)
{
    int h = blockIdx.x * 256 + threadIdx.x;
    int c = blockIdx.y;
    int b = blockIdx.z;

    float A[NN], invA[NN], st[NN];
    const float* ap = A_p + h * NN;
#pragma unroll
    for (int n = 0; n < NN; n++) {
        float a = -__expf(ap[n]);
        A[n] = a; invA[n] = 1.0f / a; st[n] = 0.0f;
    }

    const u16*   vbase = vs  + ((size_t)b * TT + (size_t)c * SC) * HH + h;
    const float* dbase = dtf + ((size_t)b * TT + (size_t)c * SC) * HH + h;

    float s_dt = 0.0f;
#pragma unroll 4
    for (int t = 0; t < SC; t++) {
        float dt = dbase[(size_t)t * HH];
        float xv = bf2f(vbase[(size_t)t * HH]);
        s_dt += dt;
#pragma unroll
        for (int n = 0; n < NN; n++) {
            float e  = __expf(A[n] * dt);
            float dB = (e - 1.0f) * invA[n] * dt;
            st[n] = fmaf(e, st[n], dB * xv);
        }
    }

    size_t base = (((size_t)c * BB + b) * HH + h) * NN;
#pragma unroll
    for (int n = 0; n < NN; n += 4)
        *(float4*)(Lst + base + n) = make_float4(st[n], st[n+1], st[n+2], st[n+3]);
    sdt[((size_t)c * BB + b) * HH + h] = s_dt;
}

__global__ __launch_bounds__(256) void scan_carry(
    const float* __restrict__ A_p, const float* __restrict__ sdt,
    float* __restrict__ Lst)
{
    int i = blockIdx.x * 256 + threadIdx.x;   // (b*HH+h)*NN+n
    int n  = i & (NN - 1);
    int bh = i >> 4;
    int h  = bh & (HH - 1);
    int b  = bh >> 9;

    float A = -__expf(A_p[h * NN + n]);
    float E = 0.0f;
#pragma unroll
    for (int c = 0; c < CC; c++) {
        size_t sidx = ((size_t)c * BB + b) * HH + h;
        float P = __expf(A * sdt[sidx]);
        size_t lidx = sidx * NN + n;
        float Lc = Lst[lidx];
        Lst[lidx] = E;
        E = fmaf(P, E, Lc);
    }
}

__global__ __launch_bounds__(256) void scan_pass2(
    const u16* __restrict__ vs, const float* __restrict__ dtf,
    const float* __restrict__ A_p, const float* __restrict__ D_p,
    const float* __restrict__ carry,
    u16* __restrict__ y)               // (B,T,H) bf16
{
    int h = blockIdx.x * 256 + threadIdx.x;
    int c = blockIdx.y;
    int b = blockIdx.z;

    float A[NN], invA[NN], Ap[NN], st[NN];
    const float* app = A_p + h * NN;
    size_t cbase = (((size_t)c * BB + b) * HH + h) * NN;
#pragma unroll
    for (int n = 0; n < NN; n += 4) {
        float4 c4 = *(const float4*)(carry + cbase + n);
        st[n] = c4.x; st[n+1] = c4.y; st[n+2] = c4.z; st[n+3] = c4.w;
    }
#pragma unroll
    for (int n = 0; n < NN; n++) {
        float apv = app[n];
        Ap[n] = apv;
        float a = -__expf(apv);
        A[n] = a; invA[n] = 1.0f / a;
    }
    float Dp = D_p[h];

    const u16*   vbase = vs  + ((size_t)b * TT + (size_t)c * SC) * HH + h;
    const float* dbase = dtf + ((size_t)b * TT + (size_t)c * SC) * HH + h;
    u16*         ybase = y   + ((size_t)b * TT + (size_t)c * SC) * HH + h;

#pragma unroll 2
    for (int t = 0; t < SC; t++) {
        float dt = dbase[(size_t)t * HH];
        float xv = bf2f(vbase[(size_t)t * HH]);
        float acc = Dp * xv;
#pragma unroll
        for (int n = 0; n < NN; n++) {
            float e  = __expf(A[n] * dt);
            float dB = (e - 1.0f) * invA[n] * dt;
            st[n] = fmaf(e, st[n], dB * xv);
            acc = fmaf(st[n], Ap[n], acc);
        }
        ybase[(size_t)t * HH] = f2bf(acc);
    }
}

// ---------------------------------------------------------------------------
// Head: final LN on last token, head1+silu, head2. One block per batch.
// ---------------------------------------------------------------------------
__global__ __launch_bounds__(256) void head_kernel(
    const float* __restrict__ h,
    const float* __restrict__ fg, const float* __restrict__ fb,
    const float* __restrict__ w1, const float* __restrict__ b1,
    const float* __restrict__ w2, const float* __restrict__ b2,
    float* __restrict__ out)
{
    int b = blockIdx.x;
    int d = threadIdx.x;
    __shared__ float hn[DD], s1[DD];
    __shared__ float red[4];

    float v = h[((size_t)b * TT + (TT - 1)) * DD + d];

    float s = v;
#pragma unroll
    for (int o = 32; o > 0; o >>= 1) s += __shfl_down(s, o);
    int lane = d & 63, wave = d >> 6;
    if (lane == 0) red[wave] = s;
    __syncthreads();
    float mean = (red[0] + red[1] + red[2] + red[3]) * (1.0f / DD);
    __syncthreads();

    float c = v - mean;
    float s2 = c * c;
#pragma unroll
    for (int o = 32; o > 0; o >>= 1) s2 += __shfl_down(s2, o);
    if (lane == 0) red[wave] = s2;
    __syncthreads();
    float var = (red[0] + red[1] + red[2] + red[3]) * (1.0f / DD);

    hn[d] = c * rsqrtf(var + 1e-5f) * fg[d] + fb[d];
    __syncthreads();

    float a1 = b1[d];
    const float* w1r = w1 + d * DD;
#pragma unroll 8
    for (int k = 0; k < DD; k++) a1 = fmaf(hn[k], w1r[k], a1);
    s1[d] = a1 / (1.0f + __expf(-a1));
    __syncthreads();

    if (d < OUT_LEN) {
        float a2 = b2[d];
        const float* w2r = w2 + d * DD;
#pragma unroll 8
        for (int k = 0; k < DD; k++) a2 = fmaf(s1[k], w2r[k], a2);
        out[b * OUT_LEN + d] = a2;
    }
}

// ---------------------------------------------------------------------------
extern "C" void kernel_launch(void* const* d_in, const int* in_sizes, int n_in,
                              void* d_out, int out_size, void* d_ws, size_t ws_size,
                              hipStream_t stream)
{
    (void)in_sizes; (void)n_in; (void)out_size; (void)ws_size;

    const float* x       = (const float*)d_in[0];
    const float* emb_w   = (const float*)d_in[1];
    const float* emb_b   = (const float*)d_in[2];
    const float* norm_g  = (const float*)d_in[3];
    const float* norm_b  = (const float*)d_in[4];
    const float* in_w    = (const float*)d_in[5];
    const float* conv_w  = (const float*)d_in[6];
    const float* A_p     = (const float*)d_in[7];
    const float* D_p     = (const float*)d_in[8];
    const float* dt1_w   = (const float*)d_in[9];
    const float* dt1_b   = (const float*)d_in[10];
    const float* dt2_w   = (const float*)d_in[11];
    const float* dt2_b   = (const float*)d_in[12];
    const float* out_w   = (const float*)d_in[13];
    const float* final_g = (const float*)d_in[14];
    const float* final_b = (const float*)d_in[15];
    const float* head1_w = (const float*)d_in[16];
    const float* head1_b = (const float*)d_in[17];
    const float* head2_w = (const float*)d_in[18];
    const float* head2_b = (const float*)d_in[19];
    float* outp = (float*)d_out;

    char* ws = (char*)d_ws;
    float* h    = (float*)ws;                 ws += (size_t)MM * DD * 4;   // fp32 residual
    u16*   vbf  = (u16*)ws;                   ws += (size_t)MM * HH * 2;   // gemm1 out (bf16)
    u16*   vsb  = (u16*)ws;                   ws += (size_t)MM * HH * 2;   // conv+silu (bf16)
    float* dtf  = (float*)ws;                 ws += (size_t)MM * HH * 4;   // softplus dt (fp32)
    u16*   yb_u = (u16*)ws;                   ws += (size_t)MM * HH * 2;   // ln-out / y (bf16)
    float* Lst  = (float*)ws;                 ws += (size_t)CC * BB * HH * NN * 4;
    float* sdt  = (float*)ws;                 ws += (size_t)CC * BB * HH * 4;
    u16*   wbf_in  = (u16*)ws;                ws += (size_t)4 * HH * DD * 2;
    u16*   wbf_out = (u16*)ws;                ws += (size_t)4 * DD * HH * 2;

    cvt_bf16_kernel<<<(4 * HH * DD) / 256, 256, 0, stream>>>(in_w,  wbf_in,  4 * HH * DD);
    cvt_bf16_kernel<<<(4 * DD * HH) / 256, 256, 0, stream>>>(out_w, wbf_out, 4 * DD * HH);

    embed_kernel<<<MM, 256, 0, stream>>>(x, emb_w, emb_b, h);

    for (int l = 0; l < 4; l++) {
        ln_kernel<<<MM, 256, 0, stream>>>(h, norm_g + l * DD, norm_b + l * DD, yb_u);
        gemm_bf16<128, 64, 1><<<dim3(HH / 64, MM / 128), 256, 0, stream>>>(
            yb_u, wbf_in + (size_t)l * HH * DD, vbf, MM, HH, DD, 0);
        conv_dt_kernel<<<dim3(TT / TPB_T, BB), 256, 0, stream>>>(
            vbf, conv_w + (size_t)l * HH * 3,
            dt1_w + (size_t)l * RR * HH, dt1_b + l * RR,
            dt2_w + (size_t)l * HH * RR, dt2_b + l * HH, vsb, dtf);

        scan_pass1<<<dim3(HH / 256, CC, BB), 256, 0, stream>>>(
            vsb, dtf, A_p + (size_t)l * HH * NN, Lst, sdt);
        scan_carry<<<(BB * HH * NN) / 256, 256, 0, stream>>>(
            A_p + (size_t)l * HH * NN, sdt, Lst);
        scan_pass2<<<dim3(HH / 256, CC, BB), 256, 0, stream>>>(
            vsb, dtf, A_p + (size_t)l * HH * NN, D_p + l * HH, Lst, yb_u);

        gemm_bf16<64, 64, 0><<<dim3(DD / 64, MM / 64), 256, 0, stream>>>(
            yb_u, wbf_out + (size_t)l * DD * HH, h, MM, DD, HH, 1);
    }

    head_kernel<<<BB, 256, 0, stream>>>(h, final_g, final_b,
                                        head1_w, head1_b, head2_w, head2_b, outp);
}

// Round 6
// 540.368 us; speedup vs baseline: 2.6424x; 1.1887x over previous
//
#include <hip/hip_runtime.h>
#include <hip/hip_bf16.h>
#include <math.h>

// Model dims
#define BB 8
#define TT 1024
#define DD 256
#define HH 512
#define NN 16
#define RR 8
#define OUT_LEN 96
#define IN_DIM 32
#define MM (BB*TT)   // 8192 rows

// scan chunking
#define SC 32
#define CC (TT/SC)   // 32

typedef unsigned short u16;
typedef unsigned int u32;
typedef __attribute__((ext_vector_type(8))) short short8;
typedef __attribute__((ext_vector_type(8))) unsigned short u16x8;
typedef __attribute__((ext_vector_type(4))) float float4v;

__device__ __forceinline__ u16 f2bf(float f) {
    __hip_bfloat16 h = __float2bfloat16(f);
    return *(u16*)&h;
}
__device__ __forceinline__ float bf2f(u16 u) {
    u32 v = ((u32)u) << 16;
    return *(float*)&v;
}

#define GLD_LDS16(src, dst) __builtin_amdgcn_global_load_lds( \
    (const __attribute__((address_space(1))) void*)(src),     \
    (__attribute__((address_space(3))) void*)(dst), 16, 0, 0)

// ---------------------------------------------------------------------------
// Embedding + positional encoding
// ---------------------------------------------------------------------------
__global__ __launch_bounds__(256) void embed_kernel(
    const float* __restrict__ x, const float* __restrict__ emb_w,
    const float* __restrict__ emb_b, float* __restrict__ h)
{
    int bt = blockIdx.x;
    int d  = threadIdx.x;
    int t  = bt & (TT - 1);

    __shared__ float xs[IN_DIM];
    if (threadIdx.x < IN_DIM) xs[threadIdx.x] = x[bt * IN_DIM + threadIdx.x];
    __syncthreads();

    const float* w = emb_w + d * IN_DIM;
    float acc = emb_b[d];
#pragma unroll
    for (int i = 0; i < IN_DIM; i++) acc = fmaf(xs[i], w[i], acc);

    int i2 = d & ~1;
    float div = expf(-(float)i2 * (logf(10000.0f) / (float)DD));
    float arg = (float)t * div;
    float pe = (d & 1) ? cosf(arg) : sinf(arg);
    h[bt * DD + d] = acc + pe;
}

// ---------------------------------------------------------------------------
// fp32 -> bf16 weight conversion
// ---------------------------------------------------------------------------
__global__ __launch_bounds__(256) void cvt_bf16_kernel(
    const float* __restrict__ in, u16* __restrict__ out, int n)
{
    int i = blockIdx.x * 256 + threadIdx.x;
    if (i < n) out[i] = f2bf(in[i]);
}

// ---------------------------------------------------------------------------
// LayerNorm over D=256 -> bf16 output
// ---------------------------------------------------------------------------
__global__ __launch_bounds__(256) void ln_kernel(
    const float* __restrict__ h, const float* __restrict__ g,
    const float* __restrict__ b, u16* __restrict__ out)
{
    int bt = blockIdx.x;
    int d  = threadIdx.x;
    float v = h[bt * DD + d];

    __shared__ float red[4], red2[4];
    float s = v;
#pragma unroll
    for (int o = 32; o > 0; o >>= 1) s += __shfl_down(s, o);
    int lane = d & 63, wave = d >> 6;
    if (lane == 0) red[wave] = s;
    __syncthreads();
    float mean = (red[0] + red[1] + red[2] + red[3]) * (1.0f / DD);

    float c = v - mean;
    float s2 = c * c;
#pragma unroll
    for (int o = 32; o > 0; o >>= 1) s2 += __shfl_down(s2, o);
    if (lane == 0) red2[wave] = s2;
    __syncthreads();
    float var = (red2[0] + red2[1] + red2[2] + red2[3]) * (1.0f / DD);

    out[bt * DD + d] = f2bf(c * rsqrtf(var + 1e-5f) * g[d] + b[d]);
}

// ---------------------------------------------------------------------------
// bf16 MFMA NT GEMM, BK=64 (16 MFMA per barrier pair). From R5 (validated).
// ---------------------------------------------------------------------------
template<int BM, int BN, int OUT_BF16>
__global__ __launch_bounds__(256) void gemm_bf16(
    const u16* __restrict__ A, const u16* __restrict__ B,
    void* __restrict__ Cv, int M, int N, int K, int addC)
{
    constexpr int BK = 64;
    constexpr int MT = BM / 32;
    constexpr int NT = BN / 32;
    static_assert(BN == 64, "B staging assumes BN==64");

    __shared__ __align__(16) u16 Al[8][BM][8];
    __shared__ __align__(16) u16 Bl[8][BN][8];

    const int tid = threadIdx.x;
    const int bm = blockIdx.y * BM;
    const int bn = blockIdx.x * BN;
    const int wid = tid >> 6, lane = tid & 63;
    const int wm = wid >> 1, wn = wid & 1;
    const int lq = lane >> 4, lm = lane & 15;

    float4v acc[MT][NT];
#pragma unroll
    for (int i = 0; i < MT; i++)
#pragma unroll
        for (int j = 0; j < NT; j++) acc[i][j] = (float4v){0.f, 0.f, 0.f, 0.f};

    for (int k0 = 0; k0 < K; k0 += BK) {
#pragma unroll
        for (int it = 0; it < (8 * BM) / 256; it++) {
            int c = it * 256 + tid;
            int q = c / BM, row = c % BM;
            GLD_LDS16(A + (size_t)(bm + row) * K + k0 + q * 8, &Al[q][row][0]);
        }
#pragma unroll
        for (int it = 0; it < (8 * BN) / 256; it++) {
            int c = it * 256 + tid;
            int q = c / BN, row = c % BN;
            GLD_LDS16(B + (size_t)(bn + row) * K + k0 + q * 8, &Bl[q][row][0]);
        }
        __syncthreads();

        short8 af[2][MT], bf[2][NT];
#pragma unroll
        for (int kk = 0; kk < 2; kk++) {
#pragma unroll
            for (int mt = 0; mt < MT; mt++)
                af[kk][mt] = *(const short8*)&Al[kk * 4 + lq][wm * (BM / 2) + mt * 16 + lm][0];
#pragma unroll
            for (int nt = 0; nt < NT; nt++)
                bf[kk][nt] = *(const short8*)&Bl[kk * 4 + lq][wn * (BN / 2) + nt * 16 + lm][0];
        }

#pragma unroll
        for (int kk = 0; kk < 2; kk++)
#pragma unroll
            for (int mt = 0; mt < MT; mt++)
#pragma unroll
                for (int nt = 0; nt < NT; nt++)
                    acc[mt][nt] = __builtin_amdgcn_mfma_f32_16x16x32_bf16(
                        af[kk][mt], bf[kk][nt], acc[mt][nt], 0, 0, 0);
        __syncthreads();
    }

#pragma unroll
    for (int mt = 0; mt < MT; mt++)
#pragma unroll
        for (int nt = 0; nt < NT; nt++) {
            int row0 = bm + wm * (BM / 2) + mt * 16 + lq * 4;
            int col  = bn + wn * (BN / 2) + nt * 16 + lm;
#pragma unroll
            for (int r = 0; r < 4; r++) {
                float vv = acc[mt][nt][r];
                if (OUT_BF16) {
                    ((u16*)Cv)[(size_t)(row0 + r) * N + col] = f2bf(vv);
                } else {
                    float* cp = (float*)Cv + (size_t)(row0 + r) * N + col;
                    if (addC) vv += *cp;
                    *cp = vv;
                }
            }
        }
}

// ---------------------------------------------------------------------------
// Depthwise conv (k=3, pad 1) + SiLU; bf16 in/out, 8 elements/thread.
// ---------------------------------------------------------------------------
__global__ __launch_bounds__(256) void conv_silu_kernel(
    const u16* __restrict__ v, const float* __restrict__ w,
    u16* __restrict__ out)
{
    int base = (blockIdx.x * 256 + threadIdx.x) * 8;   // B*T*H elements
    int h0 = base & (HH - 1);
    int t  = (base >> 9) & (TT - 1);

    u16x8 x0 = *(const u16x8*)(v + base);
    u16x8 xm = (t > 0)      ? *(const u16x8*)(v + base - HH) : (u16x8)(0);
    u16x8 xp = (t < TT - 1) ? *(const u16x8*)(v + base + HH) : (u16x8)(0);

    const float* wp = w + h0 * 3;
    u16x8 o;
#pragma unroll
    for (int j = 0; j < 8; j++) {
        float a = wp[j * 3] * bf2f(xm[j]);
        a = fmaf(wp[j * 3 + 1], bf2f(x0[j]), a);
        a = fmaf(wp[j * 3 + 2], bf2f(xp[j]), a);
        o[j] = f2bf(a / (1.0f + __expf(-a)));
    }
    *(u16x8*)(out + base) = o;
}

// ---------------------------------------------------------------------------
// dt1: dtr[m,:] = relu(vs[m,:] . dt1_w[:,:] + dt1_b); one wave per row.
// Full occupancy (8192 waves), one butterfly per ROW (not per timestep).
// ---------------------------------------------------------------------------
__global__ __launch_bounds__(256) void dt1_kernel(
    const u16* __restrict__ vs, const float* __restrict__ w,
    const float* __restrict__ bias, float* __restrict__ dtr)
{
    int wave = threadIdx.x >> 6;
    int lane = threadIdx.x & 63;
    int m = blockIdx.x * 4 + wave;
    const u16* vrow = vs + (size_t)m * HH;

    float acc[RR];
#pragma unroll
    for (int r = 0; r < RR; r++) acc[r] = 0.0f;

#pragma unroll
    for (int j = 0; j < HH / 64; j++) {
        int hh = j * 64 + lane;
        float vv = bf2f(vrow[hh]);
#pragma unroll
        for (int r = 0; r < RR; r++) acc[r] = fmaf(vv, w[r * HH + hh], acc[r]);
    }
#pragma unroll
    for (int r = 0; r < RR; r++) {
#pragma unroll
        for (int o = 32; o > 0; o >>= 1) acc[r] += __shfl_down(acc[r], o);
    }
    if (lane == 0) {
#pragma unroll
        for (int r = 0; r < RR; r++)
            dtr[m * RR + r] = fmaxf(acc[r] + bias[r], 0.0f);
    }
}

// ---------------------------------------------------------------------------
// softplus (fast): log(1+e^s) with overflow guard
// ---------------------------------------------------------------------------
__device__ __forceinline__ float softplus_f(float s) {
    return (s > 20.0f) ? s : __logf(1.0f + __expf(s));
}

// ---------------------------------------------------------------------------
// Chunk-parallel selective scan with dt2+softplus fused (dtf buffer removed).
// Per thread h is fixed -> dt2_w row in registers; dtr row is block-uniform
// -> scalar broadcast loads, prefetched one step ahead.
// ---------------------------------------------------------------------------
__global__ __launch_bounds__(256) void scan_pass1(
    const u16* __restrict__ vs,      // (B,T,H) conv+silu out
    const float* __restrict__ dtr,   // (B*T,R) relu'd dt1 out
    const float* __restrict__ dt2_w, // (H,R)
    const float* __restrict__ dt2_b, // (H)
    const float* __restrict__ A_p,   // (H,N)
    float* __restrict__ Lst,         // (CC,B,H,N)
    float* __restrict__ sdt)         // (CC,B,H)
{
    int h = blockIdx.x * 256 + threadIdx.x;
    int c = blockIdx.y;
    int b = blockIdx.z;

    float A[NN], invA[NN], st[NN];
    const float* ap = A_p + h * NN;
#pragma unroll
    for (int n = 0; n < NN; n++) {
        float a = -__expf(ap[n]);
        A[n] = a; invA[n] = 1.0f / a; st[n] = 0.0f;
    }
    float w2[RR];
#pragma unroll
    for (int r = 0; r < RR; r++) w2[r] = dt2_w[h * RR + r];
    float b2 = dt2_b[h];

    const u16*   vbase = vs  + ((size_t)b * TT + (size_t)c * SC) * HH + h;
    const float* drow  = dtr + ((size_t)b * TT + (size_t)c * SC) * RR;

    float dr[RR];
#pragma unroll
    for (int r = 0; r < RR; r++) dr[r] = drow[r];

    float s_dt = 0.0f;
#pragma unroll 2
    for (int t = 0; t < SC; t++) {
        float drn[RR];
        if (t + 1 < SC) {
#pragma unroll
            for (int r = 0; r < RR; r++) drn[r] = drow[(t + 1) * RR + r];
        }
        float s = b2;
#pragma unroll
        for (int r = 0; r < RR; r++) s = fmaf(dr[r], w2[r], s);
        float dt = softplus_f(s);
        float xv = bf2f(vbase[(size_t)t * HH]);
        s_dt += dt;
#pragma unroll
        for (int n = 0; n < NN; n++) {
            float e  = __expf(A[n] * dt);
            float dB = (e - 1.0f) * invA[n] * dt;
            st[n] = fmaf(e, st[n], dB * xv);
        }
#pragma unroll
        for (int r = 0; r < RR; r++) dr[r] = drn[r];
    }

    size_t base = (((size_t)c * BB + b) * HH + h) * NN;
#pragma unroll
    for (int n = 0; n < NN; n += 4)
        *(float4*)(Lst + base + n) = make_float4(st[n], st[n+1], st[n+2], st[n+3]);
    sdt[((size_t)c * BB + b) * HH + h] = s_dt;
}

__global__ __launch_bounds__(256) void scan_carry(
    const float* __restrict__ A_p, const float* __restrict__ sdt,
    float* __restrict__ Lst)
{
    int i = blockIdx.x * 256 + threadIdx.x;   // (b*HH+h)*NN+n
    int n  = i & (NN - 1);
    int bh = i >> 4;
    int h  = bh & (HH - 1);
    int b  = bh >> 9;

    float A = -__expf(A_p[h * NN + n]);
    float E = 0.0f;
#pragma unroll
    for (int c = 0; c < CC; c++) {
        size_t sidx = ((size_t)c * BB + b) * HH + h;
        float P = __expf(A * sdt[sidx]);
        size_t lidx = sidx * NN + n;
        float Lc = Lst[lidx];
        Lst[lidx] = E;
        E = fmaf(P, E, Lc);
    }
}

__global__ __launch_bounds__(256) void scan_pass2(
    const u16* __restrict__ vs,
    const float* __restrict__ dtr,
    const float* __restrict__ dt2_w,
    const float* __restrict__ dt2_b,
    const float* __restrict__ A_p, const float* __restrict__ D_p,
    const float* __restrict__ carry,
    u16* __restrict__ y)               // (B,T,H) bf16
{
    int h = blockIdx.x * 256 + threadIdx.x;
    int c = blockIdx.y;
    int b = blockIdx.z;

    float A[NN], invA[NN], Ap[NN], st[NN];
    const float* app = A_p + h * NN;
    size_t cbase = (((size_t)c * BB + b) * HH + h) * NN;
#pragma unroll
    for (int n = 0; n < NN; n += 4) {
        float4 c4 = *(const float4*)(carry + cbase + n);
        st[n] = c4.x; st[n+1] = c4.y; st[n+2] = c4.z; st[n+3] = c4.w;
    }
#pragma unroll
    for (int n = 0; n < NN; n++) {
        float apv = app[n];
        Ap[n] = apv;
        float a = -__expf(apv);
        A[n] = a; invA[n] = 1.0f / a;
    }
    float w2[RR];
#pragma unroll
    for (int r = 0; r < RR; r++) w2[r] = dt2_w[h * RR + r];
    float b2 = dt2_b[h];
    float Dp = D_p[h];

    const u16*   vbase = vs  + ((size_t)b * TT + (size_t)c * SC) * HH + h;
    const float* drow  = dtr + ((size_t)b * TT + (size_t)c * SC) * RR;
    u16*         ybase = y   + ((size_t)b * TT + (size_t)c * SC) * HH + h;

    float dr[RR];
#pragma unroll
    for (int r = 0; r < RR; r++) dr[r] = drow[r];

#pragma unroll 2
    for (int t = 0; t < SC; t++) {
        float drn[RR];
        if (t + 1 < SC) {
#pragma unroll
            for (int r = 0; r < RR; r++) drn[r] = drow[(t + 1) * RR + r];
        }
        float s = b2;
#pragma unroll
        for (int r = 0; r < RR; r++) s = fmaf(dr[r], w2[r], s);
        float dt = softplus_f(s);
        float xv = bf2f(vbase[(size_t)t * HH]);
        float acc = Dp * xv;
#pragma unroll
        for (int n = 0; n < NN; n++) {
            float e  = __expf(A[n] * dt);
            float dB = (e - 1.0f) * invA[n] * dt;
            st[n] = fmaf(e, st[n], dB * xv);
            acc = fmaf(st[n], Ap[n], acc);
        }
        ybase[(size_t)t * HH] = f2bf(acc);
#pragma unroll
        for (int r = 0; r < RR; r++) dr[r] = drn[r];
    }
}

// ---------------------------------------------------------------------------
// Head: final LN on last token, head1+silu, head2. One block per batch.
// ---------------------------------------------------------------------------
__global__ __launch_bounds__(256) void head_kernel(
    const float* __restrict__ h,
    const float* __restrict__ fg, const float* __restrict__ fb,
    const float* __restrict__ w1, const float* __restrict__ b1,
    const float* __restrict__ w2, const float* __restrict__ b2,
    float* __restrict__ out)
{
    int b = blockIdx.x;
    int d = threadIdx.x;
    __shared__ float hn[DD], s1[DD];
    __shared__ float red[4];

    float v = h[((size_t)b * TT + (TT - 1)) * DD + d];

    float s = v;
#pragma unroll
    for (int o = 32; o > 0; o >>= 1) s += __shfl_down(s, o);
    int lane = d & 63, wave = d >> 6;
    if (lane == 0) red[wave] = s;
    __syncthreads();
    float mean = (red[0] + red[1] + red[2] + red[3]) * (1.0f / DD);
    __syncthreads();

    float c = v - mean;
    float s2 = c * c;
#pragma unroll
    for (int o = 32; o > 0; o >>= 1) s2 += __shfl_down(s2, o);
    if (lane == 0) red[wave] = s2;
    __syncthreads();
    float var = (red[0] + red[1] + red[2] + red[3]) * (1.0f / DD);

    hn[d] = c * rsqrtf(var + 1e-5f) * fg[d] + fb[d];
    __syncthreads();

    float a1 = b1[d];
    const float* w1r = w1 + d * DD;
#pragma unroll 8
    for (int k = 0; k < DD; k++) a1 = fmaf(hn[k], w1r[k], a1);
    s1[d] = a1 / (1.0f + __expf(-a1));
    __syncthreads();

    if (d < OUT_LEN) {
        float a2 = b2[d];
        const float* w2r = w2 + d * DD;
#pragma unroll 8
        for (int k = 0; k < DD; k++) a2 = fmaf(s1[k], w2r[k], a2);
        out[b * OUT_LEN + d] = a2;
    }
}

// ---------------------------------------------------------------------------
extern "C" void kernel_launch(void* const* d_in, const int* in_sizes, int n_in,
                              void* d_out, int out_size, void* d_ws, size_t ws_size,
                              hipStream_t stream)
{
    (void)in_sizes; (void)n_in; (void)out_size; (void)ws_size;

    const float* x       = (const float*)d_in[0];
    const float* emb_w   = (const float*)d_in[1];
    const float* emb_b   = (const float*)d_in[2];
    const float* norm_g  = (const float*)d_in[3];
    const float* norm_b  = (const float*)d_in[4];
    const float* in_w    = (const float*)d_in[5];
    const float* conv_w  = (const float*)d_in[6];
    const float* A_p     = (const float*)d_in[7];
    const float* D_p     = (const float*)d_in[8];
    const float* dt1_w   = (const float*)d_in[9];
    const float* dt1_b   = (const float*)d_in[10];
    const float* dt2_w   = (const float*)d_in[11];
    const float* dt2_b   = (const float*)d_in[12];
    const float* out_w   = (const float*)d_in[13];
    const float* final_g = (const float*)d_in[14];
    const float* final_b = (const float*)d_in[15];
    const float* head1_w = (const float*)d_in[16];
    const float* head1_b = (const float*)d_in[17];
    const float* head2_w = (const float*)d_in[18];
    const float* head2_b = (const float*)d_in[19];
    float* outp = (float*)d_out;

    char* ws = (char*)d_ws;
    float* h    = (float*)ws;                 ws += (size_t)MM * DD * 4;   // fp32 residual
    u16*   vbf  = (u16*)ws;                   ws += (size_t)MM * HH * 2;   // gemm1 out (bf16)
    u16*   vsb  = (u16*)ws;                   ws += (size_t)MM * HH * 2;   // conv+silu (bf16)
    u16*   yb_u = (u16*)ws;                   ws += (size_t)MM * HH * 2;   // ln-out / y (bf16)
    float* dtr  = (float*)ws;                 ws += (size_t)MM * RR * 4;   // dt1 out (fp32)
    float* Lst  = (float*)ws;                 ws += (size_t)CC * BB * HH * NN * 4;
    float* sdt  = (float*)ws;                 ws += (size_t)CC * BB * HH * 4;
    u16*   wbf_in  = (u16*)ws;                ws += (size_t)4 * HH * DD * 2;
    u16*   wbf_out = (u16*)ws;                ws += (size_t)4 * DD * HH * 2;

    cvt_bf16_kernel<<<(4 * HH * DD) / 256, 256, 0, stream>>>(in_w,  wbf_in,  4 * HH * DD);
    cvt_bf16_kernel<<<(4 * DD * HH) / 256, 256, 0, stream>>>(out_w, wbf_out, 4 * DD * HH);

    embed_kernel<<<MM, 256, 0, stream>>>(x, emb_w, emb_b, h);

    for (int l = 0; l < 4; l++) {
        ln_kernel<<<MM, 256, 0, stream>>>(h, norm_g + l * DD, norm_b + l * DD, yb_u);
        gemm_bf16<128, 64, 1><<<dim3(HH / 64, MM / 128), 256, 0, stream>>>(
            yb_u, wbf_in + (size_t)l * HH * DD, vbf, MM, HH, DD, 0);
        conv_silu_kernel<<<(MM * HH) / (256 * 8), 256, 0, stream>>>(
            vbf, conv_w + (size_t)l * HH * 3, vsb);
        dt1_kernel<<<MM / 4, 256, 0, stream>>>(
            vsb, dt1_w + (size_t)l * RR * HH, dt1_b + l * RR, dtr);

        scan_pass1<<<dim3(HH / 256, CC, BB), 256, 0, stream>>>(
            vsb, dtr, dt2_w + (size_t)l * HH * RR, dt2_b + l * HH,
            A_p + (size_t)l * HH * NN, Lst, sdt);
        scan_carry<<<(BB * HH * NN) / 256, 256, 0, stream>>>(
            A_p + (size_t)l * HH * NN, sdt, Lst);
        scan_pass2<<<dim3(HH / 256, CC, BB), 256, 0, stream>>>(
            vsb, dtr, dt2_w + (size_t)l * HH * RR, dt2_b + l * HH,
            A_p + (size_t)l * HH * NN, D_p + l * HH, Lst, yb_u);

        gemm_bf16<64, 64, 0><<<dim3(DD / 64, MM / 64), 256, 0, stream>>>(
            yb_u, wbf_out + (size_t)l * DD * HH, h, MM, DD, HH, 1);
    }

    head_kernel<<<BB, 256, 0, stream>>>(h, final_g, final_b,
                                        head1_w, head1_b, head2_w, head2_b, outp);
}

// Round 7
// 535.779 us; speedup vs baseline: 2.6651x; 1.0086x over previous
//
#include <hip/hip_runtime.h>
#include <hip/hip_bf16.h>
#include <math.h>

// Model dims
#define BB 8
#define TT 1024
#define DD 256
#define HH 512
#define NN 16
#define RR 8
#define OUT_LEN 96
#define IN_DIM 32
#define MM (BB*TT)   // 8192 rows

// scan chunking: 1024 blocks/pass = 4 waves/SIMD
#define SC 16
#define CC (TT/SC)   // 64

typedef unsigned short u16;
typedef unsigned int u32;
typedef __attribute__((ext_vector_type(8))) short short8;
typedef __attribute__((ext_vector_type(8))) unsigned short u16x8;
typedef __attribute__((ext_vector_type(4))) float float4v;

__device__ __forceinline__ u16 f2bf(float f) {
    __hip_bfloat16 h = __float2bfloat16(f);
    return *(u16*)&h;
}
__device__ __forceinline__ float bf2f(u16 u) {
    u32 v = ((u32)u) << 16;
    return *(float*)&v;
}

#define GLD_LDS16(src, dst) __builtin_amdgcn_global_load_lds( \
    (const __attribute__((address_space(1))) void*)(src),     \
    (__attribute__((address_space(3))) void*)(dst), 16, 0, 0)

// ---------------------------------------------------------------------------
// Embedding + positional encoding + first-layer LayerNorm (fused).
// Block = one (b,t) row; writes fp32 h (residual) and bf16 LN-out.
// ---------------------------------------------------------------------------
__global__ __launch_bounds__(256) void embed_ln_kernel(
    const float* __restrict__ x, const float* __restrict__ emb_w,
    const float* __restrict__ emb_b,
    const float* __restrict__ g, const float* __restrict__ b,
    float* __restrict__ h, u16* __restrict__ lnout)
{
    int bt = blockIdx.x;
    int d  = threadIdx.x;
    int t  = bt & (TT - 1);

    __shared__ float xs[IN_DIM];
    __shared__ float red[4], red2[4];
    if (threadIdx.x < IN_DIM) xs[threadIdx.x] = x[bt * IN_DIM + threadIdx.x];
    __syncthreads();

    const float* w = emb_w + d * IN_DIM;
    float acc = emb_b[d];
#pragma unroll
    for (int i = 0; i < IN_DIM; i++) acc = fmaf(xs[i], w[i], acc);

    int i2 = d & ~1;
    float div = expf(-(float)i2 * (logf(10000.0f) / (float)DD));
    float arg = (float)t * div;
    float pe = (d & 1) ? cosf(arg) : sinf(arg);
    float val = acc + pe;
    h[bt * DD + d] = val;

    // LN over the 256 values in-block
    float s = val;
#pragma unroll
    for (int o = 32; o > 0; o >>= 1) s += __shfl_down(s, o);
    int lane = d & 63, wave = d >> 6;
    if (lane == 0) red[wave] = s;
    __syncthreads();
    float mean = (red[0] + red[1] + red[2] + red[3]) * (1.0f / DD);

    float c = val - mean;
    float s2 = c * c;
#pragma unroll
    for (int o = 32; o > 0; o >>= 1) s2 += __shfl_down(s2, o);
    if (lane == 0) red2[wave] = s2;
    __syncthreads();
    float var = (red2[0] + red2[1] + red2[2] + red2[3]) * (1.0f / DD);

    lnout[bt * DD + d] = f2bf(c * rsqrtf(var + 1e-5f) * g[d] + b[d]);
}

// ---------------------------------------------------------------------------
// fp32 -> bf16 conversion of both weight tensors in one launch
// ---------------------------------------------------------------------------
__global__ __launch_bounds__(256) void cvt_bf16_kernel(
    const float* __restrict__ in1, u16* __restrict__ out1, int n1,
    const float* __restrict__ in2, u16* __restrict__ out2, int n2)
{
    int i = blockIdx.x * 256 + threadIdx.x;
    if (i < n1) out1[i] = f2bf(in1[i]);
    else if (i < n1 + n2) out2[i - n1] = f2bf(in2[i - n1]);
}

// ---------------------------------------------------------------------------
// LayerNorm over D=256 -> bf16 output (layers 1..3)
// ---------------------------------------------------------------------------
__global__ __launch_bounds__(256) void ln_kernel(
    const float* __restrict__ h, const float* __restrict__ g,
    const float* __restrict__ b, u16* __restrict__ out)
{
    int bt = blockIdx.x;
    int d  = threadIdx.x;
    float v = h[bt * DD + d];

    __shared__ float red[4], red2[4];
    float s = v;
#pragma unroll
    for (int o = 32; o > 0; o >>= 1) s += __shfl_down(s, o);
    int lane = d & 63, wave = d >> 6;
    if (lane == 0) red[wave] = s;
    __syncthreads();
    float mean = (red[0] + red[1] + red[2] + red[3]) * (1.0f / DD);

    float c = v - mean;
    float s2 = c * c;
#pragma unroll
    for (int o = 32; o > 0; o >>= 1) s2 += __shfl_down(s2, o);
    if (lane == 0) red2[wave] = s2;
    __syncthreads();
    float var = (red2[0] + red2[1] + red2[2] + red2[3]) * (1.0f / DD);

    out[bt * DD + d] = f2bf(c * rsqrtf(var + 1e-5f) * g[d] + b[d]);
}

// ---------------------------------------------------------------------------
// bf16 MFMA NT GEMM, BK=64 (validated R5/R6)
// ---------------------------------------------------------------------------
template<int BM, int BN, int OUT_BF16>
__global__ __launch_bounds__(256) void gemm_bf16(
    const u16* __restrict__ A, const u16* __restrict__ B,
    void* __restrict__ Cv, int M, int N, int K, int addC)
{
    constexpr int BK = 64;
    constexpr int MT = BM / 32;
    constexpr int NT = BN / 32;
    static_assert(BN == 64, "B staging assumes BN==64");

    __shared__ __align__(16) u16 Al[8][BM][8];
    __shared__ __align__(16) u16 Bl[8][BN][8];

    const int tid = threadIdx.x;
    const int bm = blockIdx.y * BM;
    const int bn = blockIdx.x * BN;
    const int wid = tid >> 6, lane = tid & 63;
    const int wm = wid >> 1, wn = wid & 1;
    const int lq = lane >> 4, lm = lane & 15;

    float4v acc[MT][NT];
#pragma unroll
    for (int i = 0; i < MT; i++)
#pragma unroll
        for (int j = 0; j < NT; j++) acc[i][j] = (float4v){0.f, 0.f, 0.f, 0.f};

    for (int k0 = 0; k0 < K; k0 += BK) {
#pragma unroll
        for (int it = 0; it < (8 * BM) / 256; it++) {
            int c = it * 256 + tid;
            int q = c / BM, row = c % BM;
            GLD_LDS16(A + (size_t)(bm + row) * K + k0 + q * 8, &Al[q][row][0]);
        }
#pragma unroll
        for (int it = 0; it < (8 * BN) / 256; it++) {
            int c = it * 256 + tid;
            int q = c / BN, row = c % BN;
            GLD_LDS16(B + (size_t)(bn + row) * K + k0 + q * 8, &Bl[q][row][0]);
        }
        __syncthreads();

        short8 af[2][MT], bf[2][NT];
#pragma unroll
        for (int kk = 0; kk < 2; kk++) {
#pragma unroll
            for (int mt = 0; mt < MT; mt++)
                af[kk][mt] = *(const short8*)&Al[kk * 4 + lq][wm * (BM / 2) + mt * 16 + lm][0];
#pragma unroll
            for (int nt = 0; nt < NT; nt++)
                bf[kk][nt] = *(const short8*)&Bl[kk * 4 + lq][wn * (BN / 2) + nt * 16 + lm][0];
        }

#pragma unroll
        for (int kk = 0; kk < 2; kk++)
#pragma unroll
            for (int mt = 0; mt < MT; mt++)
#pragma unroll
                for (int nt = 0; nt < NT; nt++)
                    acc[mt][nt] = __builtin_amdgcn_mfma_f32_16x16x32_bf16(
                        af[kk][mt], bf[kk][nt], acc[mt][nt], 0, 0, 0);
        __syncthreads();
    }

#pragma unroll
    for (int mt = 0; mt < MT; mt++)
#pragma unroll
        for (int nt = 0; nt < NT; nt++) {
            int row0 = bm + wm * (BM / 2) + mt * 16 + lq * 4;
            int col  = bn + wn * (BN / 2) + nt * 16 + lm;
#pragma unroll
            for (int r = 0; r < 4; r++) {
                float vv = acc[mt][nt][r];
                if (OUT_BF16) {
                    ((u16*)Cv)[(size_t)(row0 + r) * N + col] = f2bf(vv);
                } else {
                    float* cp = (float*)Cv + (size_t)(row0 + r) * N + col;
                    if (addC) vv += *cp;
                    *cp = vv;
                }
            }
        }
}

// ---------------------------------------------------------------------------
// Fused depthwise conv(k=3,pad1)+SiLU + dt1 (relu'd low-rank projection).
// Block = 4 rows, wave = one (b,t) row, lane = 8 contiguous h.
// dt1_w staged in LDS in lane-swizzled layout so per-row reads are
// conflict-free ds_read_b128: value (r, h=lane*8+jc*4+jm) lives at word
// (r*2+jc)*256 + lane*4 + jm.
// ---------------------------------------------------------------------------
__global__ __launch_bounds__(256) void conv_dt1_kernel(
    const u16* __restrict__ v,        // (B,T,H) bf16 gemm1 out
    const float* __restrict__ cwg,    // (H,3) conv weights
    const float* __restrict__ w1g,    // (R,H) dt1_w
    const float* __restrict__ b1g,    // (R)
    u16* __restrict__ vsb,            // (B,T,H) bf16 conv+silu
    float* __restrict__ dtr)          // (M,R) relu(dt1)
{
    __shared__ float w1s[RR * 2 * 256];   // 16 KB swizzled
    int tid = threadIdx.x;
    {
        int lane = tid & 63, rc = tid >> 6;
#pragma unroll
        for (int i = 0; i < 4; i++) {
            int rci = rc + i * 4;            // 0..15 = r*2+jc
            int r = rci >> 1, jc = rci & 1;
            float4 wv = *(const float4*)(w1g + r * HH + lane * 8 + jc * 4);
            *(float4*)&w1s[rci * 256 + lane * 4] = wv;
        }
    }
    __syncthreads();

    int wave = tid >> 6, lane = tid & 63;
    int m = blockIdx.x * 4 + wave;           // (b*TT + t)
    int t = m & (TT - 1);
    int h0 = lane * 8;

    const u16* vrow = v + (size_t)m * HH + h0;
    u16x8 x0 = *(const u16x8*)vrow;
    u16x8 xm = (t > 0)      ? *(const u16x8*)(vrow - HH) : (u16x8)(0);
    u16x8 xp = (t < TT - 1) ? *(const u16x8*)(vrow + HH) : (u16x8)(0);

    const float* wp = cwg + h0 * 3;
    float a[8];
    u16x8 o;
#pragma unroll
    for (int j = 0; j < 8; j++) {
        float s = wp[j * 3] * bf2f(xm[j]);
        s = fmaf(wp[j * 3 + 1], bf2f(x0[j]), s);
        s = fmaf(wp[j * 3 + 2], bf2f(xp[j]), s);
        s = s / (1.0f + __expf(-s));   // silu
        a[j] = s;
        o[j] = f2bf(s);
    }
    *(u16x8*)(vsb + (size_t)m * HH + h0) = o;

    // dt1: acc[r] = sum_j a[j] * w1[r][h0+j]
    float acc[RR];
#pragma unroll
    for (int r = 0; r < RR; r++) {
        float4 wlo = *(const float4*)&w1s[(r * 2 + 0) * 256 + lane * 4];
        float4 whi = *(const float4*)&w1s[(r * 2 + 1) * 256 + lane * 4];
        float s = a[0] * wlo.x;
        s = fmaf(a[1], wlo.y, s);
        s = fmaf(a[2], wlo.z, s);
        s = fmaf(a[3], wlo.w, s);
        s = fmaf(a[4], whi.x, s);
        s = fmaf(a[5], whi.y, s);
        s = fmaf(a[6], whi.z, s);
        s = fmaf(a[7], whi.w, s);
        acc[r] = s;
    }
#pragma unroll
    for (int r = 0; r < RR; r++) {
#pragma unroll
        for (int o2 = 1; o2 < 64; o2 <<= 1) acc[r] += __shfl_xor(acc[r], o2);
    }
    if (lane == 0) {
#pragma unroll
        for (int r = 0; r < RR; r++) acc[r] = fmaxf(acc[r] + b1g[r], 0.0f);
        *(float4*)(dtr + (size_t)m * RR)     = make_float4(acc[0], acc[1], acc[2], acc[3]);
        *(float4*)(dtr + (size_t)m * RR + 4) = make_float4(acc[4], acc[5], acc[6], acc[7]);
    }
}

// ---------------------------------------------------------------------------
__device__ __forceinline__ float softplus_f(float s) {
    return (s > 20.0f) ? s : __logf(1.0f + __expf(s));
}

// ---------------------------------------------------------------------------
// Chunk-parallel selective scan with dt2+softplus fused (validated R6).
// ---------------------------------------------------------------------------
__global__ __launch_bounds__(256) void scan_pass1(
    const u16* __restrict__ vs,      // (B,T,H)
    const float* __restrict__ dtr,   // (B*T,R)
    const float* __restrict__ dt2_w, // (H,R)
    const float* __restrict__ dt2_b, // (H)
    const float* __restrict__ A_p,   // (H,N)
    float* __restrict__ Lst,         // (CC,B,H,N)
    float* __restrict__ sdt)         // (CC,B,H)
{
    int h = blockIdx.x * 256 + threadIdx.x;
    int c = blockIdx.y;
    int b = blockIdx.z;

    float A[NN], invA[NN], st[NN];
    const float* ap = A_p + h * NN;
#pragma unroll
    for (int n = 0; n < NN; n++) {
        float a = -__expf(ap[n]);
        A[n] = a; invA[n] = 1.0f / a; st[n] = 0.0f;
    }
    float w2[RR];
#pragma unroll
    for (int r = 0; r < RR; r++) w2[r] = dt2_w[h * RR + r];
    float b2 = dt2_b[h];

    const u16*   vbase = vs  + ((size_t)b * TT + (size_t)c * SC) * HH + h;
    const float* drow  = dtr + ((size_t)b * TT + (size_t)c * SC) * RR;

    float dr[RR];
#pragma unroll
    for (int r = 0; r < RR; r++) dr[r] = drow[r];

    float s_dt = 0.0f;
#pragma unroll 2
    for (int t = 0; t < SC; t++) {
        float drn[RR];
        if (t + 1 < SC) {
#pragma unroll
            for (int r = 0; r < RR; r++) drn[r] = drow[(t + 1) * RR + r];
        }
        float s = b2;
#pragma unroll
        for (int r = 0; r < RR; r++) s = fmaf(dr[r], w2[r], s);
        float dt = softplus_f(s);
        float xv = bf2f(vbase[(size_t)t * HH]);
        s_dt += dt;
#pragma unroll
        for (int n = 0; n < NN; n++) {
            float e  = __expf(A[n] * dt);
            float dB = (e - 1.0f) * invA[n] * dt;
            st[n] = fmaf(e, st[n], dB * xv);
        }
#pragma unroll
        for (int r = 0; r < RR; r++) dr[r] = drn[r];
    }

    size_t base = (((size_t)c * BB + b) * HH + h) * NN;
#pragma unroll
    for (int n = 0; n < NN; n += 4)
        *(float4*)(Lst + base + n) = make_float4(st[n], st[n+1], st[n+2], st[n+3]);
    sdt[((size_t)c * BB + b) * HH + h] = s_dt;
}

__global__ __launch_bounds__(256) void scan_carry(
    const float* __restrict__ A_p, const float* __restrict__ sdt,
    float* __restrict__ Lst)
{
    int i = blockIdx.x * 256 + threadIdx.x;   // (b*HH+h)*NN+n
    int n  = i & (NN - 1);
    int bh = i >> 4;
    int h  = bh & (HH - 1);
    int b  = bh >> 9;

    float A = -__expf(A_p[h * NN + n]);
    float E = 0.0f;
    for (int c = 0; c < CC; c++) {
        size_t sidx = ((size_t)c * BB + b) * HH + h;
        float P = __expf(A * sdt[sidx]);
        size_t lidx = sidx * NN + n;
        float Lc = Lst[lidx];
        Lst[lidx] = E;
        E = fmaf(P, E, Lc);
    }
}

__global__ __launch_bounds__(256) void scan_pass2(
    const u16* __restrict__ vs,
    const float* __restrict__ dtr,
    const float* __restrict__ dt2_w,
    const float* __restrict__ dt2_b,
    const float* __restrict__ A_p, const float* __restrict__ D_p,
    const float* __restrict__ carry,
    u16* __restrict__ y)               // (B,T,H) bf16
{
    int h = blockIdx.x * 256 + threadIdx.x;
    int c = blockIdx.y;
    int b = blockIdx.z;

    float A[NN], invA[NN], Ap[NN], st[NN];
    const float* app = A_p + h * NN;
    size_t cbase = (((size_t)c * BB + b) * HH + h) * NN;
#pragma unroll
    for (int n = 0; n < NN; n += 4) {
        float4 c4 = *(const float4*)(carry + cbase + n);
        st[n] = c4.x; st[n+1] = c4.y; st[n+2] = c4.z; st[n+3] = c4.w;
    }
#pragma unroll
    for (int n = 0; n < NN; n++) {
        float apv = app[n];
        Ap[n] = apv;
        float a = -__expf(apv);
        A[n] = a; invA[n] = 1.0f / a;
    }
    float w2[RR];
#pragma unroll
    for (int r = 0; r < RR; r++) w2[r] = dt2_w[h * RR + r];
    float b2 = dt2_b[h];
    float Dp = D_p[h];

    const u16*   vbase = vs  + ((size_t)b * TT + (size_t)c * SC) * HH + h;
    const float* drow  = dtr + ((size_t)b * TT + (size_t)c * SC) * RR;
    u16*         ybase = y   + ((size_t)b * TT + (size_t)c * SC) * HH + h;

    float dr[RR];
#pragma unroll
    for (int r = 0; r < RR; r++) dr[r] = drow[r];

#pragma unroll 2
    for (int t = 0; t < SC; t++) {
        float drn[RR];
        if (t + 1 < SC) {
#pragma unroll
            for (int r = 0; r < RR; r++) drn[r] = drow[(t + 1) * RR + r];
        }
        float s = b2;
#pragma unroll
        for (int r = 0; r < RR; r++) s = fmaf(dr[r], w2[r], s);
        float dt = softplus_f(s);
        float xv = bf2f(vbase[(size_t)t * HH]);
        float acc = Dp * xv;
#pragma unroll
        for (int n = 0; n < NN; n++) {
            float e  = __expf(A[n] * dt);
            float dB = (e - 1.0f) * invA[n] * dt;
            st[n] = fmaf(e, st[n], dB * xv);
            acc = fmaf(st[n], Ap[n], acc);
        }
        ybase[(size_t)t * HH] = f2bf(acc);
#pragma unroll
        for (int r = 0; r < RR; r++) dr[r] = drn[r];
    }
}

// ---------------------------------------------------------------------------
// Head: final LN on last token, head1+silu, head2. One block per batch.
// ---------------------------------------------------------------------------
__global__ __launch_bounds__(256) void head_kernel(
    const float* __restrict__ h,
    const float* __restrict__ fg, const float* __restrict__ fb,
    const float* __restrict__ w1, const float* __restrict__ b1,
    const float* __restrict__ w2, const float* __restrict__ b2,
    float* __restrict__ out)
{
    int b = blockIdx.x;
    int d = threadIdx.x;
    __shared__ float hn[DD], s1[DD];
    __shared__ float red[4];

    float v = h[((size_t)b * TT + (TT - 1)) * DD + d];

    float s = v;
#pragma unroll
    for (int o = 32; o > 0; o >>= 1) s += __shfl_down(s, o);
    int lane = d & 63, wave = d >> 6;
    if (lane == 0) red[wave] = s;
    __syncthreads();
    float mean = (red[0] + red[1] + red[2] + red[3]) * (1.0f / DD);
    __syncthreads();

    float c = v - mean;
    float s2 = c * c;
#pragma unroll
    for (int o = 32; o > 0; o >>= 1) s2 += __shfl_down(s2, o);
    if (lane == 0) red[wave] = s2;
    __syncthreads();
    float var = (red[0] + red[1] + red[2] + red[3]) * (1.0f / DD);

    hn[d] = c * rsqrtf(var + 1e-5f) * fg[d] + fb[d];
    __syncthreads();

    float a1 = b1[d];
    const float* w1r = w1 + d * DD;
#pragma unroll 8
    for (int k = 0; k < DD; k++) a1 = fmaf(hn[k], w1r[k], a1);
    s1[d] = a1 / (1.0f + __expf(-a1));
    __syncthreads();

    if (d < OUT_LEN) {
        float a2 = b2[d];
        const float* w2r = w2 + d * DD;
#pragma unroll 8
        for (int k = 0; k < DD; k++) a2 = fmaf(s1[k], w2r[k], a2);
        out[b * OUT_LEN + d] = a2;
    }
}

// ---------------------------------------------------------------------------
extern "C" void kernel_launch(void* const* d_in, const int* in_sizes, int n_in,
                              void* d_out, int out_size, void* d_ws, size_t ws_size,
                              hipStream_t stream)
{
    (void)in_sizes; (void)n_in; (void)out_size; (void)ws_size;

    const float* x       = (const float*)d_in[0];
    const float* emb_w   = (const float*)d_in[1];
    const float* emb_b   = (const float*)d_in[2];
    const float* norm_g  = (const float*)d_in[3];
    const float* norm_b  = (const float*)d_in[4];
    const float* in_w    = (const float*)d_in[5];
    const float* conv_w  = (const float*)d_in[6];
    const float* A_p     = (const float*)d_in[7];
    const float* D_p     = (const float*)d_in[8];
    const float* dt1_w   = (const float*)d_in[9];
    const float* dt1_b   = (const float*)d_in[10];
    const float* dt2_w   = (const float*)d_in[11];
    const float* dt2_b   = (const float*)d_in[12];
    const float* out_w   = (const float*)d_in[13];
    const float* final_g = (const float*)d_in[14];
    const float* final_b = (const float*)d_in[15];
    const float* head1_w = (const float*)d_in[16];
    const float* head1_b = (const float*)d_in[17];
    const float* head2_w = (const float*)d_in[18];
    const float* head2_b = (const float*)d_in[19];
    float* outp = (float*)d_out;

    char* ws = (char*)d_ws;
    float* h    = (float*)ws;                 ws += (size_t)MM * DD * 4;   // fp32 residual
    u16*   vbf  = (u16*)ws;                   ws += (size_t)MM * HH * 2;   // gemm1 out (bf16)
    u16*   vsb  = (u16*)ws;                   ws += (size_t)MM * HH * 2;   // conv+silu (bf16)
    u16*   yb_u = (u16*)ws;                   ws += (size_t)MM * HH * 2;   // ln-out / y (bf16)
    float* dtr  = (float*)ws;                 ws += (size_t)MM * RR * 4;   // dt1 out (fp32)
    float* Lst  = (float*)ws;                 ws += (size_t)CC * BB * HH * NN * 4;
    float* sdt  = (float*)ws;                 ws += (size_t)CC * BB * HH * 4;
    u16*   wbf_in  = (u16*)ws;                ws += (size_t)4 * HH * DD * 2;
    u16*   wbf_out = (u16*)ws;                ws += (size_t)4 * DD * HH * 2;

    const int NW = 4 * HH * DD;
    cvt_bf16_kernel<<<(2 * NW) / 256, 256, 0, stream>>>(in_w, wbf_in, NW, out_w, wbf_out, NW);

    embed_ln_kernel<<<MM, 256, 0, stream>>>(x, emb_w, emb_b, norm_g, norm_b, h, yb_u);

    for (int l = 0; l < 4; l++) {
        if (l > 0)
            ln_kernel<<<MM, 256, 0, stream>>>(h, norm_g + l * DD, norm_b + l * DD, yb_u);
        gemm_bf16<128, 64, 1><<<dim3(HH / 64, MM / 128), 256, 0, stream>>>(
            yb_u, wbf_in + (size_t)l * HH * DD, vbf, MM, HH, DD, 0);
        conv_dt1_kernel<<<MM / 4, 256, 0, stream>>>(
            vbf, conv_w + (size_t)l * HH * 3,
            dt1_w + (size_t)l * RR * HH, dt1_b + l * RR, vsb, dtr);

        scan_pass1<<<dim3(HH / 256, CC, BB), 256, 0, stream>>>(
            vsb, dtr, dt2_w + (size_t)l * HH * RR, dt2_b + l * HH,
            A_p + (size_t)l * HH * NN, Lst, sdt);
        scan_carry<<<(BB * HH * NN) / 256, 256, 0, stream>>>(
            A_p + (size_t)l * HH * NN, sdt, Lst);
        scan_pass2<<<dim3(HH / 256, CC, BB), 256, 0, stream>>>(
            vsb, dtr, dt2_w + (size_t)l * HH * RR, dt2_b + l * HH,
            A_p + (size_t)l * HH * NN, D_p + l * HH, Lst, yb_u);

        gemm_bf16<64, 64, 0><<<dim3(DD / 64, MM / 64), 256, 0, stream>>>(
            yb_u, wbf_out + (size_t)l * DD * HH, h, MM, DD, HH, 1);
    }

    head_kernel<<<BB, 256, 0, stream>>>(h, final_g, final_b,
                                        head1_w, head1_b, head2_w, head2_b, outp);
}

// Round 9
// 526.190 us; speedup vs baseline: 2.7136x; 1.0182x over previous
//
#include <hip/hip_runtime.h>
#include <hip/hip_bf16.h>
#include <math.h>

// Model dims
#define BB 8
#define TT 1024
#define DD 256
#define HH 512
#define NN 16
#define RR 8
#define OUT_LEN 96
#define IN_DIM 32
#define MM (BB*TT)   // 8192 rows

// scan chunking (validated R7): 1024 blocks/pass = 4 waves/SIMD
#define SC 16
#define CC (TT/SC)   // 64

typedef unsigned short u16;
typedef unsigned int u32;
typedef __attribute__((ext_vector_type(8))) short short8;
typedef __attribute__((ext_vector_type(8))) unsigned short u16x8;
typedef __attribute__((ext_vector_type(4))) float float4v;

__device__ __forceinline__ u16 f2bf(float f) {
    __hip_bfloat16 h = __float2bfloat16(f);
    return *(u16*)&h;
}
__device__ __forceinline__ float bf2f(u16 u) {
    u32 v = ((u32)u) << 16;
    return *(float*)&v;
}

#define GLD_LDS16(src, dst) __builtin_amdgcn_global_load_lds( \
    (const __attribute__((address_space(1))) void*)(src),     \
    (__attribute__((address_space(3))) void*)(dst), 16, 0, 0)

// ---------------------------------------------------------------------------
// Embedding + positional encoding + layer-0 LayerNorm (validated R7/R8)
// ---------------------------------------------------------------------------
__global__ __launch_bounds__(256) void embed_ln_kernel(
    const float* __restrict__ x, const float* __restrict__ emb_w,
    const float* __restrict__ emb_b,
    const float* __restrict__ g, const float* __restrict__ b,
    float* __restrict__ h, u16* __restrict__ lnout)
{
    int bt = blockIdx.x;
    int d  = threadIdx.x;
    int t  = bt & (TT - 1);

    __shared__ float xs[IN_DIM];
    __shared__ float red[4], red2[4];
    if (threadIdx.x < IN_DIM) xs[threadIdx.x] = x[bt * IN_DIM + threadIdx.x];
    __syncthreads();

    const float* w = emb_w + d * IN_DIM;
    float acc = emb_b[d];
#pragma unroll
    for (int i = 0; i < IN_DIM; i++) acc = fmaf(xs[i], w[i], acc);

    int i2 = d & ~1;
    float div = expf(-(float)i2 * (logf(10000.0f) / (float)DD));
    float arg = (float)t * div;
    float pe = (d & 1) ? cosf(arg) : sinf(arg);
    float val = acc + pe;
    h[bt * DD + d] = val;

    float s = val;
#pragma unroll
    for (int o = 32; o > 0; o >>= 1) s += __shfl_down(s, o);
    int lane = d & 63, wave = d >> 6;
    if (lane == 0) red[wave] = s;
    __syncthreads();
    float mean = (red[0] + red[1] + red[2] + red[3]) * (1.0f / DD);

    float c = val - mean;
    float s2 = c * c;
#pragma unroll
    for (int o = 32; o > 0; o >>= 1) s2 += __shfl_down(s2, o);
    if (lane == 0) red2[wave] = s2;
    __syncthreads();
    float var = (red2[0] + red2[1] + red2[2] + red2[3]) * (1.0f / DD);

    lnout[bt * DD + d] = f2bf(c * rsqrtf(var + 1e-5f) * g[d] + b[d]);
}

// ---------------------------------------------------------------------------
// fp32 -> bf16 conversion of both weight tensors in one launch
// ---------------------------------------------------------------------------
__global__ __launch_bounds__(256) void cvt_bf16_kernel(
    const float* __restrict__ in1, u16* __restrict__ out1, int n1,
    const float* __restrict__ in2, u16* __restrict__ out2, int n2)
{
    int i = blockIdx.x * 256 + threadIdx.x;
    if (i < n1) out1[i] = f2bf(in1[i]);
    else if (i < n1 + n2) out2[i - n1] = f2bf(in2[i - n1]);
}

// ---------------------------------------------------------------------------
// bf16 MFMA NT GEMM, BK=64 (validated R5-R7). In-projection.
// ---------------------------------------------------------------------------
template<int BM, int BN, int OUT_BF16>
__global__ __launch_bounds__(256) void gemm_bf16(
    const u16* __restrict__ A, const u16* __restrict__ B,
    void* __restrict__ Cv, int M, int N, int K, int addC)
{
    constexpr int BK = 64;
    constexpr int MT = BM / 32;
    constexpr int NT = BN / 32;
    static_assert(BN == 64, "B staging assumes BN==64");

    __shared__ __align__(16) u16 Al[8][BM][8];
    __shared__ __align__(16) u16 Bl[8][BN][8];

    const int tid = threadIdx.x;
    const int bm = blockIdx.y * BM;
    const int bn = blockIdx.x * BN;
    const int wid = tid >> 6, lane = tid & 63;
    const int wm = wid >> 1, wn = wid & 1;
    const int lq = lane >> 4, lm = lane & 15;

    float4v acc[MT][NT];
#pragma unroll
    for (int i = 0; i < MT; i++)
#pragma unroll
        for (int j = 0; j < NT; j++) acc[i][j] = (float4v){0.f, 0.f, 0.f, 0.f};

    for (int k0 = 0; k0 < K; k0 += BK) {
#pragma unroll
        for (int it = 0; it < (8 * BM) / 256; it++) {
            int c = it * 256 + tid;
            int q = c / BM, row = c % BM;
            GLD_LDS16(A + (size_t)(bm + row) * K + k0 + q * 8, &Al[q][row][0]);
        }
#pragma unroll
        for (int it = 0; it < (8 * BN) / 256; it++) {
            int c = it * 256 + tid;
            int q = c / BN, row = c % BN;
            GLD_LDS16(B + (size_t)(bn + row) * K + k0 + q * 8, &Bl[q][row][0]);
        }
        __syncthreads();

        short8 af[2][MT], bf[2][NT];
#pragma unroll
        for (int kk = 0; kk < 2; kk++) {
#pragma unroll
            for (int mt = 0; mt < MT; mt++)
                af[kk][mt] = *(const short8*)&Al[kk * 4 + lq][wm * (BM / 2) + mt * 16 + lm][0];
#pragma unroll
            for (int nt = 0; nt < NT; nt++)
                bf[kk][nt] = *(const short8*)&Bl[kk * 4 + lq][wn * (BN / 2) + nt * 16 + lm][0];
        }

#pragma unroll
        for (int kk = 0; kk < 2; kk++)
#pragma unroll
            for (int mt = 0; mt < MT; mt++)
#pragma unroll
                for (int nt = 0; nt < NT; nt++)
                    acc[mt][nt] = __builtin_amdgcn_mfma_f32_16x16x32_bf16(
                        af[kk][mt], bf[kk][nt], acc[mt][nt], 0, 0, 0);
        __syncthreads();
    }

#pragma unroll
    for (int mt = 0; mt < MT; mt++)
#pragma unroll
        for (int nt = 0; nt < NT; nt++) {
            int row0 = bm + wm * (BM / 2) + mt * 16 + lq * 4;
            int col  = bn + wn * (BN / 2) + nt * 16 + lm;
#pragma unroll
            for (int r = 0; r < 4; r++) {
                float vv = acc[mt][nt][r];
                if (OUT_BF16) {
                    ((u16*)Cv)[(size_t)(row0 + r) * N + col] = f2bf(vv);
                } else {
                    float* cp = (float*)Cv + (size_t)(row0 + r) * N + col;
                    if (addC) vv += *cp;
                    *cp = vv;
                }
            }
        }
}

// ---------------------------------------------------------------------------
// Out-projection GEMM + residual add + next-layer LayerNorm (from R8; staging
// verified contiguous for wave-uniform global_load_lds: A dst offset == tid*16,
// B dst offset == c*16 within each 256-chunk sweep).
// BM=32 x BN=256 full-width so each block owns complete rows.
// ---------------------------------------------------------------------------
__global__ __launch_bounds__(256) void gemm2_ln(
    const u16* __restrict__ A, const u16* __restrict__ B,
    float* __restrict__ h,
    const float* __restrict__ g, const float* __restrict__ bb,
    u16* __restrict__ lnout, int doLN)
{
    constexpr int BM = 32;
    __shared__ __align__(16) u16 Al[8][BM][8];   // 4 KB
    __shared__ __align__(16) u16 Bl[8][256][8];  // 32 KB
    __shared__ float rs[2][BM], qs[2][BM];

    const int tid = threadIdx.x;
    const int bm = blockIdx.x * BM;
    const int wid = tid >> 6, lane = tid & 63;
    const int wm = wid >> 1, wn = wid & 1;       // wave = 16 rows x 128 cols
    const int lq = lane >> 4, lm = lane & 15;

    float4v acc[8];
#pragma unroll
    for (int j = 0; j < 8; j++) acc[j] = (float4v){0.f, 0.f, 0.f, 0.f};

    for (int k0 = 0; k0 < 512; k0 += 64) {
        {   // A: 256 chunks, 1/thread; LDS offset = tid*16 (contiguous)
            int q = tid >> 5, row = tid & 31;
            GLD_LDS16(A + (size_t)(bm + row) * 512 + k0 + q * 8, &Al[q][row][0]);
        }
#pragma unroll
        for (int it = 0; it < 8; it++) {   // B: 2048 chunks, 8/thread
            int c = it * 256 + tid;
            int q = c >> 8, row = c & 255;
            GLD_LDS16(B + (size_t)row * 512 + k0 + q * 8, &Bl[q][row][0]);
        }
        __syncthreads();

        short8 af[2], bf[2][8];
#pragma unroll
        for (int kk = 0; kk < 2; kk++) {
            af[kk] = *(const short8*)&Al[kk * 4 + lq][wm * 16 + lm][0];
#pragma unroll
            for (int nt = 0; nt < 8; nt++)
                bf[kk][nt] = *(const short8*)&Bl[kk * 4 + lq][wn * 128 + nt * 16 + lm][0];
        }
#pragma unroll
        for (int kk = 0; kk < 2; kk++)
#pragma unroll
            for (int nt = 0; nt < 8; nt++)
                acc[nt] = __builtin_amdgcn_mfma_f32_16x16x32_bf16(
                    af[kk], bf[kk][nt], acc[nt], 0, 0, 0);
        __syncthreads();
    }

    // epilogue: residual add + row sums for LN
    float val[4][8];
    float s1[4] = {0.f, 0.f, 0.f, 0.f}, s2[4] = {0.f, 0.f, 0.f, 0.f};
#pragma unroll
    for (int r = 0; r < 4; r++) {
        int row = bm + wm * 16 + lq * 4 + r;
#pragma unroll
        for (int nt = 0; nt < 8; nt++) {
            int col = wn * 128 + nt * 16 + lm;
            float v = acc[nt][r] + h[(size_t)row * DD + col];
            val[r][nt] = v;
            s1[r] += v;
            s2[r] = fmaf(v, v, s2[r]);
            h[(size_t)row * DD + col] = v;
        }
    }
#pragma unroll
    for (int r = 0; r < 4; r++) {
#pragma unroll
        for (int o = 1; o < 16; o <<= 1) {
            s1[r] += __shfl_xor(s1[r], o);
            s2[r] += __shfl_xor(s2[r], o);
        }
    }
    if (lm == 0) {
#pragma unroll
        for (int r = 0; r < 4; r++) {
            rs[wn][wm * 16 + lq * 4 + r] = s1[r];
            qs[wn][wm * 16 + lq * 4 + r] = s2[r];
        }
    }
    __syncthreads();

    if (doLN) {
#pragma unroll
        for (int r = 0; r < 4; r++) {
            int i = wm * 16 + lq * 4 + r;
            int row = bm + i;
            float mean = (rs[0][i] + rs[1][i]) * (1.0f / DD);
            float var  = (qs[0][i] + qs[1][i]) * (1.0f / DD) - mean * mean;
            float rstd = rsqrtf(var + 1e-5f);
#pragma unroll
            for (int nt = 0; nt < 8; nt++) {
                int col = wn * 128 + nt * 16 + lm;
                lnout[(size_t)row * DD + col] =
                    f2bf((val[r][nt] - mean) * rstd * g[col] + bb[col]);
            }
        }
    }
}

// ---------------------------------------------------------------------------
// Fused depthwise conv(k=3,pad1)+SiLU + dt1 (validated R7)
// ---------------------------------------------------------------------------
__global__ __launch_bounds__(256) void conv_dt1_kernel(
    const u16* __restrict__ v, const float* __restrict__ cwg,
    const float* __restrict__ w1g, const float* __restrict__ b1g,
    u16* __restrict__ vsb, float* __restrict__ dtr)
{
    __shared__ float w1s[RR * 2 * 256];
    int tid = threadIdx.x;
    {
        int lane = tid & 63, rc = tid >> 6;
#pragma unroll
        for (int i = 0; i < 4; i++) {
            int rci = rc + i * 4;
            int r = rci >> 1, jc = rci & 1;
            float4 wv = *(const float4*)(w1g + r * HH + lane * 8 + jc * 4);
            *(float4*)&w1s[rci * 256 + lane * 4] = wv;
        }
    }
    __syncthreads();

    int wave = tid >> 6, lane = tid & 63;
    int m = blockIdx.x * 4 + wave;
    int t = m & (TT - 1);
    int h0 = lane * 8;

    const u16* vrow = v + (size_t)m * HH + h0;
    u16x8 x0 = *(const u16x8*)vrow;
    u16x8 xm = (t > 0)      ? *(const u16x8*)(vrow - HH) : (u16x8)(0);
    u16x8 xp = (t < TT - 1) ? *(const u16x8*)(vrow + HH) : (u16x8)(0);

    const float* wp = cwg + h0 * 3;
    float a[8];
    u16x8 o;
#pragma unroll
    for (int j = 0; j < 8; j++) {
        float s = wp[j * 3] * bf2f(xm[j]);
        s = fmaf(wp[j * 3 + 1], bf2f(x0[j]), s);
        s = fmaf(wp[j * 3 + 2], bf2f(xp[j]), s);
        s = s / (1.0f + __expf(-s));
        a[j] = s;
        o[j] = f2bf(s);
    }
    *(u16x8*)(vsb + (size_t)m * HH + h0) = o;

    float acc[RR];
#pragma unroll
    for (int r = 0; r < RR; r++) {
        float4 wlo = *(const float4*)&w1s[(r * 2 + 0) * 256 + lane * 4];
        float4 whi = *(const float4*)&w1s[(r * 2 + 1) * 256 + lane * 4];
        float s = a[0] * wlo.x;
        s = fmaf(a[1], wlo.y, s);
        s = fmaf(a[2], wlo.z, s);
        s = fmaf(a[3], wlo.w, s);
        s = fmaf(a[4], whi.x, s);
        s = fmaf(a[5], whi.y, s);
        s = fmaf(a[6], whi.z, s);
        s = fmaf(a[7], whi.w, s);
        acc[r] = s;
    }
#pragma unroll
    for (int r = 0; r < RR; r++) {
#pragma unroll
        for (int o2 = 1; o2 < 64; o2 <<= 1) acc[r] += __shfl_xor(acc[r], o2);
    }
    if (lane == 0) {
#pragma unroll
        for (int r = 0; r < RR; r++) acc[r] = fmaxf(acc[r] + b1g[r], 0.0f);
        *(float4*)(dtr + (size_t)m * RR)     = make_float4(acc[0], acc[1], acc[2], acc[3]);
        *(float4*)(dtr + (size_t)m * RR + 4) = make_float4(acc[4], acc[5], acc[6], acc[7]);
    }
}

// ---------------------------------------------------------------------------
__device__ __forceinline__ float softplus_f(float s) {
    return (s > 20.0f) ? s : __logf(1.0f + __expf(s));
}

// ---------------------------------------------------------------------------
// Chunk-parallel selective scan, 3 kernels (validated R7).
// ---------------------------------------------------------------------------
__global__ __launch_bounds__(256) void scan_pass1(
    const u16* __restrict__ vs, const float* __restrict__ dtr,
    const float* __restrict__ dt2_w, const float* __restrict__ dt2_b,
    const float* __restrict__ A_p,
    float* __restrict__ Lst, float* __restrict__ sdt)
{
    int h = blockIdx.x * 256 + threadIdx.x;
    int c = blockIdx.y;
    int b = blockIdx.z;

    float A[NN], invA[NN], st[NN];
    const float* ap = A_p + h * NN;
#pragma unroll
    for (int n = 0; n < NN; n++) {
        float a = -__expf(ap[n]);
        A[n] = a; invA[n] = 1.0f / a; st[n] = 0.0f;
    }
    float w2[RR];
#pragma unroll
    for (int r = 0; r < RR; r++) w2[r] = dt2_w[h * RR + r];
    float b2 = dt2_b[h];

    const u16*   vbase = vs  + ((size_t)b * TT + (size_t)c * SC) * HH + h;
    const float* drow  = dtr + ((size_t)b * TT + (size_t)c * SC) * RR;

    float dr[RR];
#pragma unroll
    for (int r = 0; r < RR; r++) dr[r] = drow[r];

    float s_dt = 0.0f;
#pragma unroll 2
    for (int t = 0; t < SC; t++) {
        float drn[RR];
        if (t + 1 < SC) {
#pragma unroll
            for (int r = 0; r < RR; r++) drn[r] = drow[(t + 1) * RR + r];
        }
        float s = b2;
#pragma unroll
        for (int r = 0; r < RR; r++) s = fmaf(dr[r], w2[r], s);
        float dt = softplus_f(s);
        float xv = bf2f(vbase[(size_t)t * HH]);
        s_dt += dt;
#pragma unroll
        for (int n = 0; n < NN; n++) {
            float e  = __expf(A[n] * dt);
            float dB = (e - 1.0f) * invA[n] * dt;
            st[n] = fmaf(e, st[n], dB * xv);
        }
#pragma unroll
        for (int r = 0; r < RR; r++) dr[r] = drn[r];
    }

    size_t base = (((size_t)c * BB + b) * HH + h) * NN;
#pragma unroll
    for (int n = 0; n < NN; n += 4)
        *(float4*)(Lst + base + n) = make_float4(st[n], st[n+1], st[n+2], st[n+3]);
    sdt[((size_t)c * BB + b) * HH + h] = s_dt;
}

__global__ __launch_bounds__(256) void scan_carry(
    const float* __restrict__ A_p, const float* __restrict__ sdt,
    float* __restrict__ Lst)
{
    int i = blockIdx.x * 256 + threadIdx.x;   // (b*HH+h)*NN+n
    int n  = i & (NN - 1);
    int bh = i >> 4;
    int h  = bh & (HH - 1);
    int b  = bh >> 9;

    float A = -__expf(A_p[h * NN + n]);
    float E = 0.0f;
    for (int c = 0; c < CC; c++) {
        size_t sidx = ((size_t)c * BB + b) * HH + h;
        float P = __expf(A * sdt[sidx]);
        size_t lidx = sidx * NN + n;
        float Lc = Lst[lidx];
        Lst[lidx] = E;
        E = fmaf(P, E, Lc);
    }
}

__global__ __launch_bounds__(256) void scan_pass2(
    const u16* __restrict__ vs,
    const float* __restrict__ dtr,
    const float* __restrict__ dt2_w,
    const float* __restrict__ dt2_b,
    const float* __restrict__ A_p, const float* __restrict__ D_p,
    const float* __restrict__ carry,
    u16* __restrict__ y)
{
    int h = blockIdx.x * 256 + threadIdx.x;
    int c = blockIdx.y;
    int b = blockIdx.z;

    float A[NN], invA[NN], Ap[NN], st[NN];
    const float* app = A_p + h * NN;
    size_t cbase = (((size_t)c * BB + b) * HH + h) * NN;
#pragma unroll
    for (int n = 0; n < NN; n += 4) {
        float4 c4 = *(const float4*)(carry + cbase + n);
        st[n] = c4.x; st[n+1] = c4.y; st[n+2] = c4.z; st[n+3] = c4.w;
    }
#pragma unroll
    for (int n = 0; n < NN; n++) {
        float apv = app[n];
        Ap[n] = apv;
        float a = -__expf(apv);
        A[n] = a; invA[n] = 1.0f / a;
    }
    float w2[RR];
#pragma unroll
    for (int r = 0; r < RR; r++) w2[r] = dt2_w[h * RR + r];
    float b2 = dt2_b[h];
    float Dp = D_p[h];

    const u16*   vbase = vs  + ((size_t)b * TT + (size_t)c * SC) * HH + h;
    const float* drow  = dtr + ((size_t)b * TT + (size_t)c * SC) * RR;
    u16*         ybase = y   + ((size_t)b * TT + (size_t)c * SC) * HH + h;

    float dr[RR];
#pragma unroll
    for (int r = 0; r < RR; r++) dr[r] = drow[r];

#pragma unroll 2
    for (int t = 0; t < SC; t++) {
        float drn[RR];
        if (t + 1 < SC) {
#pragma unroll
            for (int r = 0; r < RR; r++) drn[r] = drow[(t + 1) * RR + r];
        }
        float s = b2;
#pragma unroll
        for (int r = 0; r < RR; r++) s = fmaf(dr[r], w2[r], s);
        float dt = softplus_f(s);
        float xv = bf2f(vbase[(size_t)t * HH]);
        float acc = Dp * xv;
#pragma unroll
        for (int n = 0; n < NN; n++) {
            float e  = __expf(A[n] * dt);
            float dB = (e - 1.0f) * invA[n] * dt;
            st[n] = fmaf(e, st[n], dB * xv);
            acc = fmaf(st[n], Ap[n], acc);
        }
        ybase[(size_t)t * HH] = f2bf(acc);
#pragma unroll
        for (int r = 0; r < RR; r++) dr[r] = drn[r];
    }
}

// ---------------------------------------------------------------------------
// Head: final LN on last token, head1+silu, head2. One block per batch.
// ---------------------------------------------------------------------------
__global__ __launch_bounds__(256) void head_kernel(
    const float* __restrict__ h,
    const float* __restrict__ fg, const float* __restrict__ fb,
    const float* __restrict__ w1, const float* __restrict__ b1,
    const float* __restrict__ w2, const float* __restrict__ b2,
    float* __restrict__ out)
{
    int b = blockIdx.x;
    int d = threadIdx.x;
    __shared__ float hn[DD], s1[DD];
    __shared__ float red[4];

    float v = h[((size_t)b * TT + (TT - 1)) * DD + d];

    float s = v;
#pragma unroll
    for (int o = 32; o > 0; o >>= 1) s += __shfl_down(s, o);
    int lane = d & 63, wave = d >> 6;
    if (lane == 0) red[wave] = s;
    __syncthreads();
    float mean = (red[0] + red[1] + red[2] + red[3]) * (1.0f / DD);
    __syncthreads();

    float c = v - mean;
    float s2 = c * c;
#pragma unroll
    for (int o = 32; o > 0; o >>= 1) s2 += __shfl_down(s2, o);
    if (lane == 0) red[wave] = s2;
    __syncthreads();
    float var = (red[0] + red[1] + red[2] + red[3]) * (1.0f / DD);

    hn[d] = c * rsqrtf(var + 1e-5f) * fg[d] + fb[d];
    __syncthreads();

    float a1 = b1[d];
    const float* w1r = w1 + d * DD;
#pragma unroll 8
    for (int k = 0; k < DD; k++) a1 = fmaf(hn[k], w1r[k], a1);
    s1[d] = a1 / (1.0f + __expf(-a1));
    __syncthreads();

    if (d < OUT_LEN) {
        float a2 = b2[d];
        const float* w2r = w2 + d * DD;
#pragma unroll 8
        for (int k = 0; k < DD; k++) a2 = fmaf(s1[k], w2r[k], a2);
        out[b * OUT_LEN + d] = a2;
    }
}

// ---------------------------------------------------------------------------
extern "C" void kernel_launch(void* const* d_in, const int* in_sizes, int n_in,
                              void* d_out, int out_size, void* d_ws, size_t ws_size,
                              hipStream_t stream)
{
    (void)in_sizes; (void)n_in; (void)out_size; (void)ws_size;

    const float* x       = (const float*)d_in[0];
    const float* emb_w   = (const float*)d_in[1];
    const float* emb_b   = (const float*)d_in[2];
    const float* norm_g  = (const float*)d_in[3];
    const float* norm_b  = (const float*)d_in[4];
    const float* in_w    = (const float*)d_in[5];
    const float* conv_w  = (const float*)d_in[6];
    const float* A_p     = (const float*)d_in[7];
    const float* D_p     = (const float*)d_in[8];
    const float* dt1_w   = (const float*)d_in[9];
    const float* dt1_b   = (const float*)d_in[10];
    const float* dt2_w   = (const float*)d_in[11];
    const float* dt2_b   = (const float*)d_in[12];
    const float* out_w   = (const float*)d_in[13];
    const float* final_g = (const float*)d_in[14];
    const float* final_b = (const float*)d_in[15];
    const float* head1_w = (const float*)d_in[16];
    const float* head1_b = (const float*)d_in[17];
    const float* head2_w = (const float*)d_in[18];
    const float* head2_b = (const float*)d_in[19];
    float* outp = (float*)d_out;

    char* ws = (char*)d_ws;
    float* h     = (float*)ws;                ws += (size_t)MM * DD * 4;   // fp32 residual
    u16*   vbf   = (u16*)ws;                  ws += (size_t)MM * HH * 2;   // gemm1 out
    u16*   vsb   = (u16*)ws;                  ws += (size_t)MM * HH * 2;   // conv+silu
    u16*   ybf   = (u16*)ws;                  ws += (size_t)MM * HH * 2;   // scan y
    u16*   lnbuf = (u16*)ws;                  ws += (size_t)MM * DD * 2;   // LN out
    float* dtr   = (float*)ws;                ws += (size_t)MM * RR * 4;
    float* Lst   = (float*)ws;                ws += (size_t)CC * BB * HH * NN * 4;
    float* sdt   = (float*)ws;                ws += (size_t)CC * BB * HH * 4;
    u16*   wbf_in  = (u16*)ws;                ws += (size_t)4 * HH * DD * 2;
    u16*   wbf_out = (u16*)ws;                ws += (size_t)4 * DD * HH * 2;

    const int NW = 4 * HH * DD;
    cvt_bf16_kernel<<<(2 * NW) / 256, 256, 0, stream>>>(in_w, wbf_in, NW, out_w, wbf_out, NW);

    embed_ln_kernel<<<MM, 256, 0, stream>>>(x, emb_w, emb_b, norm_g, norm_b, h, lnbuf);

    for (int l = 0; l < 4; l++) {
        gemm_bf16<128, 64, 1><<<dim3(HH / 64, MM / 128), 256, 0, stream>>>(
            lnbuf, wbf_in + (size_t)l * HH * DD, vbf, MM, HH, DD, 0);
        conv_dt1_kernel<<<MM / 4, 256, 0, stream>>>(
            vbf, conv_w + (size_t)l * HH * 3,
            dt1_w + (size_t)l * RR * HH, dt1_b + l * RR, vsb, dtr);

        scan_pass1<<<dim3(HH / 256, CC, BB), 256, 0, stream>>>(
            vsb, dtr, dt2_w + (size_t)l * HH * RR, dt2_b + l * HH,
            A_p + (size_t)l * HH * NN, Lst, sdt);
        scan_carry<<<(BB * HH * NN) / 256, 256, 0, stream>>>(
            A_p + (size_t)l * HH * NN, sdt, Lst);
        scan_pass2<<<dim3(HH / 256, CC, BB), 256, 0, stream>>>(
            vsb, dtr, dt2_w + (size_t)l * HH * RR, dt2_b + l * HH,
            A_p + (size_t)l * HH * NN, D_p + l * HH, Lst, ybf);

        const float* g_next = (l < 3) ? (norm_g + (l + 1) * DD) : final_g;
        const float* b_next = (l < 3) ? (norm_b + (l + 1) * DD) : final_b;
        gemm2_ln<<<MM / 32, 256, 0, stream>>>(
            ybf, wbf_out + (size_t)l * DD * HH, h, g_next, b_next,
            lnbuf, (l < 3) ? 1 : 0);
    }

    head_kernel<<<BB, 256, 0, stream>>>(h, final_g, final_b,
                                        head1_w, head1_b, head2_w, head2_b, outp);
}

// Round 10
// 498.156 us; speedup vs baseline: 2.8663x; 1.0563x over previous
//
#include <hip/hip_runtime.h>
#include <hip/hip_bf16.h>
#include <math.h>

// Model dims
#define BB 8
#define TT 1024
#define DD 256
#define HH 512
#define NN 16
#define RR 8
#define OUT_LEN 96
#define IN_DIM 32
#define MM (BB*TT)   // 8192 rows

// scan chunking: 512 blocks/pass (2 waves/SIMD), halved prologue + Lst size
#define SC 32
#define CC (TT/SC)   // 32

typedef unsigned short u16;
typedef unsigned int u32;
typedef __attribute__((ext_vector_type(8))) short short8;
typedef __attribute__((ext_vector_type(8))) unsigned short u16x8;
typedef __attribute__((ext_vector_type(4))) float float4v;

__device__ __forceinline__ u16 f2bf(float f) {
    __hip_bfloat16 h = __float2bfloat16(f);
    return *(u16*)&h;
}
__device__ __forceinline__ float bf2f(u16 u) {
    u32 v = ((u32)u) << 16;
    return *(float*)&v;
}

#define GLD_LDS16(src, dst) __builtin_amdgcn_global_load_lds( \
    (const __attribute__((address_space(1))) void*)(src),     \
    (__attribute__((address_space(3))) void*)(dst), 16, 0, 0)

// ---------------------------------------------------------------------------
// Embedding + PE + layer-0 LN (blocks 0..MM-1)  |  weight bf16 cvt (rest).
// Block-uniform branch; cvt blocks never touch the barrier path's semantics
// differently (both paths hit the same __syncthreads count? cvt path skips
// them entirely -- fine, barriers are per-block).
// ---------------------------------------------------------------------------
__global__ __launch_bounds__(256) void embed_ln_cvt_kernel(
    const float* __restrict__ x, const float* __restrict__ emb_w,
    const float* __restrict__ emb_b,
    const float* __restrict__ g, const float* __restrict__ b,
    float* __restrict__ h, u16* __restrict__ lnout,
    const float* __restrict__ w_in, u16* __restrict__ wbf_in,
    const float* __restrict__ w_out, u16* __restrict__ wbf_out, int nw)
{
    int bid = blockIdx.x;
    if (bid >= MM) {
        int i = (bid - MM) * 256 + threadIdx.x;
        if (i < nw) wbf_in[i] = f2bf(w_in[i]);
        else        wbf_out[i - nw] = f2bf(w_out[i - nw]);
        return;
    }

    int bt = bid;
    int d  = threadIdx.x;
    int t  = bt & (TT - 1);

    __shared__ float xs[IN_DIM];
    __shared__ float red[4], red2[4];
    if (threadIdx.x < IN_DIM) xs[threadIdx.x] = x[bt * IN_DIM + threadIdx.x];
    __syncthreads();

    const float* w = emb_w + d * IN_DIM;
    float acc = emb_b[d];
#pragma unroll
    for (int i = 0; i < IN_DIM; i++) acc = fmaf(xs[i], w[i], acc);

    int i2 = d & ~1;
    float div = expf(-(float)i2 * (logf(10000.0f) / (float)DD));
    float arg = (float)t * div;
    float pe = (d & 1) ? cosf(arg) : sinf(arg);
    float val = acc + pe;
    h[bt * DD + d] = val;

    float s = val;
#pragma unroll
    for (int o = 32; o > 0; o >>= 1) s += __shfl_down(s, o);
    int lane = d & 63, wave = d >> 6;
    if (lane == 0) red[wave] = s;
    __syncthreads();
    float mean = (red[0] + red[1] + red[2] + red[3]) * (1.0f / DD);

    float c = val - mean;
    float s2 = c * c;
#pragma unroll
    for (int o = 32; o > 0; o >>= 1) s2 += __shfl_down(s2, o);
    if (lane == 0) red2[wave] = s2;
    __syncthreads();
    float var = (red2[0] + red2[1] + red2[2] + red2[3]) * (1.0f / DD);

    lnout[bt * DD + d] = f2bf(c * rsqrtf(var + 1e-5f) * g[d] + b[d]);
}

// ---------------------------------------------------------------------------
// bf16 MFMA NT GEMM, BK=64 (validated R5-R9). In-projection.
// ---------------------------------------------------------------------------
template<int BM, int BN, int OUT_BF16>
__global__ __launch_bounds__(256) void gemm_bf16(
    const u16* __restrict__ A, const u16* __restrict__ B,
    void* __restrict__ Cv, int M, int N, int K, int addC)
{
    constexpr int BK = 64;
    constexpr int MT = BM / 32;
    constexpr int NT = BN / 32;
    static_assert(BN == 64, "B staging assumes BN==64");

    __shared__ __align__(16) u16 Al[8][BM][8];
    __shared__ __align__(16) u16 Bl[8][BN][8];

    const int tid = threadIdx.x;
    const int bm = blockIdx.y * BM;
    const int bn = blockIdx.x * BN;
    const int wid = tid >> 6, lane = tid & 63;
    const int wm = wid >> 1, wn = wid & 1;
    const int lq = lane >> 4, lm = lane & 15;

    float4v acc[MT][NT];
#pragma unroll
    for (int i = 0; i < MT; i++)
#pragma unroll
        for (int j = 0; j < NT; j++) acc[i][j] = (float4v){0.f, 0.f, 0.f, 0.f};

    for (int k0 = 0; k0 < K; k0 += BK) {
#pragma unroll
        for (int it = 0; it < (8 * BM) / 256; it++) {
            int c = it * 256 + tid;
            int q = c / BM, row = c % BM;
            GLD_LDS16(A + (size_t)(bm + row) * K + k0 + q * 8, &Al[q][row][0]);
        }
#pragma unroll
        for (int it = 0; it < (8 * BN) / 256; it++) {
            int c = it * 256 + tid;
            int q = c / BN, row = c % BN;
            GLD_LDS16(B + (size_t)(bn + row) * K + k0 + q * 8, &Bl[q][row][0]);
        }
        __syncthreads();

        short8 af[2][MT], bf[2][NT];
#pragma unroll
        for (int kk = 0; kk < 2; kk++) {
#pragma unroll
            for (int mt = 0; mt < MT; mt++)
                af[kk][mt] = *(const short8*)&Al[kk * 4 + lq][wm * (BM / 2) + mt * 16 + lm][0];
#pragma unroll
            for (int nt = 0; nt < NT; nt++)
                bf[kk][nt] = *(const short8*)&Bl[kk * 4 + lq][wn * (BN / 2) + nt * 16 + lm][0];
        }

#pragma unroll
        for (int kk = 0; kk < 2; kk++)
#pragma unroll
            for (int mt = 0; mt < MT; mt++)
#pragma unroll
                for (int nt = 0; nt < NT; nt++)
                    acc[mt][nt] = __builtin_amdgcn_mfma_f32_16x16x32_bf16(
                        af[kk][mt], bf[kk][nt], acc[mt][nt], 0, 0, 0);
        __syncthreads();
    }

#pragma unroll
    for (int mt = 0; mt < MT; mt++)
#pragma unroll
        for (int nt = 0; nt < NT; nt++) {
            int row0 = bm + wm * (BM / 2) + mt * 16 + lq * 4;
            int col  = bn + wn * (BN / 2) + nt * 16 + lm;
#pragma unroll
            for (int r = 0; r < 4; r++) {
                float vv = acc[mt][nt][r];
                if (OUT_BF16) {
                    ((u16*)Cv)[(size_t)(row0 + r) * N + col] = f2bf(vv);
                } else {
                    float* cp = (float*)Cv + (size_t)(row0 + r) * N + col;
                    if (addC) vv += *cp;
                    *cp = vv;
                }
            }
        }
}

// ---------------------------------------------------------------------------
// Out-projection GEMM + residual + next-layer LN (validated R9)
// ---------------------------------------------------------------------------
__global__ __launch_bounds__(256) void gemm2_ln(
    const u16* __restrict__ A, const u16* __restrict__ B,
    float* __restrict__ h,
    const float* __restrict__ g, const float* __restrict__ bb,
    u16* __restrict__ lnout, int doLN)
{
    constexpr int BM = 32;
    __shared__ __align__(16) u16 Al[8][BM][8];   // 4 KB
    __shared__ __align__(16) u16 Bl[8][256][8];  // 32 KB
    __shared__ float rs[2][BM], qs[2][BM];

    const int tid = threadIdx.x;
    const int bm = blockIdx.x * BM;
    const int wid = tid >> 6, lane = tid & 63;
    const int wm = wid >> 1, wn = wid & 1;
    const int lq = lane >> 4, lm = lane & 15;

    float4v acc[8];
#pragma unroll
    for (int j = 0; j < 8; j++) acc[j] = (float4v){0.f, 0.f, 0.f, 0.f};

    for (int k0 = 0; k0 < 512; k0 += 64) {
        {
            int q = tid >> 5, row = tid & 31;
            GLD_LDS16(A + (size_t)(bm + row) * 512 + k0 + q * 8, &Al[q][row][0]);
        }
#pragma unroll
        for (int it = 0; it < 8; it++) {
            int c = it * 256 + tid;
            int q = c >> 8, row = c & 255;
            GLD_LDS16(B + (size_t)row * 512 + k0 + q * 8, &Bl[q][row][0]);
        }
        __syncthreads();

        short8 af[2], bf[2][8];
#pragma unroll
        for (int kk = 0; kk < 2; kk++) {
            af[kk] = *(const short8*)&Al[kk * 4 + lq][wm * 16 + lm][0];
#pragma unroll
            for (int nt = 0; nt < 8; nt++)
                bf[kk][nt] = *(const short8*)&Bl[kk * 4 + lq][wn * 128 + nt * 16 + lm][0];
        }
#pragma unroll
        for (int kk = 0; kk < 2; kk++)
#pragma unroll
            for (int nt = 0; nt < 8; nt++)
                acc[nt] = __builtin_amdgcn_mfma_f32_16x16x32_bf16(
                    af[kk], bf[kk][nt], acc[nt], 0, 0, 0);
        __syncthreads();
    }

    float val[4][8];
    float s1[4] = {0.f, 0.f, 0.f, 0.f}, s2[4] = {0.f, 0.f, 0.f, 0.f};
#pragma unroll
    for (int r = 0; r < 4; r++) {
        int row = bm + wm * 16 + lq * 4 + r;
#pragma unroll
        for (int nt = 0; nt < 8; nt++) {
            int col = wn * 128 + nt * 16 + lm;
            float v = acc[nt][r] + h[(size_t)row * DD + col];
            val[r][nt] = v;
            s1[r] += v;
            s2[r] = fmaf(v, v, s2[r]);
            h[(size_t)row * DD + col] = v;
        }
    }
#pragma unroll
    for (int r = 0; r < 4; r++) {
#pragma unroll
        for (int o = 1; o < 16; o <<= 1) {
            s1[r] += __shfl_xor(s1[r], o);
            s2[r] += __shfl_xor(s2[r], o);
        }
    }
    if (lm == 0) {
#pragma unroll
        for (int r = 0; r < 4; r++) {
            rs[wn][wm * 16 + lq * 4 + r] = s1[r];
            qs[wn][wm * 16 + lq * 4 + r] = s2[r];
        }
    }
    __syncthreads();

    if (doLN) {
#pragma unroll
        for (int r = 0; r < 4; r++) {
            int i = wm * 16 + lq * 4 + r;
            int row = bm + i;
            float mean = (rs[0][i] + rs[1][i]) * (1.0f / DD);
            float var  = (qs[0][i] + qs[1][i]) * (1.0f / DD) - mean * mean;
            float rstd = rsqrtf(var + 1e-5f);
#pragma unroll
            for (int nt = 0; nt < 8; nt++) {
                int col = wn * 128 + nt * 16 + lm;
                lnout[(size_t)row * DD + col] =
                    f2bf((val[r][nt] - mean) * rstd * g[col] + bb[col]);
            }
        }
    }
}

// ---------------------------------------------------------------------------
// Fused depthwise conv(k=3,pad1)+SiLU + dt1 (validated R7-R9)
// ---------------------------------------------------------------------------
__global__ __launch_bounds__(256) void conv_dt1_kernel(
    const u16* __restrict__ v, const float* __restrict__ cwg,
    const float* __restrict__ w1g, const float* __restrict__ b1g,
    u16* __restrict__ vsb, float* __restrict__ dtr)
{
    __shared__ float w1s[RR * 2 * 256];
    int tid = threadIdx.x;
    {
        int lane = tid & 63, rc = tid >> 6;
#pragma unroll
        for (int i = 0; i < 4; i++) {
            int rci = rc + i * 4;
            int r = rci >> 1, jc = rci & 1;
            float4 wv = *(const float4*)(w1g + r * HH + lane * 8 + jc * 4);
            *(float4*)&w1s[rci * 256 + lane * 4] = wv;
        }
    }
    __syncthreads();

    int wave = tid >> 6, lane = tid & 63;
    int m = blockIdx.x * 4 + wave;
    int t = m & (TT - 1);
    int h0 = lane * 8;

    const u16* vrow = v + (size_t)m * HH + h0;
    u16x8 x0 = *(const u16x8*)vrow;
    u16x8 xm = (t > 0)      ? *(const u16x8*)(vrow - HH) : (u16x8)(0);
    u16x8 xp = (t < TT - 1) ? *(const u16x8*)(vrow + HH) : (u16x8)(0);

    const float* wp = cwg + h0 * 3;
    float a[8];
    u16x8 o;
#pragma unroll
    for (int j = 0; j < 8; j++) {
        float s = wp[j * 3] * bf2f(xm[j]);
        s = fmaf(wp[j * 3 + 1], bf2f(x0[j]), s);
        s = fmaf(wp[j * 3 + 2], bf2f(xp[j]), s);
        s = s / (1.0f + __expf(-s));
        a[j] = s;
        o[j] = f2bf(s);
    }
    *(u16x8*)(vsb + (size_t)m * HH + h0) = o;

    float acc[RR];
#pragma unroll
    for (int r = 0; r < RR; r++) {
        float4 wlo = *(const float4*)&w1s[(r * 2 + 0) * 256 + lane * 4];
        float4 whi = *(const float4*)&w1s[(r * 2 + 1) * 256 + lane * 4];
        float s = a[0] * wlo.x;
        s = fmaf(a[1], wlo.y, s);
        s = fmaf(a[2], wlo.z, s);
        s = fmaf(a[3], wlo.w, s);
        s = fmaf(a[4], whi.x, s);
        s = fmaf(a[5], whi.y, s);
        s = fmaf(a[6], whi.z, s);
        s = fmaf(a[7], whi.w, s);
        acc[r] = s;
    }
#pragma unroll
    for (int r = 0; r < RR; r++) {
#pragma unroll
        for (int o2 = 1; o2 < 64; o2 <<= 1) acc[r] += __shfl_xor(acc[r], o2);
    }
    if (lane == 0) {
#pragma unroll
        for (int r = 0; r < RR; r++) acc[r] = fmaxf(acc[r] + b1g[r], 0.0f);
        *(float4*)(dtr + (size_t)m * RR)     = make_float4(acc[0], acc[1], acc[2], acc[3]);
        *(float4*)(dtr + (size_t)m * RR + 4) = make_float4(acc[4], acc[5], acc[6], acc[7]);
    }
}

// ---------------------------------------------------------------------------
__device__ __forceinline__ float softplus_f(float s) {
    return (s > 20.0f) ? s : __logf(1.0f + __expf(s));
}

// ---------------------------------------------------------------------------
// Chunk-parallel selective scan (validated structure R7/R9).
// NEW: Lst stored as bf16 (states are O(1); carry-in error enters y through
// x Ap ~ 0.01 sums -- absmax headroom 4.8x). Halves scan-state HBM traffic.
// ---------------------------------------------------------------------------
__global__ __launch_bounds__(256) void scan_pass1(
    const u16* __restrict__ vs, const float* __restrict__ dtr,
    const float* __restrict__ dt2_w, const float* __restrict__ dt2_b,
    const float* __restrict__ A_p,
    u16* __restrict__ Lst, float* __restrict__ sdt)
{
    int h = blockIdx.x * 256 + threadIdx.x;
    int c = blockIdx.y;
    int b = blockIdx.z;

    float A[NN], invA[NN], st[NN];
    const float* ap = A_p + h * NN;
#pragma unroll
    for (int n = 0; n < NN; n++) {
        float a = -__expf(ap[n]);
        A[n] = a; invA[n] = 1.0f / a; st[n] = 0.0f;
    }
    float w2[RR];
#pragma unroll
    for (int r = 0; r < RR; r++) w2[r] = dt2_w[h * RR + r];
    float b2 = dt2_b[h];

    const u16*   vbase = vs  + ((size_t)b * TT + (size_t)c * SC) * HH + h;
    const float* drow  = dtr + ((size_t)b * TT + (size_t)c * SC) * RR;

    float dr[RR];
#pragma unroll
    for (int r = 0; r < RR; r++) dr[r] = drow[r];

    float s_dt = 0.0f;
#pragma unroll 2
    for (int t = 0; t < SC; t++) {
        float drn[RR];
        if (t + 1 < SC) {
#pragma unroll
            for (int r = 0; r < RR; r++) drn[r] = drow[(t + 1) * RR + r];
        }
        float s = b2;
#pragma unroll
        for (int r = 0; r < RR; r++) s = fmaf(dr[r], w2[r], s);
        float dt = softplus_f(s);
        float xv = bf2f(vbase[(size_t)t * HH]);
        s_dt += dt;
#pragma unroll
        for (int n = 0; n < NN; n++) {
            float e  = __expf(A[n] * dt);
            float dB = (e - 1.0f) * invA[n] * dt;
            st[n] = fmaf(e, st[n], dB * xv);
        }
#pragma unroll
        for (int r = 0; r < RR; r++) dr[r] = drn[r];
    }

    size_t base = (((size_t)c * BB + b) * HH + h) * NN;
    u16x8 lo, hi;
#pragma unroll
    for (int n = 0; n < 8; n++) { lo[n] = f2bf(st[n]); hi[n] = f2bf(st[n + 8]); }
    *(u16x8*)(Lst + base)     = lo;
    *(u16x8*)(Lst + base + 8) = hi;
    sdt[((size_t)c * BB + b) * HH + h] = s_dt;
}

__global__ __launch_bounds__(256) void scan_carry(
    const float* __restrict__ A_p, const float* __restrict__ sdt,
    u16* __restrict__ Lst)
{
    int i = blockIdx.x * 256 + threadIdx.x;   // (b*HH+h)*NN+n
    int n  = i & (NN - 1);
    int bh = i >> 4;
    int h  = bh & (HH - 1);
    int b  = bh >> 9;

    float A = -__expf(A_p[h * NN + n]);
    float E = 0.0f;
    for (int c = 0; c < CC; c++) {
        size_t sidx = ((size_t)c * BB + b) * HH + h;
        float P = __expf(A * sdt[sidx]);
        size_t lidx = sidx * NN + n;
        float Lc = bf2f(Lst[lidx]);
        Lst[lidx] = f2bf(E);
        E = fmaf(P, E, Lc);
    }
}

__global__ __launch_bounds__(256) void scan_pass2(
    const u16* __restrict__ vs,
    const float* __restrict__ dtr,
    const float* __restrict__ dt2_w,
    const float* __restrict__ dt2_b,
    const float* __restrict__ A_p, const float* __restrict__ D_p,
    const u16* __restrict__ carry,
    u16* __restrict__ y)
{
    int h = blockIdx.x * 256 + threadIdx.x;
    int c = blockIdx.y;
    int b = blockIdx.z;

    float A[NN], invA[NN], Ap[NN], st[NN];
    const float* app = A_p + h * NN;
    size_t cbase = (((size_t)c * BB + b) * HH + h) * NN;
    {
        u16x8 lo = *(const u16x8*)(carry + cbase);
        u16x8 hi = *(const u16x8*)(carry + cbase + 8);
#pragma unroll
        for (int n = 0; n < 8; n++) { st[n] = bf2f(lo[n]); st[n + 8] = bf2f(hi[n]); }
    }
#pragma unroll
    for (int n = 0; n < NN; n++) {
        float apv = app[n];
        Ap[n] = apv;
        float a = -__expf(apv);
        A[n] = a; invA[n] = 1.0f / a;
    }
    float w2[RR];
#pragma unroll
    for (int r = 0; r < RR; r++) w2[r] = dt2_w[h * RR + r];
    float b2 = dt2_b[h];
    float Dp = D_p[h];

    const u16*   vbase = vs  + ((size_t)b * TT + (size_t)c * SC) * HH + h;
    const float* drow  = dtr + ((size_t)b * TT + (size_t)c * SC) * RR;
    u16*         ybase = y   + ((size_t)b * TT + (size_t)c * SC) * HH + h;

    float dr[RR];
#pragma unroll
    for (int r = 0; r < RR; r++) dr[r] = drow[r];

#pragma unroll 2
    for (int t = 0; t < SC; t++) {
        float drn[RR];
        if (t + 1 < SC) {
#pragma unroll
            for (int r = 0; r < RR; r++) drn[r] = drow[(t + 1) * RR + r];
        }
        float s = b2;
#pragma unroll
        for (int r = 0; r < RR; r++) s = fmaf(dr[r], w2[r], s);
        float dt = softplus_f(s);
        float xv = bf2f(vbase[(size_t)t * HH]);
        float acc = Dp * xv;
#pragma unroll
        for (int n = 0; n < NN; n++) {
            float e  = __expf(A[n] * dt);
            float dB = (e - 1.0f) * invA[n] * dt;
            st[n] = fmaf(e, st[n], dB * xv);
            acc = fmaf(st[n], Ap[n], acc);
        }
        ybase[(size_t)t * HH] = f2bf(acc);
#pragma unroll
        for (int r = 0; r < RR; r++) dr[r] = drn[r];
    }
}

// ---------------------------------------------------------------------------
// Head: final LN on last token, head1+silu, head2. One block per batch.
// ---------------------------------------------------------------------------
__global__ __launch_bounds__(256) void head_kernel(
    const float* __restrict__ h,
    const float* __restrict__ fg, const float* __restrict__ fb,
    const float* __restrict__ w1, const float* __restrict__ b1,
    const float* __restrict__ w2, const float* __restrict__ b2,
    float* __restrict__ out)
{
    int b = blockIdx.x;
    int d = threadIdx.x;
    __shared__ float hn[DD], s1[DD];
    __shared__ float red[4];

    float v = h[((size_t)b * TT + (TT - 1)) * DD + d];

    float s = v;
#pragma unroll
    for (int o = 32; o > 0; o >>= 1) s += __shfl_down(s, o);
    int lane = d & 63, wave = d >> 6;
    if (lane == 0) red[wave] = s;
    __syncthreads();
    float mean = (red[0] + red[1] + red[2] + red[3]) * (1.0f / DD);
    __syncthreads();

    float c = v - mean;
    float s2 = c * c;
#pragma unroll
    for (int o = 32; o > 0; o >>= 1) s2 += __shfl_down(s2, o);
    if (lane == 0) red[wave] = s2;
    __syncthreads();
    float var = (red[0] + red[1] + red[2] + red[3]) * (1.0f / DD);

    hn[d] = c * rsqrtf(var + 1e-5f) * fg[d] + fb[d];
    __syncthreads();

    float a1 = b1[d];
    const float* w1r = w1 + d * DD;
#pragma unroll 8
    for (int k = 0; k < DD; k++) a1 = fmaf(hn[k], w1r[k], a1);
    s1[d] = a1 / (1.0f + __expf(-a1));
    __syncthreads();

    if (d < OUT_LEN) {
        float a2 = b2[d];
        const float* w2r = w2 + d * DD;
#pragma unroll 8
        for (int k = 0; k < DD; k++) a2 = fmaf(s1[k], w2r[k], a2);
        out[b * OUT_LEN + d] = a2;
    }
}

// ---------------------------------------------------------------------------
extern "C" void kernel_launch(void* const* d_in, const int* in_sizes, int n_in,
                              void* d_out, int out_size, void* d_ws, size_t ws_size,
                              hipStream_t stream)
{
    (void)in_sizes; (void)n_in; (void)out_size; (void)ws_size;

    const float* x       = (const float*)d_in[0];
    const float* emb_w   = (const float*)d_in[1];
    const float* emb_b   = (const float*)d_in[2];
    const float* norm_g  = (const float*)d_in[3];
    const float* norm_b  = (const float*)d_in[4];
    const float* in_w    = (const float*)d_in[5];
    const float* conv_w  = (const float*)d_in[6];
    const float* A_p     = (const float*)d_in[7];
    const float* D_p     = (const float*)d_in[8];
    const float* dt1_w   = (const float*)d_in[9];
    const float* dt1_b   = (const float*)d_in[10];
    const float* dt2_w   = (const float*)d_in[11];
    const float* dt2_b   = (const float*)d_in[12];
    const float* out_w   = (const float*)d_in[13];
    const float* final_g = (const float*)d_in[14];
    const float* final_b = (const float*)d_in[15];
    const float* head1_w = (const float*)d_in[16];
    const float* head1_b = (const float*)d_in[17];
    const float* head2_w = (const float*)d_in[18];
    const float* head2_b = (const float*)d_in[19];
    float* outp = (float*)d_out;

    char* ws = (char*)d_ws;
    float* h     = (float*)ws;                ws += (size_t)MM * DD * 4;   // fp32 residual
    u16*   vbf   = (u16*)ws;                  ws += (size_t)MM * HH * 2;   // gemm1 out
    u16*   vsb   = (u16*)ws;                  ws += (size_t)MM * HH * 2;   // conv+silu
    u16*   ybf   = (u16*)ws;                  ws += (size_t)MM * HH * 2;   // scan y
    u16*   lnbuf = (u16*)ws;                  ws += (size_t)MM * DD * 2;   // LN out
    float* dtr   = (float*)ws;                ws += (size_t)MM * RR * 4;
    u16*   Lst   = (u16*)ws;                  ws += (size_t)CC * BB * HH * NN * 2;  // bf16
    float* sdt   = (float*)ws;                ws += (size_t)CC * BB * HH * 4;
    u16*   wbf_in  = (u16*)ws;                ws += (size_t)4 * HH * DD * 2;
    u16*   wbf_out = (u16*)ws;                ws += (size_t)4 * DD * HH * 2;

    const int NW = 4 * HH * DD;
    embed_ln_cvt_kernel<<<MM + (2 * NW) / 256, 256, 0, stream>>>(
        x, emb_w, emb_b, norm_g, norm_b, h, lnbuf,
        in_w, wbf_in, out_w, wbf_out, NW);

    for (int l = 0; l < 4; l++) {
        gemm_bf16<128, 64, 1><<<dim3(HH / 64, MM / 128), 256, 0, stream>>>(
            lnbuf, wbf_in + (size_t)l * HH * DD, vbf, MM, HH, DD, 0);
        conv_dt1_kernel<<<MM / 4, 256, 0, stream>>>(
            vbf, conv_w + (size_t)l * HH * 3,
            dt1_w + (size_t)l * RR * HH, dt1_b + l * RR, vsb, dtr);

        scan_pass1<<<dim3(HH / 256, CC, BB), 256, 0, stream>>>(
            vsb, dtr, dt2_w + (size_t)l * HH * RR, dt2_b + l * HH,
            A_p + (size_t)l * HH * NN, Lst, sdt);
        scan_carry<<<(BB * HH * NN) / 256, 256, 0, stream>>>(
            A_p + (size_t)l * HH * NN, sdt, Lst);
        scan_pass2<<<dim3(HH / 256, CC, BB), 256, 0, stream>>>(
            vsb, dtr, dt2_w + (size_t)l * HH * RR, dt2_b + l * HH,
            A_p + (size_t)l * HH * NN, D_p + l * HH, Lst, ybf);

        const float* g_next = (l < 3) ? (norm_g + (l + 1) * DD) : final_g;
        const float* b_next = (l < 3) ? (norm_b + (l + 1) * DD) : final_b;
        gemm2_ln<<<MM / 32, 256, 0, stream>>>(
            ybf, wbf_out + (size_t)l * DD * HH, h, g_next, b_next,
            lnbuf, (l < 3) ? 1 : 0);
    }

    head_kernel<<<BB, 256, 0, stream>>>(h, final_g, final_b,
                                        head1_w, head1_b, head2_w, head2_b, outp);
}